// Round 1
// baseline (6774.310 us; speedup 1.0000x reference)
//
#include <hip/hip_runtime.h>
#include <math.h>

#define S_LEN 512
#define DMODEL 256
#define NHEAD 8
#define HDIM 32
#define NLAYER 4
#define NSCALE 4

enum { F_PE = 1, F_BETA = 2, F_GELU = 4 };

__device__ __forceinline__ float gelu_f(float x) {
    return 0.5f * x * (1.0f + erff(x * 0.70710678118654752440f));
}

// C[M,N] = op( A[M,K](+aadd) @ W[N,K]^T + bias (+ C if F_BETA) (+ PE if F_PE) ),
// op = gelu if F_GELU
__global__ __launch_bounds__(256) void gemm_kernel(
    const float* __restrict__ A, int lda,
    const float* __restrict__ W, int ldw,
    const float* __restrict__ bias,
    const float* __restrict__ aadd,
    float* __restrict__ C, int ldc,
    int M, int N, int K, int flags)
{
    __shared__ float As[16][65];
    __shared__ float Ws[16][65];
    const int tid = threadIdx.x;
    const int bm = blockIdx.x * 64;
    const int bn = blockIdx.y * 64;
    const int tx = tid & 15;   // n direction
    const int ty = tid >> 4;   // m direction
    const int r  = tid >> 2;   // 0..63 load row
    const int c0 = (tid & 3) << 2;

    float acc[4][4] = {};

    for (int k0 = 0; k0 < K; k0 += 16) {
        {
            int gm = bm + r;
            #pragma unroll
            for (int i = 0; i < 4; ++i) {
                int gk = k0 + c0 + i;
                float v = 0.f;
                if (gm < M && gk < K) {
                    v = A[(size_t)gm * lda + gk];
                    if (aadd) v += aadd[gk];
                }
                As[c0 + i][r] = v;
            }
            int gn = bn + r;
            #pragma unroll
            for (int i = 0; i < 4; ++i) {
                int gk = k0 + c0 + i;
                float v = 0.f;
                if (gn < N && gk < K) v = W[(size_t)gn * ldw + gk];
                Ws[c0 + i][r] = v;
            }
        }
        __syncthreads();
        #pragma unroll
        for (int kk = 0; kk < 16; ++kk) {
            float a[4], b[4];
            #pragma unroll
            for (int i = 0; i < 4; ++i) a[i] = As[kk][ty * 4 + i];
            #pragma unroll
            for (int j = 0; j < 4; ++j) b[j] = Ws[kk][tx * 4 + j];
            #pragma unroll
            for (int i = 0; i < 4; ++i)
                #pragma unroll
                for (int j = 0; j < 4; ++j)
                    acc[i][j] = fmaf(a[i], b[j], acc[i][j]);
        }
        __syncthreads();
    }

    #pragma unroll
    for (int i = 0; i < 4; ++i) {
        int gm = bm + ty * 4 + i;
        if (gm >= M) continue;
        #pragma unroll
        for (int j = 0; j < 4; ++j) {
            int gn = bn + tx * 4 + j;
            if (gn >= N) continue;
            float v = acc[i][j];
            if (bias) v += bias[gn];
            if (flags & F_BETA) v += C[(size_t)gm * ldc + gn];
            if (flags & F_PE) {
                int pos = gm & (S_LEN - 1);
                float div = expf((float)(gn & ~1) * (-9.210340371976184f / 256.0f));
                float ang = (float)pos * div;
                v += (gn & 1) ? cosf(ang) : sinf(ang);
            }
            if (flags & F_GELU) v = gelu_f(v);
            C[(size_t)gm * ldc + gn] = v;
        }
    }
}

// Banded attention: one wave per (b, h, q). qkv layout: (B*S, 768), q|k|v each 256.
// o layout: (B*S, 256), o[b,s,h*32+d].
__global__ __launch_bounds__(64) void attn_kernel(
    const float* __restrict__ qkv, float* __restrict__ o, int radius)
{
    __shared__ float sp[128];
    const int idx = blockIdx.x;
    const int q = idx & (S_LEN - 1);
    const int h = (idx >> 9) & (NHEAD - 1);
    const int b = idx >> 12;
    const int lane = threadIdx.x;

    const int k0 = max(0, q - radius);
    const int k1 = min(S_LEN - 1, q + radius);
    const int Wd = k1 - k0 + 1;     // <= 101

    const float* base = qkv + (size_t)(b * S_LEN) * 768;
    const float* qrow = base + (size_t)q * 768 + h * HDIM;

    float lmax = -1e30f;
    for (int j = lane; j < Wd; j += 64) {
        const float* krow = base + (size_t)(k0 + j) * 768 + 256 + h * HDIM;
        float d = 0.f;
        #pragma unroll
        for (int t = 0; t < HDIM; ++t) d = fmaf(qrow[t], krow[t], d);
        d *= 0.17677669529663688f;   // 1/sqrt(32)
        sp[j] = d;
        lmax = fmaxf(lmax, d);
    }
    #pragma unroll
    for (int off = 32; off; off >>= 1) lmax = fmaxf(lmax, __shfl_xor(lmax, off, 64));

    float lsum = 0.f;
    for (int j = lane; j < Wd; j += 64) {
        float p = expf(sp[j] - lmax);
        sp[j] = p;
        lsum += p;
    }
    #pragma unroll
    for (int off = 32; off; off >>= 1) lsum += __shfl_xor(lsum, off, 64);
    float inv = 1.0f / lsum;
    __syncthreads();

    const int d = lane & 31;
    const int half = lane >> 5;
    float acc = 0.f;
    for (int j = half; j < Wd; j += 2) {
        const float* vrow = base + (size_t)(k0 + j) * 768 + 512 + h * HDIM;
        acc = fmaf(sp[j], vrow[d], acc);
    }
    acc += __shfl_down(acc, 32, 64);
    if (lane < 32)
        o[((size_t)(b * S_LEN) + q) * DMODEL + h * HDIM + d] = acc * inv;
}

// out = LN(a (+ b2)) * g + be, optional gelu. One block (256 thr) per row of 256.
__global__ __launch_bounds__(256) void ln_kernel(
    const float* __restrict__ a, const float* __restrict__ b2,
    const float* __restrict__ g, const float* __restrict__ be,
    float* __restrict__ out, int dogelu)
{
    __shared__ float red[256];
    const int row = blockIdx.x;
    const int t = threadIdx.x;
    float v = a[(size_t)row * DMODEL + t];
    if (b2) v += b2[(size_t)row * DMODEL + t];

    red[t] = v;
    __syncthreads();
    for (int s = 128; s; s >>= 1) { if (t < s) red[t] += red[t + s]; __syncthreads(); }
    float m = red[0] * (1.0f / DMODEL);
    __syncthreads();
    float dv = v - m;
    red[t] = dv * dv;
    __syncthreads();
    for (int s = 128; s; s >>= 1) { if (t < s) red[t] += red[t + s]; __syncthreads(); }
    float var = red[0] * (1.0f / DMODEL);
    float y = dv * rsqrtf(var + 1e-5f) * g[t] + be[t];
    if (dogelu) y = gelu_f(y);
    out[(size_t)row * DMODEL + t] = y;
}

static inline void gemm(hipStream_t s, const float* A, int lda, const float* W, int ldw,
                        const float* bias, const float* aadd, float* C, int ldc,
                        int M, int N, int K, int flags)
{
    dim3 grid((M + 63) / 64, (N + 63) / 64);
    hipLaunchKernelGGL(gemm_kernel, grid, dim3(256), 0, s,
                       A, lda, W, ldw, bias, aadd, C, ldc, M, N, K, flags);
}

extern "C" void kernel_launch(void* const* d_in, const int* in_sizes, int n_in,
                              void* d_out, int out_size, void* d_ws, size_t ws_size,
                              hipStream_t stream)
{
    const float* emb        = (const float*)d_in[0];   // (16,512,640)
    const float* features   = (const float*)d_in[1];   // (16,66)
    const float* ip_w       = (const float*)d_in[2];   // (256,640)
    const float* ip_b       = (const float*)d_in[3];   // (256)
    const float* scale_emb  = (const float*)d_in[4];   // (4,256)
    const float* attn_in_w  = (const float*)d_in[5];   // (4,4,768,256)
    const float* attn_in_b  = (const float*)d_in[6];   // (4,4,768)
    const float* attn_out_w = (const float*)d_in[7];   // (4,4,256,256)
    const float* attn_out_b = (const float*)d_in[8];   // (4,4,256)
    const float* fus_w      = (const float*)d_in[9];   // (4,256,1024)
    const float* fus_b      = (const float*)d_in[10];  // (4,256)
    const float* ffn_w1     = (const float*)d_in[11];  // (4,1024,256)
    const float* ffn_b1     = (const float*)d_in[12];  // (4,1024)
    const float* ffn_w2     = (const float*)d_in[13];  // (4,256,1024)
    const float* ffn_b2     = (const float*)d_in[14];  // (4,256)
    const float* n1_g       = (const float*)d_in[15];
    const float* n1_b       = (const float*)d_in[16];
    const float* n2_g       = (const float*)d_in[17];
    const float* n2_b       = (const float*)d_in[18];
    const float* feat_w     = (const float*)d_in[19];  // (256,66)
    const float* feat_b     = (const float*)d_in[20];
    const float* feat_ln_g  = (const float*)d_in[21];
    const float* feat_ln_b  = (const float*)d_in[22];
    const float* h1_w       = (const float*)d_in[23];  // (256,512)
    const float* h1_b       = (const float*)d_in[24];
    const float* h_ln_g     = (const float*)d_in[25];
    const float* h_ln_b     = (const float*)d_in[26];
    const float* h2_w       = (const float*)d_in[27];  // (128,256)
    const float* h2_b       = (const float*)d_in[28];
    const float* h3_w       = (const float*)d_in[29];  // (1,128)
    const float* h3_b       = (const float*)d_in[30];
    float* outp = (float*)d_out;

    const int Btok = 16 * S_LEN;            // 8192 rows
    float* ws = (float*)d_ws;
    float* x     = ws;                       // 8192*256
    float* big   = x + (size_t)Btok * DMODEL;        // 8192*1024 (qkv / ffn-mid)
    float* obuf  = big + (size_t)Btok * 1024;        // 8192*256
    float* proj  = obuf + (size_t)Btok * DMODEL;     // 8192*256
    float* fused = proj + (size_t)Btok * DMODEL;     // 8192*256
    float* frbuf = fused + (size_t)Btok * DMODEL;    // 16*256
    float* h1buf = frbuf + 16 * DMODEL;              // 16*256
    float* h2buf = h1buf + 16 * DMODEL;              // 16*128

    static const int SCALES[NSCALE] = {5, 10, 20, 50};

    // x = emb @ ip_w^T + ip_b + PE
    gemm(stream, emb, 640, ip_w, 640, ip_b, nullptr, x, DMODEL,
         Btok, DMODEL, 640, F_PE);

    for (int l = 0; l < NLAYER; ++l) {
        for (int si = 0; si < NSCALE; ++si) {
            const int ls = l * NSCALE + si;
            // qkv = (x + scale_emb[si]) @ attn_in_w[l,si]^T + attn_in_b[l,si]
            gemm(stream, x, DMODEL,
                 attn_in_w + (size_t)ls * 768 * DMODEL, DMODEL,
                 attn_in_b + (size_t)ls * 768,
                 scale_emb + si * DMODEL,
                 big, 768, Btok, 768, DMODEL, 0);
            // banded attention
            hipLaunchKernelGGL(attn_kernel, dim3(16 * NHEAD * S_LEN), dim3(64), 0, stream,
                               big, obuf, SCALES[si]);
            // proj = o @ attn_out_w^T + b
            gemm(stream, obuf, DMODEL,
                 attn_out_w + (size_t)ls * DMODEL * DMODEL, DMODEL,
                 attn_out_b + (size_t)ls * DMODEL, nullptr,
                 proj, DMODEL, Btok, DMODEL, DMODEL, 0);
            // fused (+)= proj @ fus_w[l][:, si*256:(si+1)*256]^T (+ fus_b on si==0)
            gemm(stream, proj, DMODEL,
                 fus_w + (size_t)l * DMODEL * 1024 + si * DMODEL, 1024,
                 (si == 0) ? (fus_b + l * DMODEL) : nullptr, nullptr,
                 fused, DMODEL, Btok, DMODEL, DMODEL,
                 (si == 0) ? 0 : F_BETA);
        }
        // x = LN(x + fused)
        hipLaunchKernelGGL(ln_kernel, dim3(Btok), dim3(256), 0, stream,
                           x, fused, n1_g + l * DMODEL, n1_b + l * DMODEL, x, 0);
        // mid = gelu(x @ ffn_w1^T + b1)
        gemm(stream, x, DMODEL,
             ffn_w1 + (size_t)l * 1024 * DMODEL, DMODEL,
             ffn_b1 + (size_t)l * 1024, nullptr,
             big, 1024, Btok, 1024, DMODEL, F_GELU);
        // f = mid @ ffn_w2^T + b2
        gemm(stream, big, 1024,
             ffn_w2 + (size_t)l * DMODEL * 1024, 1024,
             ffn_b2 + (size_t)l * DMODEL, nullptr,
             proj, DMODEL, Btok, DMODEL, 1024, 0);
        // x = LN(x + f)
        hipLaunchKernelGGL(ln_kernel, dim3(Btok), dim3(256), 0, stream,
                           x, proj, n2_g + l * DMODEL, n2_b + l * DMODEL, x, 0);
    }

    // head
    // fr = gelu(LN(features @ feat_w^T + feat_b))
    gemm(stream, features, 66, feat_w, 66, feat_b, nullptr, frbuf, DMODEL,
         16, DMODEL, 66, 0);
    hipLaunchKernelGGL(ln_kernel, dim3(16), dim3(256), 0, stream,
                       frbuf, nullptr, feat_ln_g, feat_ln_b, frbuf, 1);
    // h1pre = xc @ h1_w[:, :256]^T + h1_b ; xc = x[:, S/2] -> row stride S*DM
    gemm(stream, x + (size_t)(S_LEN / 2) * DMODEL, S_LEN * DMODEL,
         h1_w, 512, h1_b, nullptr, h1buf, DMODEL, 16, DMODEL, DMODEL, 0);
    // h1pre += fr @ h1_w[:, 256:]^T
    gemm(stream, frbuf, DMODEL, h1_w + 256, 512, nullptr, nullptr,
         h1buf, DMODEL, 16, DMODEL, DMODEL, F_BETA);
    // h1 = gelu(LN(h1pre))
    hipLaunchKernelGGL(ln_kernel, dim3(16), dim3(256), 0, stream,
                       h1buf, nullptr, h_ln_g, h_ln_b, h1buf, 1);
    // h2 = gelu(h1 @ h2_w^T + h2_b)
    gemm(stream, h1buf, DMODEL, h2_w, DMODEL, h2_b, nullptr, h2buf, 128,
         16, 128, DMODEL, F_GELU);
    // out = h2 @ h3_w^T + h3_b
    gemm(stream, h2buf, 128, h3_w, 128, h3_b, nullptr, outp, 1,
         16, 1, 128, 0);
}

// Round 2
// 2029.762 us; speedup vs baseline: 3.3375x; 3.3375x over previous
//
#include <hip/hip_runtime.h>
#include <math.h>

#define S_LEN 512
#define DMODEL 256
#define NHEAD 8
#define HDIM 32
#define NLAYER 4
#define NSCALE 4

typedef unsigned short ushortT;
typedef unsigned int uintT;
typedef short bf16x8 __attribute__((ext_vector_type(8)));
typedef float f32x4 __attribute__((ext_vector_type(4)));

enum { F_PE = 1, F_BETA = 2, F_GELU = 4 };

__device__ __forceinline__ float gelu_f(float x) {
    return 0.5f * x * (1.0f + erff(x * 0.70710678118654752440f));
}
__device__ __forceinline__ ushortT f2bf(float f) {
    union { float f; uintT i; } u; u.f = f;
    uintT r = u.i + 0x7FFF + ((u.i >> 16) & 1);   // RNE
    return (ushortT)(r >> 16);
}
__device__ __forceinline__ float bf2f(ushortT s) {
    union { uintT i; float f; } u; u.i = ((uintT)s) << 16;
    return u.f;
}
__device__ __forceinline__ int swz(int r) { return (r & 3) ^ ((r >> 2) & 3); }

#define GLD16(g, l) \
    __builtin_amdgcn_global_load_lds((const __attribute__((address_space(1))) void*)(g), \
                                     (__attribute__((address_space(3))) void*)(l), 16, 0, 0)

// C[M,N] = op(A[M,K]bf16 @ W[N,K]bf16^T + bias) ; M%128==0, N%BN==0, K%32==0
template<int BN>
__global__ __launch_bounds__(256) void mfma_gemm(
    const ushortT* __restrict__ A, int lda,
    const ushortT* __restrict__ W, int ldw,
    const float* __restrict__ bias,
    const float* __restrict__ betaC,
    float* __restrict__ out32,
    ushortT* __restrict__ out16,
    int ldc, int K, int flags)
{
    constexpr int NI = BN / 32;          // 16-wide n-tiles per wave
    __shared__ __align__(16) ushortT As[128 * 32];
    __shared__ __align__(16) ushortT Bs[BN * 32];
    const int tid = threadIdx.x;
    const int wave = tid >> 6, lane = tid & 63;
    const int l15 = lane & 15, qd = lane >> 4;
    const int m0 = blockIdx.x * 128, n0 = blockIdx.y * BN;
    const int wm = (wave >> 1) * 64, wn = (wave & 1) * (BN / 2);

    f32x4 acc[4][NI];
    #pragma unroll
    for (int i = 0; i < 4; ++i)
        #pragma unroll
        for (int j = 0; j < NI; ++j) acc[i][j] = (f32x4){0.f, 0.f, 0.f, 0.f};

    for (int k0 = 0; k0 < K; k0 += 32) {
        #pragma unroll
        for (int it = 0; it < 2; ++it) {        // A: 512 16B-chunks
            int c = it * 256 + tid;
            int m = c >> 2, s = c & 3;
            int kc = s ^ swz(m);
            const ushortT* g = A + (size_t)(m0 + m) * lda + k0 + kc * 8;
            GLD16(g, (ushortT*)As + (size_t)(it * 256 + wave * 64) * 8);
        }
        #pragma unroll
        for (int it = 0; it < BN / 64; ++it) {  // B: BN*4 chunks
            int c = it * 256 + tid;
            int n = c >> 2, s = c & 3;
            int kc = s ^ swz(n);
            const ushortT* g = W + (size_t)(n0 + n) * ldw + k0 + kc * 8;
            GLD16(g, (ushortT*)Bs + (size_t)(it * 256 + wave * 64) * 8);
        }
        __syncthreads();
        bf16x8 af[4], bfr[NI];
        #pragma unroll
        for (int mi = 0; mi < 4; ++mi) {
            int r = wm + mi * 16 + l15;
            af[mi] = *(const bf16x8*)(As + r * 32 + (qd ^ swz(r)) * 8);
        }
        #pragma unroll
        for (int ni = 0; ni < NI; ++ni) {
            int r = wn + ni * 16 + l15;
            bfr[ni] = *(const bf16x8*)(Bs + r * 32 + (qd ^ swz(r)) * 8);
        }
        #pragma unroll
        for (int mi = 0; mi < 4; ++mi)
            #pragma unroll
            for (int ni = 0; ni < NI; ++ni)
                acc[mi][ni] = __builtin_amdgcn_mfma_f32_16x16x32_bf16(
                    af[mi], bfr[ni], acc[mi][ni], 0, 0, 0);
        __syncthreads();
    }

    #pragma unroll
    for (int mi = 0; mi < 4; ++mi) {
        #pragma unroll
        for (int ni = 0; ni < NI; ++ni) {
            int col = n0 + wn + ni * 16 + l15;
            float bv = bias ? bias[col] : 0.f;
            #pragma unroll
            for (int r = 0; r < 4; ++r) {
                int grow = m0 + wm + mi * 16 + qd * 4 + r;
                float v = acc[mi][ni][r] + bv;
                if (flags & F_BETA) v += betaC[(size_t)grow * ldc + col];
                if (flags & F_PE) {
                    int pos = grow & (S_LEN - 1);
                    float div = expf((float)(col & ~1) * (-9.210340371976184f / 256.0f));
                    float ang = (float)pos * div;
                    v += (col & 1) ? cosf(ang) : sinf(ang);
                }
                if (flags & F_GELU) v = gelu_f(v);
                if (out32) out32[(size_t)grow * ldc + col] = v;
                if (out16) out16[(size_t)grow * ldc + col] = f2bf(v);
            }
        }
    }
}

// Banded attention, bf16 in/out. qkv: (B*S, 768) per scale; o -> ocat (B*S,1024) slice si
__global__ __launch_bounds__(64) void attn_kernel(
    const ushortT* __restrict__ qkv, ushortT* __restrict__ ocat, int radius, int si)
{
    __shared__ float sp[128];
    const int idx = blockIdx.x;
    const int q = idx & (S_LEN - 1);
    const int h = (idx >> 9) & (NHEAD - 1);
    const int b = idx >> 12;
    const int lane = threadIdx.x;

    const int k0 = max(0, q - radius);
    const int k1 = min(S_LEN - 1, q + radius);
    const int Wd = k1 - k0 + 1;   // <= 101

    const ushortT* base = qkv + (size_t)(b * S_LEN) * 768;
    const uintT* qrow = (const uintT*)(base + (size_t)q * 768 + h * HDIM);
    float qv[HDIM];
    #pragma unroll
    for (int t = 0; t < 16; ++t) {
        uintT u = qrow[t];
        qv[2 * t] = bf2f((ushortT)(u & 0xffff));
        qv[2 * t + 1] = bf2f((ushortT)(u >> 16));
    }

    float lmax = -1e30f;
    for (int j = lane; j < Wd; j += 64) {
        const uintT* kr = (const uintT*)(base + (size_t)(k0 + j) * 768 + 256 + h * HDIM);
        float d = 0.f;
        #pragma unroll
        for (int t = 0; t < 16; ++t) {
            uintT u = kr[t];
            d = fmaf(qv[2 * t], bf2f((ushortT)(u & 0xffff)), d);
            d = fmaf(qv[2 * t + 1], bf2f((ushortT)(u >> 16)), d);
        }
        d *= 0.17677669529663688f;
        sp[j] = d;
        lmax = fmaxf(lmax, d);
    }
    #pragma unroll
    for (int off = 32; off; off >>= 1) lmax = fmaxf(lmax, __shfl_xor(lmax, off, 64));

    float lsum = 0.f;
    for (int j = lane; j < Wd; j += 64) {
        float p = expf(sp[j] - lmax);
        sp[j] = p;
        lsum += p;
    }
    #pragma unroll
    for (int off = 32; off; off >>= 1) lsum += __shfl_xor(lsum, off, 64);
    float inv = 1.0f / lsum;
    __syncthreads();

    const int d = lane & 31;
    const int half = lane >> 5;
    float acc = 0.f;
    for (int j = half; j < Wd; j += 2) {
        const ushortT* vr = base + (size_t)(k0 + j) * 768 + 512 + h * HDIM;
        acc = fmaf(sp[j], bf2f(vr[d]), acc);
    }
    acc += __shfl_down(acc, 32, 64);
    if (lane < 32)
        ocat[((size_t)(b * S_LEN) + q) * 1024 + si * DMODEL + h * HDIM + d] = f2bf(acc * inv);
}

// one wave per 256-wide row: out = LN(a (+b2)) * g + be (+gelu); dual fp32/bf16 write
__global__ __launch_bounds__(64) void ln_wave(
    const float* __restrict__ a, const float* __restrict__ b2,
    const float* __restrict__ g, const float* __restrict__ be,
    float* __restrict__ o32, ushortT* __restrict__ o16, int dogelu)
{
    const int row = blockIdx.x, lane = threadIdx.x;
    float4 v = *(const float4*)(a + (size_t)row * DMODEL + lane * 4);
    if (b2) {
        float4 w = *(const float4*)(b2 + (size_t)row * DMODEL + lane * 4);
        v.x += w.x; v.y += w.y; v.z += w.z; v.w += w.w;
    }
    float s = v.x + v.y + v.z + v.w;
    #pragma unroll
    for (int off = 32; off; off >>= 1) s += __shfl_xor(s, off, 64);
    float m = s * (1.0f / DMODEL);
    float dx = v.x - m, dy = v.y - m, dz = v.z - m, dw = v.w - m;
    float s2 = dx * dx + dy * dy + dz * dz + dw * dw;
    #pragma unroll
    for (int off = 32; off; off >>= 1) s2 += __shfl_xor(s2, off, 64);
    float r = rsqrtf(s2 * (1.0f / DMODEL) + 1e-5f);
    float4 gg = *(const float4*)(g + lane * 4);
    float4 bb = *(const float4*)(be + lane * 4);
    float y0 = dx * r * gg.x + bb.x, y1 = dy * r * gg.y + bb.y;
    float y2 = dz * r * gg.z + bb.z, y3 = dw * r * gg.w + bb.w;
    if (dogelu) { y0 = gelu_f(y0); y1 = gelu_f(y1); y2 = gelu_f(y2); y3 = gelu_f(y3); }
    if (o32) *(float4*)(o32 + (size_t)row * DMODEL + lane * 4) = make_float4(y0, y1, y2, y3);
    if (o16) {
        ushort4 u; u.x = f2bf(y0); u.y = f2bf(y1); u.z = f2bf(y2); u.w = f2bf(y3);
        *(ushort4*)(o16 + (size_t)row * DMODEL + lane * 4) = u;
    }
}

// tiny-M fp32 GEMM for the head (M<=16)
__global__ __launch_bounds__(256) void smallmm(
    const float* __restrict__ A, int lda, const float* __restrict__ W, int ldw,
    const float* __restrict__ bias, float* __restrict__ C, int ldc,
    int M, int N, int K, int flags)
{
    int n = blockIdx.x * 16 + (threadIdx.x & 15);
    int i = threadIdx.x >> 4;
    if (i >= M || n >= N) return;
    float s = bias ? bias[n] : 0.f;
    const float* a = A + (size_t)i * lda;
    const float* w = W + (size_t)n * ldw;
    for (int k = 0; k < K; ++k) s = fmaf(a[k], w[k], s);
    if (flags & F_BETA) s += C[(size_t)i * ldc + n];
    if (flags & F_GELU) s = gelu_f(s);
    C[(size_t)i * ldc + n] = s;
}

__global__ __launch_bounds__(256) void cvt_kernel(
    const float4* __restrict__ src, ushort4* __restrict__ dst, int n4)
{
    int i = blockIdx.x * 256 + threadIdx.x;
    if (i < n4) {
        float4 f = src[i];
        ushort4 u; u.x = f2bf(f.x); u.y = f2bf(f.y); u.z = f2bf(f.z); u.w = f2bf(f.w);
        dst[i] = u;
    }
}

// Wcat[l][n][si*256+d] = sum_j fus_w[l][n][si*256+j] * attn_out_w[l][si][j][d]
__global__ __launch_bounds__(256) void wc_kernel(
    const float* __restrict__ fus_w, const float* __restrict__ ao_w, ushortT* __restrict__ Wcat)
{
    int bid = blockIdx.x;             // 4096
    int n = bid & 255, ls = bid >> 8;
    int l = ls >> 2, si = ls & 3;
    int d = threadIdx.x;
    const float* fw = fus_w + ((size_t)l * 256 + n) * 1024 + si * 256;
    const float* ao = ao_w + (size_t)ls * 65536 + d;
    float s = 0.f;
    for (int j = 0; j < 256; ++j) s = fmaf(fw[j], ao[(size_t)j * 256], s);
    Wcat[((size_t)l * 256 + n) * 1024 + si * 256 + d] = f2bf(s);
}

// eff qkv bias: eb[i] = attn_in_b[i] + dot(scale_emb[si], attn_in_w_row[i]); i over 4*4*768
__global__ __launch_bounds__(256) void qkvbias_kernel(
    const float* __restrict__ aib, const float* __restrict__ aiw,
    const float* __restrict__ se, float* __restrict__ eb)
{
    int i = blockIdx.x * 256 + threadIdx.x;   // < 12288
    int r = i % 3072, si = r / 768;
    const float* w = aiw + (size_t)i * 256;
    const float* s = se + si * 256;
    float acc = aib[i];
    for (int k = 0; k < 256; ++k) acc = fmaf(s[k], w[k], acc);
    eb[i] = acc;
}

// fb[l][n] = fus_b[l][n] + sum_j attn_out_b_cat[l][j] * fus_w[l][n][j]
__global__ __launch_bounds__(256) void fusbias_kernel(
    const float* __restrict__ fus_b, const float* __restrict__ fus_w,
    const float* __restrict__ aob, float* __restrict__ fb)
{
    int l = blockIdx.x, n = threadIdx.x;
    const float* w = fus_w + ((size_t)l * 256 + n) * 1024;
    const float* o = aob + (size_t)l * 1024;
    float acc = fus_b[l * 256 + n];
    for (int j = 0; j < 1024; ++j) acc = fmaf(o[j], w[j], acc);
    fb[l * 256 + n] = acc;
}

static inline void mgemm(hipStream_t s, const ushortT* A, int lda, const ushortT* W, int ldw,
                         const float* bias, const float* betaC, float* o32, ushortT* o16,
                         int ldc, int M, int N, int K, int flags)
{
    if (N >= 768) {
        dim3 g(M / 128, N / 128);
        hipLaunchKernelGGL(mfma_gemm<128>, g, dim3(256), 0, s,
                           A, lda, W, ldw, bias, betaC, o32, o16, ldc, K, flags);
    } else {
        dim3 g(M / 128, N / 64);
        hipLaunchKernelGGL(mfma_gemm<64>, g, dim3(256), 0, s,
                           A, lda, W, ldw, bias, betaC, o32, o16, ldc, K, flags);
    }
}

static inline void cvt(hipStream_t s, const float* src, ushortT* dst, size_t n)
{
    int n4 = (int)(n / 4);
    hipLaunchKernelGGL(cvt_kernel, dim3((n4 + 255) / 256), dim3(256), 0, s,
                       (const float4*)src, (ushort4*)dst, n4);
}

extern "C" void kernel_launch(void* const* d_in, const int* in_sizes, int n_in,
                              void* d_out, int out_size, void* d_ws, size_t ws_size,
                              hipStream_t stream)
{
    const float* emb        = (const float*)d_in[0];
    const float* features   = (const float*)d_in[1];
    const float* ip_w       = (const float*)d_in[2];
    const float* ip_b       = (const float*)d_in[3];
    const float* scale_emb  = (const float*)d_in[4];
    const float* attn_in_w  = (const float*)d_in[5];
    const float* attn_in_b  = (const float*)d_in[6];
    const float* attn_out_w = (const float*)d_in[7];
    const float* attn_out_b = (const float*)d_in[8];
    const float* fus_w      = (const float*)d_in[9];
    const float* fus_b      = (const float*)d_in[10];
    const float* ffn_w1     = (const float*)d_in[11];
    const float* ffn_b1     = (const float*)d_in[12];
    const float* ffn_w2     = (const float*)d_in[13];
    const float* ffn_b2     = (const float*)d_in[14];
    const float* n1_g       = (const float*)d_in[15];
    const float* n1_b       = (const float*)d_in[16];
    const float* n2_g       = (const float*)d_in[17];
    const float* n2_b       = (const float*)d_in[18];
    const float* feat_w     = (const float*)d_in[19];
    const float* feat_b     = (const float*)d_in[20];
    const float* feat_ln_g  = (const float*)d_in[21];
    const float* feat_ln_b  = (const float*)d_in[22];
    const float* h1_w       = (const float*)d_in[23];
    const float* h1_b       = (const float*)d_in[24];
    const float* h_ln_g     = (const float*)d_in[25];
    const float* h_ln_b     = (const float*)d_in[26];
    const float* h2_w       = (const float*)d_in[27];
    const float* h2_b       = (const float*)d_in[28];
    const float* h3_w       = (const float*)d_in[29];
    const float* h3_b       = (const float*)d_in[30];
    float* outp = (float*)d_out;

    const int Btok = 16 * S_LEN;   // 8192

    // ---- workspace carve-up ----
    char* p = (char*)d_ws;
    float* x32     = (float*)p;              p += (size_t)Btok * DMODEL * 4;   // 8.39MB
    float* fused32 = (float*)p;              p += (size_t)Btok * DMODEL * 4;   // 8.39MB
    float* effqkvb = (float*)p;              p += 12288 * 4;
    float* fusbias = (float*)p;              p += 1024 * 4;
    float* frbuf   = (float*)p;              p += 16 * DMODEL * 4;
    float* h1buf   = (float*)p;              p += 16 * DMODEL * 4;
    float* h2buf   = (float*)p;              p += 16 * 128 * 4;
    ushortT* xbf   = (ushortT*)p;            p += (size_t)Btok * DMODEL * 2;   // 4.19MB
    ushortT* bigb  = (ushortT*)p;            p += (size_t)Btok * 768 * 2;      // 12.58MB (qkv / emb_bf)
    ushortT* ocat  = (ushortT*)p;            p += (size_t)Btok * 1024 * 2;     // 16.78MB (ocat / ffn mid)
    ushortT* ipw_bf  = (ushortT*)p;          p += (size_t)DMODEL * 640 * 2;
    ushortT* aiw_bf  = (ushortT*)p;          p += (size_t)16 * 768 * 256 * 2;
    ushortT* wcat_bf = (ushortT*)p;          p += (size_t)4 * 256 * 1024 * 2;
    ushortT* f1_bf   = (ushortT*)p;          p += (size_t)4 * 1024 * 256 * 2;
    ushortT* f2_bf   = (ushortT*)p;          p += (size_t)4 * 256 * 1024 * 2;
    ushortT* embbf = bigb;                   // alias: emb_bf dead before layer-0 qkv
    ushortT* midbf = ocat;                   // alias: ffn mid after ocat consumed

    static const int SCALES[NSCALE] = {5, 10, 20, 50};

    // ---- precompute: conversions + folded weights/biases ----
    cvt(stream, emb, embbf, (size_t)Btok * 640);
    cvt(stream, ip_w, ipw_bf, (size_t)DMODEL * 640);
    cvt(stream, attn_in_w, aiw_bf, (size_t)16 * 768 * 256);
    cvt(stream, ffn_w1, f1_bf, (size_t)4 * 1024 * 256);
    cvt(stream, ffn_w2, f2_bf, (size_t)4 * 256 * 1024);
    hipLaunchKernelGGL(wc_kernel, dim3(4096), dim3(256), 0, stream, fus_w, attn_out_w, wcat_bf);
    hipLaunchKernelGGL(qkvbias_kernel, dim3(48), dim3(256), 0, stream,
                       attn_in_b, attn_in_w, scale_emb, effqkvb);
    hipLaunchKernelGGL(fusbias_kernel, dim3(4), dim3(256), 0, stream,
                       fus_b, fus_w, attn_out_b, fusbias);

    // ---- x = emb @ ip_w^T + ip_b + PE  (dual fp32/bf16) ----
    mgemm(stream, embbf, 640, ipw_bf, 640, ip_b, nullptr, x32, xbf,
          DMODEL, Btok, DMODEL, 640, F_PE);

    for (int l = 0; l < NLAYER; ++l) {
        for (int si = 0; si < NSCALE; ++si) {
            const int ls = l * NSCALE + si;
            // qkv = x @ W^T + effbias  -> bigb (bf16)
            mgemm(stream, xbf, DMODEL, aiw_bf + (size_t)ls * 768 * 256, DMODEL,
                  effqkvb + (size_t)ls * 768, nullptr, nullptr, bigb,
                  768, Btok, 768, DMODEL, 0);
            hipLaunchKernelGGL(attn_kernel, dim3(Btok * NHEAD), dim3(64), 0, stream,
                               bigb, ocat, SCALES[si], si);
        }
        // fused = ocat @ Wcat[l]^T + fusbias[l]   (fp32 out)
        mgemm(stream, ocat, 1024, wcat_bf + (size_t)l * 256 * 1024, 1024,
              fusbias + l * DMODEL, nullptr, fused32, nullptr,
              DMODEL, Btok, DMODEL, 1024, 0);
        // x = LN(x + fused)  (dual write)
        hipLaunchKernelGGL(ln_wave, dim3(Btok), dim3(64), 0, stream,
                           x32, fused32, n1_g + l * DMODEL, n1_b + l * DMODEL, x32, xbf, 0);
        // mid = gelu(x @ ffn1^T + b1) -> bf16 (reuses ocat region)
        mgemm(stream, xbf, DMODEL, f1_bf + (size_t)l * 1024 * 256, DMODEL,
              ffn_b1 + (size_t)l * 1024, nullptr, nullptr, midbf,
              1024, Btok, 1024, DMODEL, F_GELU);
        // f = mid @ ffn2^T + b2 -> fp32 (reuses fused32)
        mgemm(stream, midbf, 1024, f2_bf + (size_t)l * 256 * 1024, 1024,
              ffn_b2 + (size_t)l * DMODEL, nullptr, fused32, nullptr,
              DMODEL, Btok, DMODEL, 1024, 0);
        // x = LN(x + f)
        hipLaunchKernelGGL(ln_wave, dim3(Btok), dim3(64), 0, stream,
                           x32, fused32, n2_g + l * DMODEL, n2_b + l * DMODEL, x32, xbf, 0);
    }

    // ---- head (tiny, fp32) ----
    hipLaunchKernelGGL(smallmm, dim3(16), dim3(256), 0, stream,
                       features, 66, feat_w, 66, feat_b, frbuf, DMODEL, 16, DMODEL, 66, 0);
    hipLaunchKernelGGL(ln_wave, dim3(16), dim3(64), 0, stream,
                       frbuf, nullptr, feat_ln_g, feat_ln_b, frbuf, nullptr, 1);
    hipLaunchKernelGGL(smallmm, dim3(16), dim3(256), 0, stream,
                       x32 + (size_t)(S_LEN / 2) * DMODEL, S_LEN * DMODEL,
                       h1_w, 512, h1_b, h1buf, DMODEL, 16, DMODEL, DMODEL, 0);
    hipLaunchKernelGGL(smallmm, dim3(16), dim3(256), 0, stream,
                       frbuf, DMODEL, h1_w + 256, 512, nullptr, h1buf, DMODEL,
                       16, DMODEL, DMODEL, F_BETA);
    hipLaunchKernelGGL(ln_wave, dim3(16), dim3(64), 0, stream,
                       h1buf, nullptr, h_ln_g, h_ln_b, h1buf, nullptr, 1);
    hipLaunchKernelGGL(smallmm, dim3(8), dim3(256), 0, stream,
                       h1buf, DMODEL, h2_w, DMODEL, h2_b, h2buf, 128, 16, 128, DMODEL, F_GELU);
    hipLaunchKernelGGL(smallmm, dim3(1), dim3(256), 0, stream,
                       h2buf, 128, h3_w, 128, h3_b, outp, 1, 16, 1, 128, 0);
}

// Round 3
// 1672.166 us; speedup vs baseline: 4.0512x; 1.2139x over previous
//
#include <hip/hip_runtime.h>
#include <math.h>

#define S_LEN 512
#define DMODEL 256
#define NHEAD 8
#define HDIM 32
#define NLAYER 4
#define NSCALE 4

typedef unsigned short ushortT;
typedef unsigned int uintT;
typedef short bf16x8 __attribute__((ext_vector_type(8)));
typedef float f32x4 __attribute__((ext_vector_type(4)));

enum { F_PE = 1, F_BETA = 2, F_GELU = 4 };

__device__ __forceinline__ float gelu_f(float x) {
    return 0.5f * x * (1.0f + erff(x * 0.70710678118654752440f));
}
__device__ __forceinline__ ushortT f2bf(float f) {
    union { float f; uintT i; } u; u.f = f;
    uintT r = u.i + 0x7FFF + ((u.i >> 16) & 1);   // RNE
    return (ushortT)(r >> 16);
}
__device__ __forceinline__ float bf2f(ushortT s) {
    union { uintT i; float f; } u; u.i = ((uintT)s) << 16;
    return u.f;
}
// bf16 pair packed in a dword -> two fp32 (low elem = bits 15:0, high = 31:16)
__device__ __forceinline__ void unpack2(uintT u, float& lo, float& hi) {
    union { uintT i; float f; } a, b;
    a.i = u << 16; b.i = u & 0xffff0000u;
    lo = a.f; hi = b.f;
}
__device__ __forceinline__ int swz(int r) { return (r & 3) ^ ((r >> 2) & 3); }

#define GLD16(g, l) \
    __builtin_amdgcn_global_load_lds((const __attribute__((address_space(1))) void*)(g), \
                                     (__attribute__((address_space(3))) void*)(l), 16, 0, 0)

// C[M,N] = op(A[M,K]bf16 @ W[N,K]bf16^T + bias) ; M%128==0, N%BN==0, K%32==0
template<int BN>
__global__ __launch_bounds__(256) void mfma_gemm(
    const ushortT* __restrict__ A, int lda,
    const ushortT* __restrict__ W, int ldw,
    const float* __restrict__ bias,
    const float* __restrict__ betaC,
    float* __restrict__ out32,
    ushortT* __restrict__ out16,
    int ldc, int K, int flags)
{
    constexpr int NI = BN / 32;
    __shared__ __align__(16) ushortT As[128 * 32];
    __shared__ __align__(16) ushortT Bs[BN * 32];
    const int tid = threadIdx.x;
    const int wave = tid >> 6, lane = tid & 63;
    const int l15 = lane & 15, qd = lane >> 4;
    const int m0 = blockIdx.x * 128, n0 = blockIdx.y * BN;
    const int wm = (wave >> 1) * 64, wn = (wave & 1) * (BN / 2);

    f32x4 acc[4][NI];
    #pragma unroll
    for (int i = 0; i < 4; ++i)
        #pragma unroll
        for (int j = 0; j < NI; ++j) acc[i][j] = (f32x4){0.f, 0.f, 0.f, 0.f};

    for (int k0 = 0; k0 < K; k0 += 32) {
        #pragma unroll
        for (int it = 0; it < 2; ++it) {
            int c = it * 256 + tid;
            int m = c >> 2, s = c & 3;
            int kc = s ^ swz(m);
            const ushortT* g = A + (size_t)(m0 + m) * lda + k0 + kc * 8;
            GLD16(g, (ushortT*)As + (size_t)(it * 256 + wave * 64) * 8);
        }
        #pragma unroll
        for (int it = 0; it < BN / 64; ++it) {
            int c = it * 256 + tid;
            int n = c >> 2, s = c & 3;
            int kc = s ^ swz(n);
            const ushortT* g = W + (size_t)(n0 + n) * ldw + k0 + kc * 8;
            GLD16(g, (ushortT*)Bs + (size_t)(it * 256 + wave * 64) * 8);
        }
        __syncthreads();
        bf16x8 af[4], bfr[NI];
        #pragma unroll
        for (int mi = 0; mi < 4; ++mi) {
            int r = wm + mi * 16 + l15;
            af[mi] = *(const bf16x8*)(As + r * 32 + (qd ^ swz(r)) * 8);
        }
        #pragma unroll
        for (int ni = 0; ni < NI; ++ni) {
            int r = wn + ni * 16 + l15;
            bfr[ni] = *(const bf16x8*)(Bs + r * 32 + (qd ^ swz(r)) * 8);
        }
        #pragma unroll
        for (int mi = 0; mi < 4; ++mi)
            #pragma unroll
            for (int ni = 0; ni < NI; ++ni)
                acc[mi][ni] = __builtin_amdgcn_mfma_f32_16x16x32_bf16(
                    af[mi], bfr[ni], acc[mi][ni], 0, 0, 0);
        __syncthreads();
    }

    #pragma unroll
    for (int mi = 0; mi < 4; ++mi) {
        #pragma unroll
        for (int ni = 0; ni < NI; ++ni) {
            int col = n0 + wn + ni * 16 + l15;
            float bv = bias ? bias[col] : 0.f;
            #pragma unroll
            for (int r = 0; r < 4; ++r) {
                int grow = m0 + wm + mi * 16 + qd * 4 + r;
                float v = acc[mi][ni][r] + bv;
                if (flags & F_BETA) v += betaC[(size_t)grow * ldc + col];
                if (flags & F_PE) {
                    int pos = grow & (S_LEN - 1);
                    float div = expf((float)(col & ~1) * (-9.210340371976184f / 256.0f));
                    float ang = (float)pos * div;
                    v += (col & 1) ? cosf(ang) : sinf(ang);
                }
                if (flags & F_GELU) v = gelu_f(v);
                if (out32) out32[(size_t)grow * ldc + col] = v;
                if (out16) out16[(size_t)grow * ldc + col] = f2bf(v);
            }
        }
    }
}

// Banded attention, q-per-lane, K/V staged in LDS.
// qkv: (B*S, 1536) holding a PAIR of scales (local col 0 / 768), each 768 = q|k|v * 256.
// Block = 128 thr (2 waves) for (pairslot, b, h, 128-q chunk). Writes ocat (B*S,1024).
__global__ __launch_bounds__(128) void attn_kernel(
    const ushortT* __restrict__ qkv, ushortT* __restrict__ ocat,
    int si0, int r0, int si1, int r1)
{
    __shared__ __align__(16) ushortT Ks[232 * 32];
    __shared__ __align__(16) ushortT Vs[232 * 32];
    const int bid = blockIdx.x;
    const int qc = bid & 3, h = (bid >> 2) & 7, b = (bid >> 5) & 15, sp = bid >> 9;
    const int si = sp ? si1 : si0;
    const int r  = sp ? r1 : r0;
    const int lcol = sp * 768;
    const int tid = threadIdx.x;

    const int q0 = qc * 128;
    const int kb0 = max(0, q0 - r);
    const int kb1 = min(S_LEN - 1, q0 + 127 + r);
    const int cnt = kb1 - kb0 + 1;           // <= 229

    const ushortT* base = qkv + (size_t)(b * S_LEN) * 1536;

    for (int idx = tid; idx < cnt * 4; idx += 128) {
        int row = idx >> 2, ch = (idx & 3) * 8;
        const ushortT* rbase = base + (size_t)(kb0 + row) * 1536 + lcol + h * HDIM;
        *(uint4*)&Ks[row * 32 + ch] = *(const uint4*)(rbase + 256 + ch);
        *(uint4*)&Vs[row * 32 + ch] = *(const uint4*)(rbase + 512 + ch);
    }
    __syncthreads();

    const int wid = tid >> 6, lane = tid & 63;
    const int q0w = q0 + wid * 64;
    const int q = q0w + lane;

    float qv[32];
    {
        const ushortT* qp = base + (size_t)q * 1536 + lcol + h * HDIM;
        #pragma unroll
        for (int c = 0; c < 4; ++c) {
            uint4 u = *(const uint4*)(qp + c * 8);
            uintT w[4] = {u.x, u.y, u.z, u.w};
            #pragma unroll
            for (int t = 0; t < 4; ++t)
                unpack2(w[t], qv[c * 8 + 2 * t], qv[c * 8 + 2 * t + 1]);
        }
    }

    float o[32];
    #pragma unroll
    for (int j = 0; j < 32; ++j) o[j] = 0.f;
    float l = 0.f;

    const int kw0 = max(0, q0w - r);
    const int kw1 = min(S_LEN - 1, q0w + 63 + r);
    const unsigned span = (unsigned)(2 * r);

    for (int k = kw0; k <= kw1; ++k) {
        const ushortT* kp = &Ks[(k - kb0) * 32];
        float s = 0.f;
        #pragma unroll
        for (int c = 0; c < 4; ++c) {
            uint4 u = *(const uint4*)(kp + c * 8);
            uintT w[4] = {u.x, u.y, u.z, u.w};
            #pragma unroll
            for (int t = 0; t < 4; ++t) {
                float lo, hi; unpack2(w[t], lo, hi);
                s = fmaf(qv[c * 8 + 2 * t], lo, s);
                s = fmaf(qv[c * 8 + 2 * t + 1], hi, s);
            }
        }
        s *= 0.17677669529663688f;
        unsigned dd = (unsigned)(k - q + r);
        float p = (dd <= span) ? __expf(fminf(s, 80.f)) : 0.f;
        l += p;
        const ushortT* vp = &Vs[(k - kb0) * 32];
        #pragma unroll
        for (int c = 0; c < 4; ++c) {
            uint4 u = *(const uint4*)(vp + c * 8);
            uintT w[4] = {u.x, u.y, u.z, u.w};
            #pragma unroll
            for (int t = 0; t < 4; ++t) {
                float lo, hi; unpack2(w[t], lo, hi);
                o[c * 8 + 2 * t]     = fmaf(p, lo, o[c * 8 + 2 * t]);
                o[c * 8 + 2 * t + 1] = fmaf(p, hi, o[c * 8 + 2 * t + 1]);
            }
        }
    }

    float inv = 1.0f / l;
    uintT outw[16];
    #pragma unroll
    for (int j = 0; j < 16; ++j)
        outw[j] = (uintT)f2bf(o[2 * j] * inv) | ((uintT)f2bf(o[2 * j + 1] * inv) << 16);
    ushortT* op = ocat + ((size_t)(b * S_LEN) + q) * 1024 + si * 256 + h * HDIM;
    #pragma unroll
    for (int c = 0; c < 4; ++c)
        *(uint4*)(op + c * 8) = ((const uint4*)outw)[c];
}

// one wave per 256-wide row: out = LN(a (+b2)) * g + be (+gelu); dual fp32/bf16 write
__global__ __launch_bounds__(64) void ln_wave(
    const float* __restrict__ a, const float* __restrict__ b2,
    const float* __restrict__ g, const float* __restrict__ be,
    float* __restrict__ o32, ushortT* __restrict__ o16, int dogelu)
{
    const int row = blockIdx.x, lane = threadIdx.x;
    float4 v = *(const float4*)(a + (size_t)row * DMODEL + lane * 4);
    if (b2) {
        float4 w = *(const float4*)(b2 + (size_t)row * DMODEL + lane * 4);
        v.x += w.x; v.y += w.y; v.z += w.z; v.w += w.w;
    }
    float s = v.x + v.y + v.z + v.w;
    #pragma unroll
    for (int off = 32; off; off >>= 1) s += __shfl_xor(s, off, 64);
    float m = s * (1.0f / DMODEL);
    float dx = v.x - m, dy = v.y - m, dz = v.z - m, dw = v.w - m;
    float s2 = dx * dx + dy * dy + dz * dz + dw * dw;
    #pragma unroll
    for (int off = 32; off; off >>= 1) s2 += __shfl_xor(s2, off, 64);
    float r = rsqrtf(s2 * (1.0f / DMODEL) + 1e-5f);
    float4 gg = *(const float4*)(g + lane * 4);
    float4 bb = *(const float4*)(be + lane * 4);
    float y0 = dx * r * gg.x + bb.x, y1 = dy * r * gg.y + bb.y;
    float y2 = dz * r * gg.z + bb.z, y3 = dw * r * gg.w + bb.w;
    if (dogelu) { y0 = gelu_f(y0); y1 = gelu_f(y1); y2 = gelu_f(y2); y3 = gelu_f(y3); }
    if (o32) *(float4*)(o32 + (size_t)row * DMODEL + lane * 4) = make_float4(y0, y1, y2, y3);
    if (o16) {
        ushort4 u; u.x = f2bf(y0); u.y = f2bf(y1); u.z = f2bf(y2); u.w = f2bf(y3);
        *(ushort4*)(o16 + (size_t)row * DMODEL + lane * 4) = u;
    }
}

// tiny-M fp32 GEMM for the head (M<=16)
__global__ __launch_bounds__(256) void smallmm(
    const float* __restrict__ A, int lda, const float* __restrict__ W, int ldw,
    const float* __restrict__ bias, float* __restrict__ C, int ldc,
    int M, int N, int K, int flags)
{
    int n = blockIdx.x * 16 + (threadIdx.x & 15);
    int i = threadIdx.x >> 4;
    if (i >= M || n >= N) return;
    float s = bias ? bias[n] : 0.f;
    const float* a = A + (size_t)i * lda;
    const float* w = W + (size_t)n * ldw;
    for (int k = 0; k < K; ++k) s = fmaf(a[k], w[k], s);
    if (flags & F_BETA) s += C[(size_t)i * ldc + n];
    if (flags & F_GELU) s = gelu_f(s);
    C[(size_t)i * ldc + n] = s;
}

__global__ __launch_bounds__(256) void cvt_kernel(
    const float4* __restrict__ src, ushort4* __restrict__ dst, int n4)
{
    int i = blockIdx.x * 256 + threadIdx.x;
    if (i < n4) {
        float4 f = src[i];
        ushort4 u; u.x = f2bf(f.x); u.y = f2bf(f.y); u.z = f2bf(f.z); u.w = f2bf(f.w);
        dst[i] = u;
    }
}

// Wcat[l][n][si*256+d] = sum_j fus_w[l][n][si*256+j] * attn_out_w[l][si][j][d]
__global__ __launch_bounds__(256) void wc_kernel(
    const float* __restrict__ fus_w, const float* __restrict__ ao_w, ushortT* __restrict__ Wcat)
{
    int bid = blockIdx.x;
    int n = bid & 255, ls = bid >> 8;
    int l = ls >> 2, si = ls & 3;
    int d = threadIdx.x;
    const float* fw = fus_w + ((size_t)l * 256 + n) * 1024 + si * 256;
    const float* ao = ao_w + (size_t)ls * 65536 + d;
    float s = 0.f;
    for (int j = 0; j < 256; ++j) s = fmaf(fw[j], ao[(size_t)j * 256], s);
    Wcat[((size_t)l * 256 + n) * 1024 + si * 256 + d] = f2bf(s);
}

__global__ __launch_bounds__(256) void qkvbias_kernel(
    const float* __restrict__ aib, const float* __restrict__ aiw,
    const float* __restrict__ se, float* __restrict__ eb)
{
    int i = blockIdx.x * 256 + threadIdx.x;   // < 12288
    int r = i % 3072, si = r / 768;
    const float* w = aiw + (size_t)i * 256;
    const float* s = se + si * 256;
    float acc = aib[i];
    for (int k = 0; k < 256; ++k) acc = fmaf(s[k], w[k], acc);
    eb[i] = acc;
}

__global__ __launch_bounds__(256) void fusbias_kernel(
    const float* __restrict__ fus_b, const float* __restrict__ fus_w,
    const float* __restrict__ aob, float* __restrict__ fb)
{
    int l = blockIdx.x, n = threadIdx.x;
    const float* w = fus_w + ((size_t)l * 256 + n) * 1024;
    const float* o = aob + (size_t)l * 1024;
    float acc = fus_b[l * 256 + n];
    for (int j = 0; j < 1024; ++j) acc = fmaf(o[j], w[j], acc);
    fb[l * 256 + n] = acc;
}

static inline void mgemm(hipStream_t s, const ushortT* A, int lda, const ushortT* W, int ldw,
                         const float* bias, const float* betaC, float* o32, ushortT* o16,
                         int ldc, int M, int N, int K, int flags)
{
    if (N % 128 == 0) {
        dim3 g(M / 128, N / 128);
        hipLaunchKernelGGL(mfma_gemm<128>, g, dim3(256), 0, s,
                           A, lda, W, ldw, bias, betaC, o32, o16, ldc, K, flags);
    } else {
        dim3 g(M / 128, N / 64);
        hipLaunchKernelGGL(mfma_gemm<64>, g, dim3(256), 0, s,
                           A, lda, W, ldw, bias, betaC, o32, o16, ldc, K, flags);
    }
}

static inline void cvt(hipStream_t s, const float* src, ushortT* dst, size_t n)
{
    int n4 = (int)(n / 4);
    hipLaunchKernelGGL(cvt_kernel, dim3((n4 + 255) / 256), dim3(256), 0, s,
                       (const float4*)src, (ushort4*)dst, n4);
}

extern "C" void kernel_launch(void* const* d_in, const int* in_sizes, int n_in,
                              void* d_out, int out_size, void* d_ws, size_t ws_size,
                              hipStream_t stream)
{
    const float* emb        = (const float*)d_in[0];
    const float* features   = (const float*)d_in[1];
    const float* ip_w       = (const float*)d_in[2];
    const float* ip_b       = (const float*)d_in[3];
    const float* scale_emb  = (const float*)d_in[4];
    const float* attn_in_w  = (const float*)d_in[5];
    const float* attn_in_b  = (const float*)d_in[6];
    const float* attn_out_w = (const float*)d_in[7];
    const float* attn_out_b = (const float*)d_in[8];
    const float* fus_w      = (const float*)d_in[9];
    const float* fus_b      = (const float*)d_in[10];
    const float* ffn_w1     = (const float*)d_in[11];
    const float* ffn_b1     = (const float*)d_in[12];
    const float* ffn_w2     = (const float*)d_in[13];
    const float* ffn_b2     = (const float*)d_in[14];
    const float* n1_g       = (const float*)d_in[15];
    const float* n1_b       = (const float*)d_in[16];
    const float* n2_g       = (const float*)d_in[17];
    const float* n2_b       = (const float*)d_in[18];
    const float* feat_w     = (const float*)d_in[19];
    const float* feat_b     = (const float*)d_in[20];
    const float* feat_ln_g  = (const float*)d_in[21];
    const float* feat_ln_b  = (const float*)d_in[22];
    const float* h1_w       = (const float*)d_in[23];
    const float* h1_b       = (const float*)d_in[24];
    const float* h_ln_g     = (const float*)d_in[25];
    const float* h_ln_b     = (const float*)d_in[26];
    const float* h2_w       = (const float*)d_in[27];
    const float* h2_b       = (const float*)d_in[28];
    const float* h3_w       = (const float*)d_in[29];
    const float* h3_b       = (const float*)d_in[30];
    float* outp = (float*)d_out;

    const int Btok = 16 * S_LEN;   // 8192

    // ---- workspace carve-up ----
    char* p = (char*)d_ws;
    float* x32     = (float*)p;              p += (size_t)Btok * DMODEL * 4;
    float* fused32 = (float*)p;              p += (size_t)Btok * DMODEL * 4;
    float* effqkvb = (float*)p;              p += 12288 * 4;
    float* fusbias = (float*)p;              p += 1024 * 4;
    float* frbuf   = (float*)p;              p += 16 * DMODEL * 4;
    float* h1buf   = (float*)p;              p += 16 * DMODEL * 4;
    float* h2buf   = (float*)p;              p += 16 * 128 * 4;
    ushortT* xbf   = (ushortT*)p;            p += (size_t)Btok * DMODEL * 2;
    ushortT* qkv2  = (ushortT*)p;            p += (size_t)Btok * 1536 * 2;   // pair buffer
    ushortT* ocat  = (ushortT*)p;            p += (size_t)Btok * 1024 * 2;
    ushortT* ipw_bf  = (ushortT*)p;          p += (size_t)DMODEL * 640 * 2;
    ushortT* aiw_bf  = (ushortT*)p;          p += (size_t)16 * 768 * 256 * 2;
    ushortT* wcat_bf = (ushortT*)p;          p += (size_t)4 * 256 * 1024 * 2;
    ushortT* f1_bf   = (ushortT*)p;          p += (size_t)4 * 1024 * 256 * 2;
    ushortT* f2_bf   = (ushortT*)p;          p += (size_t)4 * 256 * 1024 * 2;
    ushortT* embbf = qkv2;                   // alias: emb_bf dead before layer-0 qkv
    ushortT* midbf = ocat;                   // alias: ffn mid after ocat consumed

    // ---- precompute ----
    cvt(stream, emb, embbf, (size_t)Btok * 640);
    cvt(stream, ip_w, ipw_bf, (size_t)DMODEL * 640);
    cvt(stream, attn_in_w, aiw_bf, (size_t)16 * 768 * 256);
    cvt(stream, ffn_w1, f1_bf, (size_t)4 * 1024 * 256);
    cvt(stream, ffn_w2, f2_bf, (size_t)4 * 256 * 1024);
    hipLaunchKernelGGL(wc_kernel, dim3(4096), dim3(256), 0, stream, fus_w, attn_out_w, wcat_bf);
    hipLaunchKernelGGL(qkvbias_kernel, dim3(48), dim3(256), 0, stream,
                       attn_in_b, attn_in_w, scale_emb, effqkvb);
    hipLaunchKernelGGL(fusbias_kernel, dim3(4), dim3(256), 0, stream,
                       fus_b, fus_w, attn_out_b, fusbias);

    // ---- x = emb @ ip_w^T + ip_b + PE ----
    mgemm(stream, embbf, 640, ipw_bf, 640, ip_b, nullptr, x32, xbf,
          DMODEL, Btok, DMODEL, 640, F_PE);

    // scale pairs balanced by band width: {5,50} and {10,20}
    static const int PAIR_SI[2][2] = {{0, 3}, {1, 2}};
    static const int PAIR_R[2][2]  = {{5, 50}, {10, 20}};

    for (int l = 0; l < NLAYER; ++l) {
        for (int pr = 0; pr < 2; ++pr) {
            #pragma unroll
            for (int slot = 0; slot < 2; ++slot) {
                int siG = PAIR_SI[pr][slot];
                int ls = l * NSCALE + siG;
                // qkv slice -> qkv2 cols [slot*768, slot*768+768)
                mgemm(stream, xbf, DMODEL, aiw_bf + (size_t)ls * 768 * 256, DMODEL,
                      effqkvb + (size_t)ls * 768, nullptr, nullptr, qkv2 + slot * 768,
                      1536, Btok, 768, DMODEL, 0);
            }
            hipLaunchKernelGGL(attn_kernel, dim3(1024), dim3(128), 0, stream,
                               qkv2, ocat,
                               PAIR_SI[pr][0], PAIR_R[pr][0],
                               PAIR_SI[pr][1], PAIR_R[pr][1]);
        }
        // fused = ocat @ Wcat[l]^T + fusbias[l]
        mgemm(stream, ocat, 1024, wcat_bf + (size_t)l * 256 * 1024, 1024,
              fusbias + l * DMODEL, nullptr, fused32, nullptr,
              DMODEL, Btok, DMODEL, 1024, 0);
        hipLaunchKernelGGL(ln_wave, dim3(Btok), dim3(64), 0, stream,
                           x32, fused32, n1_g + l * DMODEL, n1_b + l * DMODEL, x32, xbf, 0);
        mgemm(stream, xbf, DMODEL, f1_bf + (size_t)l * 1024 * 256, DMODEL,
              ffn_b1 + (size_t)l * 1024, nullptr, nullptr, midbf,
              1024, Btok, 1024, DMODEL, F_GELU);
        mgemm(stream, midbf, 1024, f2_bf + (size_t)l * 256 * 1024, 1024,
              ffn_b2 + (size_t)l * DMODEL, nullptr, fused32, nullptr,
              DMODEL, Btok, DMODEL, 1024, 0);
        hipLaunchKernelGGL(ln_wave, dim3(Btok), dim3(64), 0, stream,
                           x32, fused32, n2_g + l * DMODEL, n2_b + l * DMODEL, x32, xbf, 0);
    }

    // ---- head ----
    hipLaunchKernelGGL(smallmm, dim3(16), dim3(256), 0, stream,
                       features, 66, feat_w, 66, feat_b, frbuf, DMODEL, 16, DMODEL, 66, 0);
    hipLaunchKernelGGL(ln_wave, dim3(16), dim3(64), 0, stream,
                       frbuf, nullptr, feat_ln_g, feat_ln_b, frbuf, nullptr, 1);
    hipLaunchKernelGGL(smallmm, dim3(16), dim3(256), 0, stream,
                       x32 + (size_t)(S_LEN / 2) * DMODEL, S_LEN * DMODEL,
                       h1_w, 512, h1_b, h1buf, DMODEL, 16, DMODEL, DMODEL, 0);
    hipLaunchKernelGGL(smallmm, dim3(16), dim3(256), 0, stream,
                       frbuf, DMODEL, h1_w + 256, 512, nullptr, h1buf, DMODEL,
                       16, DMODEL, DMODEL, F_BETA);
    hipLaunchKernelGGL(ln_wave, dim3(16), dim3(64), 0, stream,
                       h1buf, nullptr, h_ln_g, h_ln_b, h1buf, nullptr, 1);
    hipLaunchKernelGGL(smallmm, dim3(8), dim3(256), 0, stream,
                       h1buf, DMODEL, h2_w, DMODEL, h2_b, h2buf, 128, 16, 128, DMODEL, F_GELU);
    hipLaunchKernelGGL(smallmm, dim3(1), dim3(256), 0, stream,
                       h2buf, 128, h3_w, 128, h3_b, outp, 1, 16, 1, 128, 0);
}

// Round 4
// 1248.961 us; speedup vs baseline: 5.4240x; 1.3388x over previous
//
#include <hip/hip_runtime.h>
#include <math.h>

#define S_LEN 512
#define DMODEL 256
#define NHEAD 8
#define HDIM 32
#define NLAYER 4
#define NSCALE 4

typedef unsigned short ushortT;
typedef unsigned int uintT;
typedef short bf16x8 __attribute__((ext_vector_type(8)));
typedef float f32x4 __attribute__((ext_vector_type(4)));

enum { F_PE = 1, F_BETA = 2, F_GELU = 4 };

__device__ __forceinline__ float gelu_f(float x) {
    return 0.5f * x * (1.0f + erff(x * 0.70710678118654752440f));
}
__device__ __forceinline__ ushortT f2bf(float f) {
    union { float f; uintT i; } u; u.f = f;
    uintT r = u.i + 0x7FFF + ((u.i >> 16) & 1);   // RNE
    return (ushortT)(r >> 16);
}
__device__ __forceinline__ int swz(int r) { return (r & 3) ^ ((r >> 2) & 3); }

#define GLD16(g, l) \
    __builtin_amdgcn_global_load_lds((const __attribute__((address_space(1))) void*)(g), \
                                     (__attribute__((address_space(3))) void*)(l), 16, 0, 0)

// C[M,N] = op(A[M,K]bf16 @ W[N,K]bf16^T + bias) ; M%128==0, N%BN==0, K%32==0
template<int BN>
__global__ __launch_bounds__(256) void mfma_gemm(
    const ushortT* __restrict__ A, int lda,
    const ushortT* __restrict__ W, int ldw,
    const float* __restrict__ bias,
    const float* __restrict__ betaC,
    float* __restrict__ out32,
    ushortT* __restrict__ out16,
    int ldc, int K, int flags)
{
    constexpr int NI = BN / 32;
    __shared__ __align__(16) ushortT As[128 * 32];
    __shared__ __align__(16) ushortT Bs[BN * 32];
    const int tid = threadIdx.x;
    const int wave = tid >> 6, lane = tid & 63;
    const int l15 = lane & 15, qd = lane >> 4;
    const int m0 = blockIdx.x * 128, n0 = blockIdx.y * BN;
    const int wm = (wave >> 1) * 64, wn = (wave & 1) * (BN / 2);

    f32x4 acc[4][NI];
    #pragma unroll
    for (int i = 0; i < 4; ++i)
        #pragma unroll
        for (int j = 0; j < NI; ++j) acc[i][j] = (f32x4){0.f, 0.f, 0.f, 0.f};

    for (int k0 = 0; k0 < K; k0 += 32) {
        #pragma unroll
        for (int it = 0; it < 2; ++it) {
            int c = it * 256 + tid;
            int m = c >> 2, s = c & 3;
            int kc = s ^ swz(m);
            const ushortT* g = A + (size_t)(m0 + m) * lda + k0 + kc * 8;
            GLD16(g, (ushortT*)As + (size_t)(it * 256 + wave * 64) * 8);
        }
        #pragma unroll
        for (int it = 0; it < BN / 64; ++it) {
            int c = it * 256 + tid;
            int n = c >> 2, s = c & 3;
            int kc = s ^ swz(n);
            const ushortT* g = W + (size_t)(n0 + n) * ldw + k0 + kc * 8;
            GLD16(g, (ushortT*)Bs + (size_t)(it * 256 + wave * 64) * 8);
        }
        __syncthreads();
        bf16x8 af[4], bfr[NI];
        #pragma unroll
        for (int mi = 0; mi < 4; ++mi) {
            int r = wm + mi * 16 + l15;
            af[mi] = *(const bf16x8*)(As + r * 32 + (qd ^ swz(r)) * 8);
        }
        #pragma unroll
        for (int ni = 0; ni < NI; ++ni) {
            int r = wn + ni * 16 + l15;
            bfr[ni] = *(const bf16x8*)(Bs + r * 32 + (qd ^ swz(r)) * 8);
        }
        #pragma unroll
        for (int mi = 0; mi < 4; ++mi)
            #pragma unroll
            for (int ni = 0; ni < NI; ++ni)
                acc[mi][ni] = __builtin_amdgcn_mfma_f32_16x16x32_bf16(
                    af[mi], bfr[ni], acc[mi][ni], 0, 0, 0);
        __syncthreads();
    }

    #pragma unroll
    for (int mi = 0; mi < 4; ++mi) {
        #pragma unroll
        for (int ni = 0; ni < NI; ++ni) {
            int col = n0 + wn + ni * 16 + l15;
            float bv = bias ? bias[col] : 0.f;
            #pragma unroll
            for (int r = 0; r < 4; ++r) {
                int grow = m0 + wm + mi * 16 + qd * 4 + r;
                float v = acc[mi][ni][r] + bv;
                if (flags & F_BETA) v += betaC[(size_t)grow * ldc + col];
                if (flags & F_PE) {
                    int pos = grow & (S_LEN - 1);
                    float div = expf((float)(col & ~1) * (-9.210340371976184f / 256.0f));
                    float ang = (float)pos * div;
                    v += (col & 1) ? cosf(ang) : sinf(ang);
                }
                if (flags & F_GELU) v = gelu_f(v);
                if (out32) out32[(size_t)grow * ldc + col] = v;
                if (out16) out16[(size_t)grow * ldc + col] = f2bf(v);
            }
        }
    }
}

// MFMA banded attention. qkv: (B*S, 1536) = pair of scales (cols 0 / 768), each q|k|v*256.
// Block = 256 thr = 4 waves; block handles (scale-slot, b, h, 64-q chunk); wave = 16 q.
// QK^T: 1 mfma/16-key-tile; P->LDS (A-layout); V staged transposed in LDS; PV: mfma.
__global__ __launch_bounds__(256) void attn_mfma(
    const ushortT* __restrict__ qkv, ushortT* __restrict__ ocat,
    int si0, int r0, int si1, int r1)
{
    __shared__ __align__(16) ushortT Vt[32 * 216];     // [d][key_local], stride 216
    __shared__ __align__(16) ushortT Pl[4][16 * 168];  // per-wave P, stride 168
    const int bid = blockIdx.x;
    const int sp   = bid & 1;
    const int qblk = (bid >> 1) & 7;
    const int h    = (bid >> 4) & 7;
    const int b    = (bid >> 7) & 15;
    const int si = sp ? si1 : si0;
    const int r  = sp ? r1 : r0;
    const int lcol = sp * 768;
    const int tid = threadIdx.x;

    const int q0blk = qblk * 64;
    const int t0 = max(0, q0blk - r) >> 4;
    const int t1 = min(S_LEN - 1, q0blk + 63 + r) >> 4;
    const int nstage = (t1 - t0 + 2) * 16;   // +1 zero pad tile
    const int kmax = min(S_LEN - 1, t1 * 16 + 15);

    const ushortT* bbase = qkv + (size_t)(b * S_LEN) * 1536 + lcol;

    // ---- stage V transposed: Vt[d][key - t0*16] ----
    for (int idx = tid; idx < nstage * 4; idx += 256) {
        int row = idx >> 2, dch = idx & 3;
        int key = t0 * 16 + row;
        uint4 u = make_uint4(0, 0, 0, 0);
        if (key <= kmax)
            u = *(const uint4*)(bbase + (size_t)key * 1536 + 512 + h * HDIM + dch * 8);
        ushortT* dst = &Vt[(dch * 8) * 216 + row];
        uintT w[4] = {u.x, u.y, u.z, u.w};
        #pragma unroll
        for (int t = 0; t < 4; ++t) {
            dst[(2 * t) * 216]     = (ushortT)(w[t] & 0xffff);
            dst[(2 * t + 1) * 216] = (ushortT)(w[t] >> 16);
        }
    }

    const int wid = tid >> 6, lane = tid & 63;
    const int quad = lane >> 4, l15 = lane & 15;
    ushortT* Pw = Pl[wid];

    // zero own-wave P (covers the odd-tile PV pad)
    {
        uint4 z = make_uint4(0, 0, 0, 0);
        #pragma unroll
        for (int i = 0; i < 6; ++i) {
            int c = lane + i * 64;
            if (c < 336) ((uint4*)Pw)[c] = z;
        }
    }
    __syncthreads();

    const int q0w = q0blk + wid * 16;
    // Q fragment (A-layout) straight from global
    bf16x8 qf = *(const bf16x8*)(bbase + (size_t)(q0w + l15) * 1536 + h * HDIM + quad * 8);

    const int kt0 = max(0, q0w - r) >> 4;
    const int kt1 = min(S_LEN - 1, q0w + 15 + r) >> 4;
    const int nt = kt1 - kt0 + 1;

    f32x4 rs4 = (f32x4){0.f, 0.f, 0.f, 0.f};
    const unsigned span = (unsigned)(2 * r);

    for (int kt = kt0; kt <= kt1; ++kt) {
        int key = kt * 16 + l15;                 // <= 511 by construction
        bf16x8 kf = *(const bf16x8*)(bbase + (size_t)key * 1536 + 256 + h * HDIM + quad * 8);
        f32x4 s4 = __builtin_amdgcn_mfma_f32_16x16x32_bf16(
            qf, kf, (f32x4){0.f, 0.f, 0.f, 0.f}, 0, 0, 0);
        #pragma unroll
        for (int rg = 0; rg < 4; ++rg) {
            int q = q0w + quad * 4 + rg;
            unsigned dd = (unsigned)(key - q + r);
            float p = (dd <= span)
                      ? __expf(fminf(s4[rg] * 0.17677669529663688f, 80.f)) : 0.f;
            rs4[rg] += p;
            Pw[(quad * 4 + rg) * 168 + (kt - kt0) * 16 + l15] = f2bf(p);
        }
    }

    // rowsum reduce over the 16 cols (lanes sharing quad group)
    #pragma unroll
    for (int m = 1; m < 16; m <<= 1) {
        #pragma unroll
        for (int rg = 0; rg < 4; ++rg) rs4[rg] += __shfl_xor(rs4[rg], m, 64);
    }

    // ---- PV ----
    f32x4 o0 = (f32x4){0.f, 0.f, 0.f, 0.f};
    f32x4 o1 = (f32x4){0.f, 0.f, 0.f, 0.f};
    const int basek = (kt0 - t0) * 16;
    const int nch = (nt + 1) >> 1;
    for (int c = 0; c < nch; ++c) {
        bf16x8 pa = *(const bf16x8*)(Pw + l15 * 168 + c * 32 + quad * 8);
        bf16x8 v0 = *(const bf16x8*)(&Vt[l15 * 216 + basek + c * 32 + quad * 8]);
        bf16x8 v1 = *(const bf16x8*)(&Vt[(l15 + 16) * 216 + basek + c * 32 + quad * 8]);
        o0 = __builtin_amdgcn_mfma_f32_16x16x32_bf16(pa, v0, o0, 0, 0, 0);
        o1 = __builtin_amdgcn_mfma_f32_16x16x32_bf16(pa, v1, o1, 0, 0, 0);
    }

    // ---- scale + write (C-layout rows == rowsum layout) ----
    #pragma unroll
    for (int rg = 0; rg < 4; ++rg) {
        float inv = 1.0f / rs4[rg];
        int q = q0w + quad * 4 + rg;
        ushortT* op = ocat + ((size_t)(b * S_LEN) + q) * 1024 + si * DMODEL + h * HDIM;
        op[l15]      = f2bf(o0[rg] * inv);
        op[16 + l15] = f2bf(o1[rg] * inv);
    }
}

// one wave per 256-wide row: out = LN(a (+b2)) * g + be (+gelu); dual fp32/bf16 write
__global__ __launch_bounds__(64) void ln_wave(
    const float* __restrict__ a, const float* __restrict__ b2,
    const float* __restrict__ g, const float* __restrict__ be,
    float* __restrict__ o32, ushortT* __restrict__ o16, int dogelu)
{
    const int row = blockIdx.x, lane = threadIdx.x;
    float4 v = *(const float4*)(a + (size_t)row * DMODEL + lane * 4);
    if (b2) {
        float4 w = *(const float4*)(b2 + (size_t)row * DMODEL + lane * 4);
        v.x += w.x; v.y += w.y; v.z += w.z; v.w += w.w;
    }
    float s = v.x + v.y + v.z + v.w;
    #pragma unroll
    for (int off = 32; off; off >>= 1) s += __shfl_xor(s, off, 64);
    float m = s * (1.0f / DMODEL);
    float dx = v.x - m, dy = v.y - m, dz = v.z - m, dw = v.w - m;
    float s2 = dx * dx + dy * dy + dz * dz + dw * dw;
    #pragma unroll
    for (int off = 32; off; off >>= 1) s2 += __shfl_xor(s2, off, 64);
    float r = rsqrtf(s2 * (1.0f / DMODEL) + 1e-5f);
    float4 gg = *(const float4*)(g + lane * 4);
    float4 bb = *(const float4*)(be + lane * 4);
    float y0 = dx * r * gg.x + bb.x, y1 = dy * r * gg.y + bb.y;
    float y2 = dz * r * gg.z + bb.z, y3 = dw * r * gg.w + bb.w;
    if (dogelu) { y0 = gelu_f(y0); y1 = gelu_f(y1); y2 = gelu_f(y2); y3 = gelu_f(y3); }
    if (o32) *(float4*)(o32 + (size_t)row * DMODEL + lane * 4) = make_float4(y0, y1, y2, y3);
    if (o16) {
        ushort4 u; u.x = f2bf(y0); u.y = f2bf(y1); u.z = f2bf(y2); u.w = f2bf(y3);
        *(ushort4*)(o16 + (size_t)row * DMODEL + lane * 4) = u;
    }
}

// tiny-M fp32 GEMM for the head (M<=16)
__global__ __launch_bounds__(256) void smallmm(
    const float* __restrict__ A, int lda, const float* __restrict__ W, int ldw,
    const float* __restrict__ bias, float* __restrict__ C, int ldc,
    int M, int N, int K, int flags)
{
    int n = blockIdx.x * 16 + (threadIdx.x & 15);
    int i = threadIdx.x >> 4;
    if (i >= M || n >= N) return;
    float s = bias ? bias[n] : 0.f;
    const float* a = A + (size_t)i * lda;
    const float* w = W + (size_t)n * ldw;
    for (int k = 0; k < K; ++k) s = fmaf(a[k], w[k], s);
    if (flags & F_BETA) s += C[(size_t)i * ldc + n];
    if (flags & F_GELU) s = gelu_f(s);
    C[(size_t)i * ldc + n] = s;
}

__global__ __launch_bounds__(256) void cvt_kernel(
    const float4* __restrict__ src, ushort4* __restrict__ dst, int n4)
{
    int i = blockIdx.x * 256 + threadIdx.x;
    if (i < n4) {
        float4 f = src[i];
        ushort4 u; u.x = f2bf(f.x); u.y = f2bf(f.y); u.z = f2bf(f.z); u.w = f2bf(f.w);
        dst[i] = u;
    }
}

// Wcat[l][n][si*256+d] = sum_j fus_w[l][n][si*256+j] * attn_out_w[l][si][j][d]
__global__ __launch_bounds__(256) void wc_kernel(
    const float* __restrict__ fus_w, const float* __restrict__ ao_w, ushortT* __restrict__ Wcat)
{
    int bid = blockIdx.x;
    int n = bid & 255, ls = bid >> 8;
    int l = ls >> 2, si = ls & 3;
    int d = threadIdx.x;
    const float* fw = fus_w + ((size_t)l * 256 + n) * 1024 + si * 256;
    const float* ao = ao_w + (size_t)ls * 65536 + d;
    float s = 0.f;
    for (int j = 0; j < 256; ++j) s = fmaf(fw[j], ao[(size_t)j * 256], s);
    Wcat[((size_t)l * 256 + n) * 1024 + si * 256 + d] = f2bf(s);
}

__global__ __launch_bounds__(256) void qkvbias_kernel(
    const float* __restrict__ aib, const float* __restrict__ aiw,
    const float* __restrict__ se, float* __restrict__ eb)
{
    int i = blockIdx.x * 256 + threadIdx.x;   // < 12288
    int r = i % 3072, si = r / 768;
    const float* w = aiw + (size_t)i * 256;
    const float* s = se + si * 256;
    float acc = aib[i];
    for (int k = 0; k < 256; ++k) acc = fmaf(s[k], w[k], acc);
    eb[i] = acc;
}

__global__ __launch_bounds__(256) void fusbias_kernel(
    const float* __restrict__ fus_b, const float* __restrict__ fus_w,
    const float* __restrict__ aob, float* __restrict__ fb)
{
    int l = blockIdx.x, n = threadIdx.x;
    const float* w = fus_w + ((size_t)l * 256 + n) * 1024;
    const float* o = aob + (size_t)l * 1024;
    float acc = fus_b[l * 256 + n];
    for (int j = 0; j < 1024; ++j) acc = fmaf(o[j], w[j], acc);
    fb[l * 256 + n] = acc;
}

static inline void mgemm(hipStream_t s, const ushortT* A, int lda, const ushortT* W, int ldw,
                         const float* bias, const float* betaC, float* o32, ushortT* o16,
                         int ldc, int M, int N, int K, int flags)
{
    if (N % 128 == 0) {
        dim3 g(M / 128, N / 128);
        hipLaunchKernelGGL(mfma_gemm<128>, g, dim3(256), 0, s,
                           A, lda, W, ldw, bias, betaC, o32, o16, ldc, K, flags);
    } else {
        dim3 g(M / 128, N / 64);
        hipLaunchKernelGGL(mfma_gemm<64>, g, dim3(256), 0, s,
                           A, lda, W, ldw, bias, betaC, o32, o16, ldc, K, flags);
    }
}

static inline void cvt(hipStream_t s, const float* src, ushortT* dst, size_t n)
{
    int n4 = (int)(n / 4);
    hipLaunchKernelGGL(cvt_kernel, dim3((n4 + 255) / 256), dim3(256), 0, s,
                       (const float4*)src, (ushort4*)dst, n4);
}

extern "C" void kernel_launch(void* const* d_in, const int* in_sizes, int n_in,
                              void* d_out, int out_size, void* d_ws, size_t ws_size,
                              hipStream_t stream)
{
    const float* emb        = (const float*)d_in[0];
    const float* features   = (const float*)d_in[1];
    const float* ip_w       = (const float*)d_in[2];
    const float* ip_b       = (const float*)d_in[3];
    const float* scale_emb  = (const float*)d_in[4];
    const float* attn_in_w  = (const float*)d_in[5];
    const float* attn_in_b  = (const float*)d_in[6];
    const float* attn_out_w = (const float*)d_in[7];
    const float* attn_out_b = (const float*)d_in[8];
    const float* fus_w      = (const float*)d_in[9];
    const float* fus_b      = (const float*)d_in[10];
    const float* ffn_w1     = (const float*)d_in[11];
    const float* ffn_b1     = (const float*)d_in[12];
    const float* ffn_w2     = (const float*)d_in[13];
    const float* ffn_b2     = (const float*)d_in[14];
    const float* n1_g       = (const float*)d_in[15];
    const float* n1_b       = (const float*)d_in[16];
    const float* n2_g       = (const float*)d_in[17];
    const float* n2_b       = (const float*)d_in[18];
    const float* feat_w     = (const float*)d_in[19];
    const float* feat_b     = (const float*)d_in[20];
    const float* feat_ln_g  = (const float*)d_in[21];
    const float* feat_ln_b  = (const float*)d_in[22];
    const float* h1_w       = (const float*)d_in[23];
    const float* h1_b       = (const float*)d_in[24];
    const float* h_ln_g     = (const float*)d_in[25];
    const float* h_ln_b     = (const float*)d_in[26];
    const float* h2_w       = (const float*)d_in[27];
    const float* h2_b       = (const float*)d_in[28];
    const float* h3_w       = (const float*)d_in[29];
    const float* h3_b       = (const float*)d_in[30];
    float* outp = (float*)d_out;

    const int Btok = 16 * S_LEN;   // 8192

    // ---- workspace carve-up ----
    char* p = (char*)d_ws;
    float* x32     = (float*)p;              p += (size_t)Btok * DMODEL * 4;
    float* fused32 = (float*)p;              p += (size_t)Btok * DMODEL * 4;
    float* effqkvb = (float*)p;              p += 12288 * 4;
    float* fusbias = (float*)p;              p += 1024 * 4;
    float* frbuf   = (float*)p;              p += 16 * DMODEL * 4;
    float* h1buf   = (float*)p;              p += 16 * DMODEL * 4;
    float* h2buf   = (float*)p;              p += 16 * 128 * 4;
    ushortT* xbf   = (ushortT*)p;            p += (size_t)Btok * DMODEL * 2;
    ushortT* qkv2  = (ushortT*)p;            p += (size_t)Btok * 1536 * 2;   // pair buffer
    ushortT* ocat  = (ushortT*)p;            p += (size_t)Btok * 1024 * 2;
    ushortT* ipw_bf  = (ushortT*)p;          p += (size_t)DMODEL * 640 * 2;
    ushortT* aiw_bf  = (ushortT*)p;          p += (size_t)16 * 768 * 256 * 2;
    ushortT* wcat_bf = (ushortT*)p;          p += (size_t)4 * 256 * 1024 * 2;
    ushortT* f1_bf   = (ushortT*)p;          p += (size_t)4 * 1024 * 256 * 2;
    ushortT* f2_bf   = (ushortT*)p;          p += (size_t)4 * 256 * 1024 * 2;
    ushortT* embbf = qkv2;                   // alias: emb_bf dead before layer-0 qkv
    ushortT* midbf = ocat;                   // alias: ffn mid after ocat consumed

    // ---- precompute ----
    cvt(stream, emb, embbf, (size_t)Btok * 640);
    cvt(stream, ip_w, ipw_bf, (size_t)DMODEL * 640);
    cvt(stream, attn_in_w, aiw_bf, (size_t)16 * 768 * 256);
    cvt(stream, ffn_w1, f1_bf, (size_t)4 * 1024 * 256);
    cvt(stream, ffn_w2, f2_bf, (size_t)4 * 256 * 1024);
    hipLaunchKernelGGL(wc_kernel, dim3(4096), dim3(256), 0, stream, fus_w, attn_out_w, wcat_bf);
    hipLaunchKernelGGL(qkvbias_kernel, dim3(48), dim3(256), 0, stream,
                       attn_in_b, attn_in_w, scale_emb, effqkvb);
    hipLaunchKernelGGL(fusbias_kernel, dim3(4), dim3(256), 0, stream,
                       fus_b, fus_w, attn_out_b, fusbias);

    // ---- x = emb @ ip_w^T + ip_b + PE ----
    mgemm(stream, embbf, 640, ipw_bf, 640, ip_b, nullptr, x32, xbf,
          DMODEL, Btok, DMODEL, 640, F_PE);

    // scale pairs balanced by band width: {5,50} and {10,20}
    static const int PAIR_SI[2][2] = {{0, 3}, {1, 2}};
    static const int PAIR_R[2][2]  = {{5, 50}, {10, 20}};

    for (int l = 0; l < NLAYER; ++l) {
        for (int pr = 0; pr < 2; ++pr) {
            #pragma unroll
            for (int slot = 0; slot < 2; ++slot) {
                int siG = PAIR_SI[pr][slot];
                int ls = l * NSCALE + siG;
                mgemm(stream, xbf, DMODEL, aiw_bf + (size_t)ls * 768 * 256, DMODEL,
                      effqkvb + (size_t)ls * 768, nullptr, nullptr, qkv2 + slot * 768,
                      1536, Btok, 768, DMODEL, 0);
            }
            hipLaunchKernelGGL(attn_mfma, dim3(2048), dim3(256), 0, stream,
                               qkv2, ocat,
                               PAIR_SI[pr][0], PAIR_R[pr][0],
                               PAIR_SI[pr][1], PAIR_R[pr][1]);
        }
        // fused = ocat @ Wcat[l]^T + fusbias[l]
        mgemm(stream, ocat, 1024, wcat_bf + (size_t)l * 256 * 1024, 1024,
              fusbias + l * DMODEL, nullptr, fused32, nullptr,
              DMODEL, Btok, DMODEL, 1024, 0);
        hipLaunchKernelGGL(ln_wave, dim3(Btok), dim3(64), 0, stream,
                           x32, fused32, n1_g + l * DMODEL, n1_b + l * DMODEL, x32, xbf, 0);
        mgemm(stream, xbf, DMODEL, f1_bf + (size_t)l * 1024 * 256, DMODEL,
              ffn_b1 + (size_t)l * 1024, nullptr, nullptr, midbf,
              1024, Btok, 1024, DMODEL, F_GELU);
        mgemm(stream, midbf, 1024, f2_bf + (size_t)l * 256 * 1024, 1024,
              ffn_b2 + (size_t)l * DMODEL, nullptr, fused32, nullptr,
              DMODEL, Btok, DMODEL, 1024, 0);
        hipLaunchKernelGGL(ln_wave, dim3(Btok), dim3(64), 0, stream,
                           x32, fused32, n2_g + l * DMODEL, n2_b + l * DMODEL, x32, xbf, 0);
    }

    // ---- head ----
    hipLaunchKernelGGL(smallmm, dim3(16), dim3(256), 0, stream,
                       features, 66, feat_w, 66, feat_b, frbuf, DMODEL, 16, DMODEL, 66, 0);
    hipLaunchKernelGGL(ln_wave, dim3(16), dim3(64), 0, stream,
                       frbuf, nullptr, feat_ln_g, feat_ln_b, frbuf, nullptr, 1);
    hipLaunchKernelGGL(smallmm, dim3(16), dim3(256), 0, stream,
                       x32 + (size_t)(S_LEN / 2) * DMODEL, S_LEN * DMODEL,
                       h1_w, 512, h1_b, h1buf, DMODEL, 16, DMODEL, DMODEL, 0);
    hipLaunchKernelGGL(smallmm, dim3(16), dim3(256), 0, stream,
                       frbuf, DMODEL, h1_w + 256, 512, nullptr, h1buf, DMODEL,
                       16, DMODEL, DMODEL, F_BETA);
    hipLaunchKernelGGL(ln_wave, dim3(16), dim3(64), 0, stream,
                       h1buf, nullptr, h_ln_g, h_ln_b, h1buf, nullptr, 1);
    hipLaunchKernelGGL(smallmm, dim3(8), dim3(256), 0, stream,
                       h1buf, DMODEL, h2_w, DMODEL, h2_b, h2buf, 128, 16, 128, DMODEL, F_GELU);
    hipLaunchKernelGGL(smallmm, dim3(1), dim3(256), 0, stream,
                       h2buf, 128, h3_w, 128, h3_b, outp, 1, 16, 1, 128, 0);
}

// Round 5
// 1111.176 us; speedup vs baseline: 6.0965x; 1.1240x over previous
//
#include <hip/hip_runtime.h>
#include <math.h>

#define S_LEN 512
#define DMODEL 256
#define NHEAD 8
#define HDIM 32
#define NLAYER 4
#define NSCALE 4

typedef unsigned short ushortT;
typedef unsigned int uintT;
typedef short bf16x8 __attribute__((ext_vector_type(8)));
typedef float f32x4 __attribute__((ext_vector_type(4)));

enum { F_PE = 1, F_BETA = 2, F_GELU = 4 };

__device__ __forceinline__ float gelu_f(float x) {
    return 0.5f * x * (1.0f + erff(x * 0.70710678118654752440f));
}
__device__ __forceinline__ ushortT f2bf(float f) {
    union { float f; uintT i; } u; u.f = f;
    uintT r = u.i + 0x7FFF + ((u.i >> 16) & 1);   // RNE
    return (ushortT)(r >> 16);
}
__device__ __forceinline__ int swz(int r) { return (r & 3) ^ ((r >> 2) & 3); }

#define GLD16(g, l) \
    __builtin_amdgcn_global_load_lds((const __attribute__((address_space(1))) void*)(g), \
                                     (__attribute__((address_space(3))) void*)(l), 16, 0, 0)

// C[M,N] = op(A[M,K]bf16 @ W[N,K]bf16^T + bias) ; M%128==0, N%BN==0, K%32==0
template<int BN>
__global__ __launch_bounds__(256) void mfma_gemm(
    const ushortT* __restrict__ A, int lda,
    const ushortT* __restrict__ W, int ldw,
    const float* __restrict__ bias,
    const float* __restrict__ betaC,
    float* __restrict__ out32,
    ushortT* __restrict__ out16,
    int ldc, int K, int flags)
{
    constexpr int NI = BN / 32;
    __shared__ __align__(16) ushortT As[128 * 32];
    __shared__ __align__(16) ushortT Bs[BN * 32];
    const int tid = threadIdx.x;
    const int wave = tid >> 6, lane = tid & 63;
    const int l15 = lane & 15, qd = lane >> 4;
    const int m0 = blockIdx.x * 128, n0 = blockIdx.y * BN;
    const int wm = (wave >> 1) * 64, wn = (wave & 1) * (BN / 2);

    f32x4 acc[4][NI];
    #pragma unroll
    for (int i = 0; i < 4; ++i)
        #pragma unroll
        for (int j = 0; j < NI; ++j) acc[i][j] = (f32x4){0.f, 0.f, 0.f, 0.f};

    for (int k0 = 0; k0 < K; k0 += 32) {
        #pragma unroll
        for (int it = 0; it < 2; ++it) {
            int c = it * 256 + tid;
            int m = c >> 2, s = c & 3;
            int kc = s ^ swz(m);
            const ushortT* g = A + (size_t)(m0 + m) * lda + k0 + kc * 8;
            GLD16(g, (ushortT*)As + (size_t)(it * 256 + wave * 64) * 8);
        }
        #pragma unroll
        for (int it = 0; it < BN / 64; ++it) {
            int c = it * 256 + tid;
            int n = c >> 2, s = c & 3;
            int kc = s ^ swz(n);
            const ushortT* g = W + (size_t)(n0 + n) * ldw + k0 + kc * 8;
            GLD16(g, (ushortT*)Bs + (size_t)(it * 256 + wave * 64) * 8);
        }
        __syncthreads();
        bf16x8 af[4], bfr[NI];
        #pragma unroll
        for (int mi = 0; mi < 4; ++mi) {
            int r = wm + mi * 16 + l15;
            af[mi] = *(const bf16x8*)(As + r * 32 + (qd ^ swz(r)) * 8);
        }
        #pragma unroll
        for (int ni = 0; ni < NI; ++ni) {
            int r = wn + ni * 16 + l15;
            bfr[ni] = *(const bf16x8*)(Bs + r * 32 + (qd ^ swz(r)) * 8);
        }
        #pragma unroll
        for (int mi = 0; mi < 4; ++mi)
            #pragma unroll
            for (int ni = 0; ni < NI; ++ni)
                acc[mi][ni] = __builtin_amdgcn_mfma_f32_16x16x32_bf16(
                    af[mi], bfr[ni], acc[mi][ni], 0, 0, 0);
        __syncthreads();
    }

    #pragma unroll
    for (int mi = 0; mi < 4; ++mi) {
        #pragma unroll
        for (int ni = 0; ni < NI; ++ni) {
            int col = n0 + wn + ni * 16 + l15;
            float bv = bias ? bias[col] : 0.f;
            #pragma unroll
            for (int r = 0; r < 4; ++r) {
                int grow = m0 + wm + mi * 16 + qd * 4 + r;
                float v = acc[mi][ni][r] + bv;
                if (flags & F_BETA) v += betaC[(size_t)grow * ldc + col];
                if (flags & F_PE) {
                    int pos = grow & (S_LEN - 1);
                    float div = expf((float)(col & ~1) * (-9.210340371976184f / 256.0f));
                    float ang = (float)pos * div;
                    v += (col & 1) ? cosf(ang) : sinf(ang);
                }
                if (flags & F_GELU) v = gelu_f(v);
                if (out32) out32[(size_t)grow * ldc + col] = v;
                if (out16) out16[(size_t)grow * ldc + col] = f2bf(v);
            }
        }
    }
}

// MFMA banded attention. qkv: (B*S, 1536) = pair of scales (cols 0 / 768), each q|k|v*256.
// Block = 256 thr = 4 waves; block handles (scale-slot, b, h, 64-q chunk); wave = 16 q.
__global__ __launch_bounds__(256) void attn_mfma(
    const ushortT* __restrict__ qkv, ushortT* __restrict__ ocat,
    int si0, int r0, int si1, int r1)
{
    __shared__ __align__(16) ushortT Vt[32 * 216];     // [d][key_local], stride 216
    __shared__ __align__(16) ushortT Pl[4][16 * 168];  // per-wave P, stride 168
    const int bid = blockIdx.x;
    const int sp   = bid & 1;
    const int qblk = (bid >> 1) & 7;
    const int h    = (bid >> 4) & 7;
    const int b    = (bid >> 7) & 15;
    const int si = sp ? si1 : si0;
    const int r  = sp ? r1 : r0;
    const int lcol = sp * 768;
    const int tid = threadIdx.x;

    const int q0blk = qblk * 64;
    const int t0 = max(0, q0blk - r) >> 4;
    const int t1 = min(S_LEN - 1, q0blk + 63 + r) >> 4;
    const int nstage = (t1 - t0 + 2) * 16;   // +1 zero pad tile
    const int kmax = min(S_LEN - 1, t1 * 16 + 15);

    const ushortT* bbase = qkv + (size_t)(b * S_LEN) * 1536 + lcol;

    // ---- stage V transposed: Vt[d][key - t0*16] ----
    for (int idx = tid; idx < nstage * 4; idx += 256) {
        int row = idx >> 2, dch = idx & 3;
        int key = t0 * 16 + row;
        uint4 u = make_uint4(0, 0, 0, 0);
        if (key <= kmax)
            u = *(const uint4*)(bbase + (size_t)key * 1536 + 512 + h * HDIM + dch * 8);
        ushortT* dst = &Vt[(dch * 8) * 216 + row];
        uintT w[4] = {u.x, u.y, u.z, u.w};
        #pragma unroll
        for (int t = 0; t < 4; ++t) {
            dst[(2 * t) * 216]     = (ushortT)(w[t] & 0xffff);
            dst[(2 * t + 1) * 216] = (ushortT)(w[t] >> 16);
        }
    }

    const int wid = tid >> 6, lane = tid & 63;
    const int quad = lane >> 4, l15 = lane & 15;
    ushortT* Pw = Pl[wid];

    // zero own-wave P (covers the odd-tile PV pad)
    {
        uint4 z = make_uint4(0, 0, 0, 0);
        #pragma unroll
        for (int i = 0; i < 6; ++i) {
            int c = lane + i * 64;
            if (c < 336) ((uint4*)Pw)[c] = z;
        }
    }
    __syncthreads();

    const int q0w = q0blk + wid * 16;
    bf16x8 qf = *(const bf16x8*)(bbase + (size_t)(q0w + l15) * 1536 + h * HDIM + quad * 8);

    const int kt0 = max(0, q0w - r) >> 4;
    const int kt1 = min(S_LEN - 1, q0w + 15 + r) >> 4;
    const int nt = kt1 - kt0 + 1;

    f32x4 rs4 = (f32x4){0.f, 0.f, 0.f, 0.f};
    const unsigned span = (unsigned)(2 * r);

    for (int kt = kt0; kt <= kt1; ++kt) {
        int key = kt * 16 + l15;
        bf16x8 kf = *(const bf16x8*)(bbase + (size_t)key * 1536 + 256 + h * HDIM + quad * 8);
        f32x4 s4 = __builtin_amdgcn_mfma_f32_16x16x32_bf16(
            qf, kf, (f32x4){0.f, 0.f, 0.f, 0.f}, 0, 0, 0);
        #pragma unroll
        for (int rg = 0; rg < 4; ++rg) {
            int q = q0w + quad * 4 + rg;
            unsigned dd = (unsigned)(key - q + r);
            float p = (dd <= span)
                      ? __expf(fminf(s4[rg] * 0.17677669529663688f, 80.f)) : 0.f;
            rs4[rg] += p;
            Pw[(quad * 4 + rg) * 168 + (kt - kt0) * 16 + l15] = f2bf(p);
        }
    }

    #pragma unroll
    for (int m = 1; m < 16; m <<= 1) {
        #pragma unroll
        for (int rg = 0; rg < 4; ++rg) rs4[rg] += __shfl_xor(rs4[rg], m, 64);
    }

    // ---- PV ----
    f32x4 o0 = (f32x4){0.f, 0.f, 0.f, 0.f};
    f32x4 o1 = (f32x4){0.f, 0.f, 0.f, 0.f};
    const int basek = (kt0 - t0) * 16;
    const int nch = (nt + 1) >> 1;
    for (int c = 0; c < nch; ++c) {
        bf16x8 pa = *(const bf16x8*)(Pw + l15 * 168 + c * 32 + quad * 8);
        bf16x8 v0 = *(const bf16x8*)(&Vt[l15 * 216 + basek + c * 32 + quad * 8]);
        bf16x8 v1 = *(const bf16x8*)(&Vt[(l15 + 16) * 216 + basek + c * 32 + quad * 8]);
        o0 = __builtin_amdgcn_mfma_f32_16x16x32_bf16(pa, v0, o0, 0, 0, 0);
        o1 = __builtin_amdgcn_mfma_f32_16x16x32_bf16(pa, v1, o1, 0, 0, 0);
    }

    #pragma unroll
    for (int rg = 0; rg < 4; ++rg) {
        float inv = 1.0f / rs4[rg];
        int q = q0w + quad * 4 + rg;
        ushortT* op = ocat + ((size_t)(b * S_LEN) + q) * 1024 + si * DMODEL + h * HDIM;
        op[l15]      = f2bf(o0[rg] * inv);
        op[16 + l15] = f2bf(o1[rg] * inv);
    }
}

// one wave per 256-wide row: out = LN(a (+b2)) * g + be (+gelu); dual fp32/bf16 write
__global__ __launch_bounds__(64) void ln_wave(
    const float* __restrict__ a, const float* __restrict__ b2,
    const float* __restrict__ g, const float* __restrict__ be,
    float* __restrict__ o32, ushortT* __restrict__ o16, int dogelu)
{
    const int row = blockIdx.x, lane = threadIdx.x;
    float4 v = *(const float4*)(a + (size_t)row * DMODEL + lane * 4);
    if (b2) {
        float4 w = *(const float4*)(b2 + (size_t)row * DMODEL + lane * 4);
        v.x += w.x; v.y += w.y; v.z += w.z; v.w += w.w;
    }
    float s = v.x + v.y + v.z + v.w;
    #pragma unroll
    for (int off = 32; off; off >>= 1) s += __shfl_xor(s, off, 64);
    float m = s * (1.0f / DMODEL);
    float dx = v.x - m, dy = v.y - m, dz = v.z - m, dw = v.w - m;
    float s2 = dx * dx + dy * dy + dz * dz + dw * dw;
    #pragma unroll
    for (int off = 32; off; off >>= 1) s2 += __shfl_xor(s2, off, 64);
    float r = rsqrtf(s2 * (1.0f / DMODEL) + 1e-5f);
    float4 gg = *(const float4*)(g + lane * 4);
    float4 bb = *(const float4*)(be + lane * 4);
    float y0 = dx * r * gg.x + bb.x, y1 = dy * r * gg.y + bb.y;
    float y2 = dz * r * gg.z + bb.z, y3 = dw * r * gg.w + bb.w;
    if (dogelu) { y0 = gelu_f(y0); y1 = gelu_f(y1); y2 = gelu_f(y2); y3 = gelu_f(y3); }
    if (o32) *(float4*)(o32 + (size_t)row * DMODEL + lane * 4) = make_float4(y0, y1, y2, y3);
    if (o16) {
        ushort4 u; u.x = f2bf(y0); u.y = f2bf(y1); u.z = f2bf(y2); u.w = f2bf(y3);
        *(ushort4*)(o16 + (size_t)row * DMODEL + lane * 4) = u;
    }
}

__device__ __forceinline__ void wave_ln4(float* v, const float* g, const float* b,
                                         int lane, bool dogelu)
{
    float s = v[0] + v[1] + v[2] + v[3];
    #pragma unroll
    for (int off = 32; off; off >>= 1) s += __shfl_xor(s, off, 64);
    float m = s * (1.0f / 256.0f);
    float d0 = v[0] - m, d1 = v[1] - m, d2 = v[2] - m, d3 = v[3] - m;
    float s2 = d0 * d0 + d1 * d1 + d2 * d2 + d3 * d3;
    #pragma unroll
    for (int off = 32; off; off >>= 1) s2 += __shfl_xor(s2, off, 64);
    float r = rsqrtf(s2 * (1.0f / 256.0f) + 1e-5f);
    v[0] = d0 * r * g[lane] + b[lane];
    v[1] = d1 * r * g[lane + 64] + b[lane + 64];
    v[2] = d2 * r * g[lane + 128] + b[lane + 128];
    v[3] = d3 * r * g[lane + 192] + b[lane + 192];
    if (dogelu) {
        v[0] = gelu_f(v[0]); v[1] = gelu_f(v[1]);
        v[2] = gelu_f(v[2]); v[3] = gelu_f(v[3]);
    }
}

// Whole head in one launch. grid=4 blocks x 256 thr; each wave owns one row (b index),
// no cross-wave data => no barriers.
__global__ __launch_bounds__(256) void head_kernel(
    const float* __restrict__ x32, const float* __restrict__ features,
    const float* __restrict__ feat_w, const float* __restrict__ feat_b,
    const float* __restrict__ feat_ln_g, const float* __restrict__ feat_ln_b,
    const float* __restrict__ h1_w, const float* __restrict__ h1_b,
    const float* __restrict__ h_ln_g, const float* __restrict__ h_ln_b,
    const float* __restrict__ h2_w, const float* __restrict__ h2_b,
    const float* __restrict__ h3_w, const float* __restrict__ h3_b,
    float* __restrict__ outp)
{
    __shared__ float xcL[4][256], frL[4][256], h1L[4][256], h2L[4][128];
    const int wv = threadIdx.x >> 6, lane = threadIdx.x & 63;
    const int row = blockIdx.x * 4 + wv;   // 0..15

    // stage xc = x[row, S/2, :]
    for (int c = lane; c < 256; c += 64)
        xcL[wv][c] = x32[((size_t)row * S_LEN + S_LEN / 2) * DMODEL + c];

    // fr = gelu(LN(features @ feat_w^T + feat_b))
    float v[4];
    const float* frow = features + (size_t)row * 66;
    #pragma unroll
    for (int c = 0; c < 4; ++c) {
        int n = lane + c * 64;
        float s = feat_b[n];
        const float* w = feat_w + (size_t)n * 66;
        for (int k = 0; k < 66; ++k) s = fmaf(frow[k], w[k], s);
        v[c] = s;
    }
    wave_ln4(v, feat_ln_g, feat_ln_b, lane, true);
    #pragma unroll
    for (int c = 0; c < 4; ++c) frL[wv][lane + c * 64] = v[c];

    // h1 = gelu(LN([xc|fr] @ h1_w^T + h1_b))
    #pragma unroll
    for (int c = 0; c < 4; ++c) {
        int n = lane + c * 64;
        float s = h1_b[n];
        const float* w = h1_w + (size_t)n * 512;
        for (int k = 0; k < 256; ++k) s = fmaf(xcL[wv][k], w[k], s);
        for (int k = 0; k < 256; ++k) s = fmaf(frL[wv][k], w[256 + k], s);
        v[c] = s;
    }
    wave_ln4(v, h_ln_g, h_ln_b, lane, true);
    #pragma unroll
    for (int c = 0; c < 4; ++c) h1L[wv][lane + c * 64] = v[c];

    // h2 = gelu(h1 @ h2_w^T + h2_b)   (128 cols: c=0,1)
    #pragma unroll
    for (int c = 0; c < 2; ++c) {
        int n = lane + c * 64;
        float s = h2_b[n];
        const float* w = h2_w + (size_t)n * 256;
        for (int k = 0; k < 256; ++k) s = fmaf(h1L[wv][k], w[k], s);
        h2L[wv][n] = gelu_f(s);
    }

    // out[row] = h2 @ h3_w^T + h3_b
    float partial = h2L[wv][lane] * h3_w[lane] + h2L[wv][lane + 64] * h3_w[lane + 64];
    #pragma unroll
    for (int off = 32; off; off >>= 1) partial += __shfl_xor(partial, off, 64);
    if (lane == 0) outp[row] = partial + h3_b[0];
}

__global__ __launch_bounds__(256) void cvt_kernel(
    const float4* __restrict__ src, ushort4* __restrict__ dst, int n4)
{
    int i = blockIdx.x * 256 + threadIdx.x;
    if (i < n4) {
        float4 f = src[i];
        ushort4 u; u.x = f2bf(f.x); u.y = f2bf(f.y); u.z = f2bf(f.z); u.w = f2bf(f.w);
        dst[i] = u;
    }
}

// Wcat[l][n][si*256+d] = sum_j fus_w[l][n][si*256+j] * attn_out_w[l][si][j][d]
__global__ __launch_bounds__(256) void wc_kernel(
    const float* __restrict__ fus_w, const float* __restrict__ ao_w, ushortT* __restrict__ Wcat)
{
    int bid = blockIdx.x;
    int n = bid & 255, ls = bid >> 8;
    int l = ls >> 2, si = ls & 3;
    int d = threadIdx.x;
    const float* fw = fus_w + ((size_t)l * 256 + n) * 1024 + si * 256;
    const float* ao = ao_w + (size_t)ls * 65536 + d;
    float s = 0.f;
    for (int j = 0; j < 256; ++j) s = fmaf(fw[j], ao[(size_t)j * 256], s);
    Wcat[((size_t)l * 256 + n) * 1024 + si * 256 + d] = f2bf(s);
}

__global__ __launch_bounds__(256) void qkvbias_kernel(
    const float* __restrict__ aib, const float* __restrict__ aiw,
    const float* __restrict__ se, float* __restrict__ eb)
{
    int i = blockIdx.x * 256 + threadIdx.x;   // < 12288
    int r = i % 3072, si = r / 768;
    const float* w = aiw + (size_t)i * 256;
    const float* s = se + si * 256;
    float acc = aib[i];
    for (int k = 0; k < 256; ++k) acc = fmaf(s[k], w[k], acc);
    eb[i] = acc;
}

__global__ __launch_bounds__(256) void fusbias_kernel(
    const float* __restrict__ fus_b, const float* __restrict__ fus_w,
    const float* __restrict__ aob, float* __restrict__ fb)
{
    int l = blockIdx.x, n = threadIdx.x;
    const float* w = fus_w + ((size_t)l * 256 + n) * 1024;
    const float* o = aob + (size_t)l * 1024;
    float acc = fus_b[l * 256 + n];
    for (int j = 0; j < 1024; ++j) acc = fmaf(o[j], w[j], acc);
    fb[l * 256 + n] = acc;
}

static inline void mgemm(hipStream_t s, const ushortT* A, int lda, const ushortT* W, int ldw,
                         const float* bias, const float* betaC, float* o32, ushortT* o16,
                         int ldc, int M, int N, int K, int flags)
{
    if (N % 128 == 0) {
        dim3 g(M / 128, N / 128);
        hipLaunchKernelGGL(mfma_gemm<128>, g, dim3(256), 0, s,
                           A, lda, W, ldw, bias, betaC, o32, o16, ldc, K, flags);
    } else {
        dim3 g(M / 128, N / 64);
        hipLaunchKernelGGL(mfma_gemm<64>, g, dim3(256), 0, s,
                           A, lda, W, ldw, bias, betaC, o32, o16, ldc, K, flags);
    }
}

static inline void cvt(hipStream_t s, const float* src, ushortT* dst, size_t n)
{
    int n4 = (int)(n / 4);
    hipLaunchKernelGGL(cvt_kernel, dim3((n4 + 255) / 256), dim3(256), 0, s,
                       (const float4*)src, (ushort4*)dst, n4);
}

extern "C" void kernel_launch(void* const* d_in, const int* in_sizes, int n_in,
                              void* d_out, int out_size, void* d_ws, size_t ws_size,
                              hipStream_t stream)
{
    const float* emb        = (const float*)d_in[0];
    const float* features   = (const float*)d_in[1];
    const float* ip_w       = (const float*)d_in[2];
    const float* ip_b       = (const float*)d_in[3];
    const float* scale_emb  = (const float*)d_in[4];
    const float* attn_in_w  = (const float*)d_in[5];
    const float* attn_in_b  = (const float*)d_in[6];
    const float* attn_out_w = (const float*)d_in[7];
    const float* attn_out_b = (const float*)d_in[8];
    const float* fus_w      = (const float*)d_in[9];
    const float* fus_b      = (const float*)d_in[10];
    const float* ffn_w1     = (const float*)d_in[11];
    const float* ffn_b1     = (const float*)d_in[12];
    const float* ffn_w2     = (const float*)d_in[13];
    const float* ffn_b2     = (const float*)d_in[14];
    const float* n1_g       = (const float*)d_in[15];
    const float* n1_b       = (const float*)d_in[16];
    const float* n2_g       = (const float*)d_in[17];
    const float* n2_b       = (const float*)d_in[18];
    const float* feat_w     = (const float*)d_in[19];
    const float* feat_b     = (const float*)d_in[20];
    const float* feat_ln_g  = (const float*)d_in[21];
    const float* feat_ln_b  = (const float*)d_in[22];
    const float* h1_w       = (const float*)d_in[23];
    const float* h1_b       = (const float*)d_in[24];
    const float* h_ln_g     = (const float*)d_in[25];
    const float* h_ln_b     = (const float*)d_in[26];
    const float* h2_w       = (const float*)d_in[27];
    const float* h2_b       = (const float*)d_in[28];
    const float* h3_w       = (const float*)d_in[29];
    const float* h3_b       = (const float*)d_in[30];
    float* outp = (float*)d_out;

    const int Btok = 16 * S_LEN;   // 8192

    // ---- workspace carve-up ----
    char* p = (char*)d_ws;
    float* x32     = (float*)p;              p += (size_t)Btok * DMODEL * 4;
    float* fused32 = (float*)p;              p += (size_t)Btok * DMODEL * 4;
    float* effqkvb = (float*)p;              p += 12288 * 4;
    float* fusbias = (float*)p;              p += 1024 * 4;
    ushortT* xbf   = (ushortT*)p;            p += (size_t)Btok * DMODEL * 2;
    ushortT* qkv2  = (ushortT*)p;            p += (size_t)Btok * 1536 * 2;   // pair buffer
    ushortT* ocat  = (ushortT*)p;            p += (size_t)Btok * 1024 * 2;
    ushortT* ipw_bf  = (ushortT*)p;          p += (size_t)DMODEL * 640 * 2;
    ushortT* aiw_bf  = (ushortT*)p;          p += (size_t)16 * 768 * 256 * 2;
    ushortT* wcat_bf = (ushortT*)p;          p += (size_t)4 * 256 * 1024 * 2;
    ushortT* f1_bf   = (ushortT*)p;          p += (size_t)4 * 1024 * 256 * 2;
    ushortT* f2_bf   = (ushortT*)p;          p += (size_t)4 * 256 * 1024 * 2;
    ushortT* embbf = qkv2;                   // alias: emb_bf dead before layer-0 qkv
    ushortT* midbf = ocat;                   // alias: ffn mid after ocat consumed

    // ---- precompute ----
    cvt(stream, emb, embbf, (size_t)Btok * 640);
    cvt(stream, ip_w, ipw_bf, (size_t)DMODEL * 640);
    cvt(stream, attn_in_w, aiw_bf, (size_t)16 * 768 * 256);
    cvt(stream, ffn_w1, f1_bf, (size_t)4 * 1024 * 256);
    cvt(stream, ffn_w2, f2_bf, (size_t)4 * 256 * 1024);
    hipLaunchKernelGGL(wc_kernel, dim3(4096), dim3(256), 0, stream, fus_w, attn_out_w, wcat_bf);
    hipLaunchKernelGGL(qkvbias_kernel, dim3(48), dim3(256), 0, stream,
                       attn_in_b, attn_in_w, scale_emb, effqkvb);
    hipLaunchKernelGGL(fusbias_kernel, dim3(4), dim3(256), 0, stream,
                       fus_b, fus_w, attn_out_b, fusbias);

    // ---- x = emb @ ip_w^T + ip_b + PE ----
    mgemm(stream, embbf, 640, ipw_bf, 640, ip_b, nullptr, x32, xbf,
          DMODEL, Btok, DMODEL, 640, F_PE);

    // contiguous scale pairs {0,1} and {2,3}: one N=1536 qkv GEMM per pair
    static const int RADII[NSCALE] = {5, 10, 20, 50};

    for (int l = 0; l < NLAYER; ++l) {
        for (int pr = 0; pr < 2; ++pr) {
            const int ls0 = l * NSCALE + pr * 2;
            // qkv for BOTH scales of the pair in one launch (W rows contiguous)
            mgemm(stream, xbf, DMODEL, aiw_bf + (size_t)ls0 * 768 * 256, DMODEL,
                  effqkvb + (size_t)ls0 * 768, nullptr, nullptr, qkv2,
                  1536, Btok, 1536, DMODEL, 0);
            hipLaunchKernelGGL(attn_mfma, dim3(2048), dim3(256), 0, stream,
                               qkv2, ocat,
                               pr * 2, RADII[pr * 2], pr * 2 + 1, RADII[pr * 2 + 1]);
        }
        // fused = ocat @ Wcat[l]^T + fusbias[l]
        mgemm(stream, ocat, 1024, wcat_bf + (size_t)l * 256 * 1024, 1024,
              fusbias + l * DMODEL, nullptr, fused32, nullptr,
              DMODEL, Btok, DMODEL, 1024, 0);
        hipLaunchKernelGGL(ln_wave, dim3(Btok), dim3(64), 0, stream,
                           x32, fused32, n1_g + l * DMODEL, n1_b + l * DMODEL, x32, xbf, 0);
        mgemm(stream, xbf, DMODEL, f1_bf + (size_t)l * 1024 * 256, DMODEL,
              ffn_b1 + (size_t)l * 1024, nullptr, nullptr, midbf,
              1024, Btok, 1024, DMODEL, F_GELU);
        mgemm(stream, midbf, 1024, f2_bf + (size_t)l * 256 * 1024, 1024,
              ffn_b2 + (size_t)l * DMODEL, nullptr, fused32, nullptr,
              DMODEL, Btok, DMODEL, 1024, 0);
        hipLaunchKernelGGL(ln_wave, dim3(Btok), dim3(64), 0, stream,
                           x32, fused32, n2_g + l * DMODEL, n2_b + l * DMODEL, x32, xbf, 0);
    }

    // ---- head: one kernel ----
    hipLaunchKernelGGL(head_kernel, dim3(4), dim3(256), 0, stream,
                       x32, features, feat_w, feat_b, feat_ln_g, feat_ln_b,
                       h1_w, h1_b, h_ln_g, h_ln_b, h2_w, h2_b, h3_w, h3_b, outp);
}

// Round 6
// 903.709 us; speedup vs baseline: 7.4961x; 1.2296x over previous
//
#include <hip/hip_runtime.h>
#include <math.h>

#define S_LEN 512
#define DMODEL 256
#define NHEAD 8
#define HDIM 32
#define NLAYER 4
#define NSCALE 4

typedef unsigned short ushortT;
typedef unsigned int uintT;
typedef short bf16x8 __attribute__((ext_vector_type(8)));
typedef float f32x4 __attribute__((ext_vector_type(4)));

enum { F_PE = 1, F_BETA = 2, F_GELU = 4 };

__device__ __forceinline__ float gelu_f(float x) {
    return 0.5f * x * (1.0f + erff(x * 0.70710678118654752440f));
}
__device__ __forceinline__ ushortT f2bf(float f) {
    union { float f; uintT i; } u; u.f = f;
    uintT r = u.i + 0x7FFF + ((u.i >> 16) & 1);   // RNE
    return (ushortT)(r >> 16);
}
__device__ __forceinline__ int swz(int r) { return (r & 3) ^ ((r >> 2) & 3); }

#define GLD16(g, l) \
    __builtin_amdgcn_global_load_lds((const __attribute__((address_space(1))) void*)(g), \
                                     (__attribute__((address_space(3))) void*)(l), 16, 0, 0)

// C[M,N] = op(A[M,K]bf16 @ W[N,K]bf16^T + bias) ; M%BM==0, N%BN==0, K%32==0
template<int BM, int BN>
__global__ __launch_bounds__(256) void mfma_gemm(
    const ushortT* __restrict__ A, int lda,
    const ushortT* __restrict__ W, int ldw,
    const float* __restrict__ bias,
    const float* __restrict__ betaC,
    float* __restrict__ out32,
    ushortT* __restrict__ out16,
    int ldc, int K, int flags)
{
    constexpr int MI = BM / 32;
    constexpr int NI = BN / 32;
    __shared__ __align__(16) ushortT As[BM * 32];
    __shared__ __align__(16) ushortT Bs[BN * 32];
    const int tid = threadIdx.x;
    const int wave = tid >> 6, lane = tid & 63;
    const int l15 = lane & 15, qd = lane >> 4;
    const int m0 = blockIdx.x * BM, n0 = blockIdx.y * BN;
    const int wm = (wave >> 1) * (BM / 2), wn = (wave & 1) * (BN / 2);

    f32x4 acc[MI][NI];
    #pragma unroll
    for (int i = 0; i < MI; ++i)
        #pragma unroll
        for (int j = 0; j < NI; ++j) acc[i][j] = (f32x4){0.f, 0.f, 0.f, 0.f};

    for (int k0 = 0; k0 < K; k0 += 32) {
        #pragma unroll
        for (int it = 0; it < BM / 64; ++it) {
            int c = it * 256 + tid;
            int m = c >> 2, s = c & 3;
            int kc = s ^ swz(m);
            const ushortT* g = A + (size_t)(m0 + m) * lda + k0 + kc * 8;
            GLD16(g, (ushortT*)As + (size_t)(it * 256 + wave * 64) * 8);
        }
        #pragma unroll
        for (int it = 0; it < BN / 64; ++it) {
            int c = it * 256 + tid;
            int n = c >> 2, s = c & 3;
            int kc = s ^ swz(n);
            const ushortT* g = W + (size_t)(n0 + n) * ldw + k0 + kc * 8;
            GLD16(g, (ushortT*)Bs + (size_t)(it * 256 + wave * 64) * 8);
        }
        __syncthreads();
        bf16x8 af[MI], bfr[NI];
        #pragma unroll
        for (int mi = 0; mi < MI; ++mi) {
            int r = wm + mi * 16 + l15;
            af[mi] = *(const bf16x8*)(As + r * 32 + (qd ^ swz(r)) * 8);
        }
        #pragma unroll
        for (int ni = 0; ni < NI; ++ni) {
            int r = wn + ni * 16 + l15;
            bfr[ni] = *(const bf16x8*)(Bs + r * 32 + (qd ^ swz(r)) * 8);
        }
        #pragma unroll
        for (int mi = 0; mi < MI; ++mi)
            #pragma unroll
            for (int ni = 0; ni < NI; ++ni)
                acc[mi][ni] = __builtin_amdgcn_mfma_f32_16x16x32_bf16(
                    af[mi], bfr[ni], acc[mi][ni], 0, 0, 0);
        __syncthreads();
    }

    #pragma unroll
    for (int mi = 0; mi < MI; ++mi) {
        #pragma unroll
        for (int ni = 0; ni < NI; ++ni) {
            int col = n0 + wn + ni * 16 + l15;
            float bv = bias ? bias[col] : 0.f;
            #pragma unroll
            for (int r = 0; r < 4; ++r) {
                int grow = m0 + wm + mi * 16 + qd * 4 + r;
                float v = acc[mi][ni][r] + bv;
                if (flags & F_BETA) v += betaC[(size_t)grow * ldc + col];
                if (flags & F_PE) {
                    int pos = grow & (S_LEN - 1);
                    float div = expf((float)(col & ~1) * (-9.210340371976184f / 256.0f));
                    float ang = (float)pos * div;
                    v += (col & 1) ? cosf(ang) : sinf(ang);
                }
                if (flags & F_GELU) v = gelu_f(v);
                if (out32) out32[(size_t)grow * ldc + col] = v;
                if (out16) out16[(size_t)grow * ldc + col] = f2bf(v);
            }
        }
    }
}

// MFMA banded attention. qkv: (B*S, 1536) = pair of scales (cols 0 / 768), each q|k|v*256.
__global__ __launch_bounds__(256) void attn_mfma(
    const ushortT* __restrict__ qkv, ushortT* __restrict__ ocat,
    int si0, int r0, int si1, int r1)
{
    __shared__ __align__(16) ushortT Vt[32 * 216];     // [d][key_local], stride 216
    __shared__ __align__(16) ushortT Pl[4][16 * 168];  // per-wave P, stride 168
    const int bid = blockIdx.x;
    const int sp   = bid & 1;
    const int qblk = (bid >> 1) & 7;
    const int h    = (bid >> 4) & 7;
    const int b    = (bid >> 7) & 15;
    const int si = sp ? si1 : si0;
    const int r  = sp ? r1 : r0;
    const int lcol = sp * 768;
    const int tid = threadIdx.x;

    const int q0blk = qblk * 64;
    const int t0 = max(0, q0blk - r) >> 4;
    const int t1 = min(S_LEN - 1, q0blk + 63 + r) >> 4;
    const int nstage = (t1 - t0 + 2) * 16;   // +1 zero pad tile
    const int kmax = min(S_LEN - 1, t1 * 16 + 15);

    const ushortT* bbase = qkv + (size_t)(b * S_LEN) * 1536 + lcol;

    for (int idx = tid; idx < nstage * 4; idx += 256) {
        int row = idx >> 2, dch = idx & 3;
        int key = t0 * 16 + row;
        uint4 u = make_uint4(0, 0, 0, 0);
        if (key <= kmax)
            u = *(const uint4*)(bbase + (size_t)key * 1536 + 512 + h * HDIM + dch * 8);
        ushortT* dst = &Vt[(dch * 8) * 216 + row];
        uintT w[4] = {u.x, u.y, u.z, u.w};
        #pragma unroll
        for (int t = 0; t < 4; ++t) {
            dst[(2 * t) * 216]     = (ushortT)(w[t] & 0xffff);
            dst[(2 * t + 1) * 216] = (ushortT)(w[t] >> 16);
        }
    }

    const int wid = tid >> 6, lane = tid & 63;
    const int quad = lane >> 4, l15 = lane & 15;
    ushortT* Pw = Pl[wid];

    {
        uint4 z = make_uint4(0, 0, 0, 0);
        #pragma unroll
        for (int i = 0; i < 6; ++i) {
            int c = lane + i * 64;
            if (c < 336) ((uint4*)Pw)[c] = z;
        }
    }
    __syncthreads();

    const int q0w = q0blk + wid * 16;
    bf16x8 qf = *(const bf16x8*)(bbase + (size_t)(q0w + l15) * 1536 + h * HDIM + quad * 8);

    const int kt0 = max(0, q0w - r) >> 4;
    const int kt1 = min(S_LEN - 1, q0w + 15 + r) >> 4;
    const int nt = kt1 - kt0 + 1;

    f32x4 rs4 = (f32x4){0.f, 0.f, 0.f, 0.f};
    const unsigned span = (unsigned)(2 * r);

    for (int kt = kt0; kt <= kt1; ++kt) {
        int key = kt * 16 + l15;
        bf16x8 kf = *(const bf16x8*)(bbase + (size_t)key * 1536 + 256 + h * HDIM + quad * 8);
        f32x4 s4 = __builtin_amdgcn_mfma_f32_16x16x32_bf16(
            qf, kf, (f32x4){0.f, 0.f, 0.f, 0.f}, 0, 0, 0);
        #pragma unroll
        for (int rg = 0; rg < 4; ++rg) {
            int q = q0w + quad * 4 + rg;
            unsigned dd = (unsigned)(key - q + r);
            float p = (dd <= span)
                      ? __expf(fminf(s4[rg] * 0.17677669529663688f, 80.f)) : 0.f;
            rs4[rg] += p;
            Pw[(quad * 4 + rg) * 168 + (kt - kt0) * 16 + l15] = f2bf(p);
        }
    }

    #pragma unroll
    for (int m = 1; m < 16; m <<= 1) {
        #pragma unroll
        for (int rg = 0; rg < 4; ++rg) rs4[rg] += __shfl_xor(rs4[rg], m, 64);
    }

    f32x4 o0 = (f32x4){0.f, 0.f, 0.f, 0.f};
    f32x4 o1 = (f32x4){0.f, 0.f, 0.f, 0.f};
    const int basek = (kt0 - t0) * 16;
    const int nch = (nt + 1) >> 1;
    for (int c = 0; c < nch; ++c) {
        bf16x8 pa = *(const bf16x8*)(Pw + l15 * 168 + c * 32 + quad * 8);
        bf16x8 v0 = *(const bf16x8*)(&Vt[l15 * 216 + basek + c * 32 + quad * 8]);
        bf16x8 v1 = *(const bf16x8*)(&Vt[(l15 + 16) * 216 + basek + c * 32 + quad * 8]);
        o0 = __builtin_amdgcn_mfma_f32_16x16x32_bf16(pa, v0, o0, 0, 0, 0);
        o1 = __builtin_amdgcn_mfma_f32_16x16x32_bf16(pa, v1, o1, 0, 0, 0);
    }

    #pragma unroll
    for (int rg = 0; rg < 4; ++rg) {
        float inv = 1.0f / rs4[rg];
        int q = q0w + quad * 4 + rg;
        ushortT* op = ocat + ((size_t)(b * S_LEN) + q) * 1024 + si * DMODEL + h * HDIM;
        op[l15]      = f2bf(o0[rg] * inv);
        op[16 + l15] = f2bf(o1[rg] * inv);
    }
}

// one wave per 256-wide row: out = LN(a (+b2)) * g + be; dual fp32/bf16 write
__global__ __launch_bounds__(64) void ln_wave(
    const float* __restrict__ a, const float* __restrict__ b2,
    const float* __restrict__ g, const float* __restrict__ be,
    float* __restrict__ o32, ushortT* __restrict__ o16, int dogelu)
{
    const int row = blockIdx.x, lane = threadIdx.x;
    float4 v = *(const float4*)(a + (size_t)row * DMODEL + lane * 4);
    if (b2) {
        float4 w = *(const float4*)(b2 + (size_t)row * DMODEL + lane * 4);
        v.x += w.x; v.y += w.y; v.z += w.z; v.w += w.w;
    }
    float s = v.x + v.y + v.z + v.w;
    #pragma unroll
    for (int off = 32; off; off >>= 1) s += __shfl_xor(s, off, 64);
    float m = s * (1.0f / DMODEL);
    float dx = v.x - m, dy = v.y - m, dz = v.z - m, dw = v.w - m;
    float s2 = dx * dx + dy * dy + dz * dz + dw * dw;
    #pragma unroll
    for (int off = 32; off; off >>= 1) s2 += __shfl_xor(s2, off, 64);
    float r = rsqrtf(s2 * (1.0f / DMODEL) + 1e-5f);
    float4 gg = *(const float4*)(g + lane * 4);
    float4 bb = *(const float4*)(be + lane * 4);
    float y0 = dx * r * gg.x + bb.x, y1 = dy * r * gg.y + bb.y;
    float y2 = dz * r * gg.z + bb.z, y3 = dw * r * gg.w + bb.w;
    if (dogelu) { y0 = gelu_f(y0); y1 = gelu_f(y1); y2 = gelu_f(y2); y3 = gelu_f(y3); }
    if (o32) *(float4*)(o32 + (size_t)row * DMODEL + lane * 4) = make_float4(y0, y1, y2, y3);
    if (o16) {
        ushort4 u; u.x = f2bf(y0); u.y = f2bf(y1); u.z = f2bf(y2); u.w = f2bf(y3);
        *(ushort4*)(o16 + (size_t)row * DMODEL + lane * 4) = u;
    }
}

// generic small transpose: dst[c*R + r] = src[r*C + c]
__global__ __launch_bounds__(256) void transp_kernel(
    const float* __restrict__ src, float* __restrict__ dst, int R, int C)
{
    int i = blockIdx.x * 256 + threadIdx.x;
    if (i < R * C) {
        int r = i / C, c = i - r * C;
        dst[(size_t)c * R + r] = src[i];
    }
}

// Whole head, 16 blocks (one per batch row) x 256 thr; weights pre-transposed
// so every global load is coalesced across threads.
__global__ __launch_bounds__(256) void head_kernel(
    const float* __restrict__ x32, const float* __restrict__ features,
    const float* __restrict__ feat_wT, const float* __restrict__ feat_b,
    const float* __restrict__ feat_ln_g, const float* __restrict__ feat_ln_b,
    const float* __restrict__ h1_wT, const float* __restrict__ h1_b,
    const float* __restrict__ h_ln_g, const float* __restrict__ h_ln_b,
    const float* __restrict__ h2_wT, const float* __restrict__ h2_b,
    const float* __restrict__ h3_w, const float* __restrict__ h3_b,
    float* __restrict__ outp)
{
    __shared__ float xcat[512];
    __shared__ float h1s[256];
    __shared__ float red[8];
    __shared__ float r2[128];
    const int r = blockIdx.x, t = threadIdx.x;
    const int wid = t >> 6, lane = t & 63;

    // xc = x[r, S/2, :]
    xcat[t] = x32[((size_t)r * S_LEN + S_LEN / 2) * DMODEL + t];

    // fr = gelu(LN(features @ feat_w^T + feat_b))
    const float* frow = features + (size_t)r * 66;
    float s = feat_b[t];
    for (int k = 0; k < 66; ++k) s = fmaf(frow[k], feat_wT[k * 256 + t], s);
    {
        float a = s, a2 = s * s;
        #pragma unroll
        for (int off = 32; off; off >>= 1) { a += __shfl_xor(a, off, 64); a2 += __shfl_xor(a2, off, 64); }
        if (lane == 0) { red[wid] = a; red[wid + 4] = a2; }
        __syncthreads();
        float ts = red[0] + red[1] + red[2] + red[3];
        float ts2 = red[4] + red[5] + red[6] + red[7];
        float m = ts * (1.0f / 256.0f);
        float var = ts2 * (1.0f / 256.0f) - m * m;
        float rstd = rsqrtf(var + 1e-5f);
        float v = (s - m) * rstd * feat_ln_g[t] + feat_ln_b[t];
        xcat[256 + t] = gelu_f(v);
        __syncthreads();
    }

    // h1 = gelu(LN(xcat @ h1_w^T + h1_b))
    s = h1_b[t];
    #pragma unroll 8
    for (int k = 0; k < 512; ++k) s = fmaf(xcat[k], h1_wT[k * 256 + t], s);
    {
        float a = s, a2 = s * s;
        #pragma unroll
        for (int off = 32; off; off >>= 1) { a += __shfl_xor(a, off, 64); a2 += __shfl_xor(a2, off, 64); }
        if (lane == 0) { red[wid] = a; red[wid + 4] = a2; }
        __syncthreads();
        float ts = red[0] + red[1] + red[2] + red[3];
        float ts2 = red[4] + red[5] + red[6] + red[7];
        float m = ts * (1.0f / 256.0f);
        float var = ts2 * (1.0f / 256.0f) - m * m;
        float rstd = rsqrtf(var + 1e-5f);
        float v = (s - m) * rstd * h_ln_g[t] + h_ln_b[t];
        h1s[t] = gelu_f(v);
        __syncthreads();
    }

    // h2 = gelu(h1 @ h2_w^T + h2_b); fold h3 weight
    if (t < 128) {
        float v = h2_b[t];
        #pragma unroll 8
        for (int k = 0; k < 256; ++k) v = fmaf(h1s[k], h2_wT[k * 128 + t], v);
        r2[t] = gelu_f(v) * h3_w[t];
    }
    __syncthreads();
    if (t < 64) {
        float p = r2[t] + r2[t + 64];
        #pragma unroll
        for (int off = 32; off; off >>= 1) p += __shfl_xor(p, off, 64);
        if (t == 0) outp[r] = p + h3_b[0];
    }
}

__global__ __launch_bounds__(256) void cvt_kernel(
    const float4* __restrict__ src, ushort4* __restrict__ dst, int n4)
{
    int i = blockIdx.x * 256 + threadIdx.x;
    if (i < n4) {
        float4 f = src[i];
        ushort4 u; u.x = f2bf(f.x); u.y = f2bf(f.y); u.z = f2bf(f.z); u.w = f2bf(f.w);
        dst[i] = u;
    }
}

// Wcat[l][n][si*256+d] = sum_j fus_w[l][n][si*256+j] * attn_out_w[l][si][j][d]
__global__ __launch_bounds__(256) void wc_kernel(
    const float* __restrict__ fus_w, const float* __restrict__ ao_w, ushortT* __restrict__ Wcat)
{
    int bid = blockIdx.x;
    int n = bid & 255, ls = bid >> 8;
    int l = ls >> 2, si = ls & 3;
    int d = threadIdx.x;
    const float* fw = fus_w + ((size_t)l * 256 + n) * 1024 + si * 256;
    const float* ao = ao_w + (size_t)ls * 65536 + d;
    float s = 0.f;
    for (int j = 0; j < 256; ++j) s = fmaf(fw[j], ao[(size_t)j * 256], s);
    Wcat[((size_t)l * 256 + n) * 1024 + si * 256 + d] = f2bf(s);
}

__global__ __launch_bounds__(256) void qkvbias_kernel(
    const float* __restrict__ aib, const float* __restrict__ aiw,
    const float* __restrict__ se, float* __restrict__ eb)
{
    int i = blockIdx.x * 256 + threadIdx.x;   // < 12288
    int r = i % 3072, si = r / 768;
    const float* w = aiw + (size_t)i * 256;
    const float* s = se + si * 256;
    float acc = aib[i];
    for (int k = 0; k < 256; ++k) acc = fmaf(s[k], w[k], acc);
    eb[i] = acc;
}

__global__ __launch_bounds__(256) void fusbias_kernel(
    const float* __restrict__ fus_b, const float* __restrict__ fus_w,
    const float* __restrict__ aob, float* __restrict__ fb)
{
    int l = blockIdx.x, n = threadIdx.x;
    const float* w = fus_w + ((size_t)l * 256 + n) * 1024;
    const float* o = aob + (size_t)l * 1024;
    float acc = fus_b[l * 256 + n];
    for (int j = 0; j < 1024; ++j) acc = fmaf(o[j], w[j], acc);
    fb[l * 256 + n] = acc;
}

static inline void mgemm(hipStream_t s, const ushortT* A, int lda, const ushortT* W, int ldw,
                         const float* bias, const float* betaC, float* o32, ushortT* o16,
                         int ldc, int M, int N, int K, int flags)
{
    if (N >= 1024 && N % 128 == 0) {
        dim3 g(M / 128, N / 128);
        hipLaunchKernelGGL((mfma_gemm<128, 128>), g, dim3(256), 0, s,
                           A, lda, W, ldw, bias, betaC, o32, o16, ldc, K, flags);
    } else {
        dim3 g(M / 64, N / 64);
        hipLaunchKernelGGL((mfma_gemm<64, 64>), g, dim3(256), 0, s,
                           A, lda, W, ldw, bias, betaC, o32, o16, ldc, K, flags);
    }
}

static inline void cvt(hipStream_t s, const float* src, ushortT* dst, size_t n)
{
    int n4 = (int)(n / 4);
    hipLaunchKernelGGL(cvt_kernel, dim3((n4 + 255) / 256), dim3(256), 0, s,
                       (const float4*)src, (ushort4*)dst, n4);
}

extern "C" void kernel_launch(void* const* d_in, const int* in_sizes, int n_in,
                              void* d_out, int out_size, void* d_ws, size_t ws_size,
                              hipStream_t stream)
{
    const float* emb        = (const float*)d_in[0];
    const float* features   = (const float*)d_in[1];
    const float* ip_w       = (const float*)d_in[2];
    const float* ip_b       = (const float*)d_in[3];
    const float* scale_emb  = (const float*)d_in[4];
    const float* attn_in_w  = (const float*)d_in[5];
    const float* attn_in_b  = (const float*)d_in[6];
    const float* attn_out_w = (const float*)d_in[7];
    const float* attn_out_b = (const float*)d_in[8];
    const float* fus_w      = (const float*)d_in[9];
    const float* fus_b      = (const float*)d_in[10];
    const float* ffn_w1     = (const float*)d_in[11];
    const float* ffn_b1     = (const float*)d_in[12];
    const float* ffn_w2     = (const float*)d_in[13];
    const float* ffn_b2     = (const float*)d_in[14];
    const float* n1_g       = (const float*)d_in[15];
    const float* n1_b       = (const float*)d_in[16];
    const float* n2_g       = (const float*)d_in[17];
    const float* n2_b       = (const float*)d_in[18];
    const float* feat_w     = (const float*)d_in[19];
    const float* feat_b     = (const float*)d_in[20];
    const float* feat_ln_g  = (const float*)d_in[21];
    const float* feat_ln_b  = (const float*)d_in[22];
    const float* h1_w       = (const float*)d_in[23];
    const float* h1_b       = (const float*)d_in[24];
    const float* h_ln_g     = (const float*)d_in[25];
    const float* h_ln_b     = (const float*)d_in[26];
    const float* h2_w       = (const float*)d_in[27];
    const float* h2_b       = (const float*)d_in[28];
    const float* h3_w       = (const float*)d_in[29];
    const float* h3_b       = (const float*)d_in[30];
    float* outp = (float*)d_out;

    const int Btok = 16 * S_LEN;   // 8192

    // ---- workspace carve-up ----
    char* p = (char*)d_ws;
    float* x32     = (float*)p;              p += (size_t)Btok * DMODEL * 4;
    float* fused32 = (float*)p;              p += (size_t)Btok * DMODEL * 4;
    float* effqkvb = (float*)p;              p += 12288 * 4;
    float* fusbias = (float*)p;              p += 1024 * 4;
    float* featwT  = (float*)p;              p += 66 * 256 * 4;
    float* h1wT    = (float*)p;              p += 512 * 256 * 4;
    float* h2wT    = (float*)p;              p += 256 * 128 * 4;
    ushortT* xbf   = (ushortT*)p;            p += (size_t)Btok * DMODEL * 2;
    ushortT* qkv2  = (ushortT*)p;            p += (size_t)Btok * 1536 * 2;   // pair buffer
    ushortT* ocat  = (ushortT*)p;            p += (size_t)Btok * 1024 * 2;
    ushortT* ipw_bf  = (ushortT*)p;          p += (size_t)DMODEL * 640 * 2;
    ushortT* aiw_bf  = (ushortT*)p;          p += (size_t)16 * 768 * 256 * 2;
    ushortT* wcat_bf = (ushortT*)p;          p += (size_t)4 * 256 * 1024 * 2;
    ushortT* f1_bf   = (ushortT*)p;          p += (size_t)4 * 1024 * 256 * 2;
    ushortT* f2_bf   = (ushortT*)p;          p += (size_t)4 * 256 * 1024 * 2;
    ushortT* embbf = qkv2;                   // alias: emb_bf dead before layer-0 qkv
    ushortT* midbf = ocat;                   // alias: ffn mid after ocat consumed

    // ---- precompute ----
    cvt(stream, emb, embbf, (size_t)Btok * 640);
    cvt(stream, ip_w, ipw_bf, (size_t)DMODEL * 640);
    cvt(stream, attn_in_w, aiw_bf, (size_t)16 * 768 * 256);
    cvt(stream, ffn_w1, f1_bf, (size_t)4 * 1024 * 256);
    cvt(stream, ffn_w2, f2_bf, (size_t)4 * 256 * 1024);
    hipLaunchKernelGGL(wc_kernel, dim3(4096), dim3(256), 0, stream, fus_w, attn_out_w, wcat_bf);
    hipLaunchKernelGGL(qkvbias_kernel, dim3(48), dim3(256), 0, stream,
                       attn_in_b, attn_in_w, scale_emb, effqkvb);
    hipLaunchKernelGGL(fusbias_kernel, dim3(4), dim3(256), 0, stream,
                       fus_b, fus_w, attn_out_b, fusbias);
    hipLaunchKernelGGL(transp_kernel, dim3(66), dim3(256), 0, stream, feat_w, featwT, 256, 66);
    hipLaunchKernelGGL(transp_kernel, dim3(512), dim3(256), 0, stream, h1_w, h1wT, 256, 512);
    hipLaunchKernelGGL(transp_kernel, dim3(128), dim3(256), 0, stream, h2_w, h2wT, 128, 256);

    // ---- x = emb @ ip_w^T + ip_b + PE ----
    mgemm(stream, embbf, 640, ipw_bf, 640, ip_b, nullptr, x32, xbf,
          DMODEL, Btok, DMODEL, 640, F_PE);

    // contiguous scale pairs {0,1} and {2,3}: one N=1536 qkv GEMM per pair
    static const int RADII[NSCALE] = {5, 10, 20, 50};

    for (int l = 0; l < NLAYER; ++l) {
        for (int pr = 0; pr < 2; ++pr) {
            const int ls0 = l * NSCALE + pr * 2;
            mgemm(stream, xbf, DMODEL, aiw_bf + (size_t)ls0 * 768 * 256, DMODEL,
                  effqkvb + (size_t)ls0 * 768, nullptr, nullptr, qkv2,
                  1536, Btok, 1536, DMODEL, 0);
            hipLaunchKernelGGL(attn_mfma, dim3(2048), dim3(256), 0, stream,
                               qkv2, ocat,
                               pr * 2, RADII[pr * 2], pr * 2 + 1, RADII[pr * 2 + 1]);
        }
        // fused = ocat @ Wcat[l]^T + fusbias[l]
        mgemm(stream, ocat, 1024, wcat_bf + (size_t)l * 256 * 1024, 1024,
              fusbias + l * DMODEL, nullptr, fused32, nullptr,
              DMODEL, Btok, DMODEL, 1024, 0);
        hipLaunchKernelGGL(ln_wave, dim3(Btok), dim3(64), 0, stream,
                           x32, fused32, n1_g + l * DMODEL, n1_b + l * DMODEL, x32, xbf, 0);
        mgemm(stream, xbf, DMODEL, f1_bf + (size_t)l * 1024 * 256, DMODEL,
              ffn_b1 + (size_t)l * 1024, nullptr, nullptr, midbf,
              1024, Btok, 1024, DMODEL, F_GELU);
        mgemm(stream, midbf, 1024, f2_bf + (size_t)l * 256 * 1024, 1024,
              ffn_b2 + (size_t)l * DMODEL, nullptr, fused32, nullptr,
              DMODEL, Btok, DMODEL, 1024, 0);
        hipLaunchKernelGGL(ln_wave, dim3(Btok), dim3(64), 0, stream,
                           x32, fused32, n2_g + l * DMODEL, n2_b + l * DMODEL, x32, xbf, 0);
    }

    // ---- head: one kernel, 16 blocks ----
    hipLaunchKernelGGL(head_kernel, dim3(16), dim3(256), 0, stream,
                       x32, features, featwT, feat_b, feat_ln_g, feat_ln_b,
                       h1wT, h1_b, h_ln_g, h_ln_b, h2wT, h2_b, h3_w, h3_b, outp);
}

// Round 7
// 882.583 us; speedup vs baseline: 7.6756x; 1.0239x over previous
//
#include <hip/hip_runtime.h>
#include <math.h>

#define S_LEN 512
#define DMODEL 256
#define NHEAD 8
#define HDIM 32
#define NLAYER 4
#define NSCALE 4

typedef unsigned short ushortT;
typedef unsigned int uintT;
typedef short bf16x8 __attribute__((ext_vector_type(8)));
typedef float f32x4 __attribute__((ext_vector_type(4)));

enum { F_PE = 1, F_BETA = 2, F_GELU = 4 };

__device__ __forceinline__ float gelu_f(float x) {
    return 0.5f * x * (1.0f + erff(x * 0.70710678118654752440f));
}
__device__ __forceinline__ ushortT f2bf(float f) {
    union { float f; uintT i; } u; u.f = f;
    uintT r = u.i + 0x7FFF + ((u.i >> 16) & 1);   // RNE
    return (ushortT)(r >> 16);
}
__device__ __forceinline__ int swz(int r) { return (r & 3) ^ ((r >> 2) & 3); }

#define GLD16(g, l) \
    __builtin_amdgcn_global_load_lds((const __attribute__((address_space(1))) void*)(g), \
                                     (__attribute__((address_space(3))) void*)(l), 16, 0, 0)

// C[M,N] = op(A[M,K]bf16 @ W[N,K]bf16^T + bias) ; M%BM==0, N%BN==0, K%32==0
template<int BM, int BN>
__global__ __launch_bounds__(256) void mfma_gemm(
    const ushortT* __restrict__ A, int lda,
    const ushortT* __restrict__ W, int ldw,
    const float* __restrict__ bias,
    const float* __restrict__ betaC,
    float* __restrict__ out32,
    ushortT* __restrict__ out16,
    int ldc, int K, int flags)
{
    constexpr int MI = BM / 32;
    constexpr int NI = BN / 32;
    __shared__ __align__(16) ushortT As[BM * 32];
    __shared__ __align__(16) ushortT Bs[BN * 32];
    const int tid = threadIdx.x;
    const int wave = tid >> 6, lane = tid & 63;
    const int l15 = lane & 15, qd = lane >> 4;
    const int m0 = blockIdx.x * BM, n0 = blockIdx.y * BN;
    const int wm = (wave >> 1) * (BM / 2), wn = (wave & 1) * (BN / 2);

    f32x4 acc[MI][NI];
    #pragma unroll
    for (int i = 0; i < MI; ++i)
        #pragma unroll
        for (int j = 0; j < NI; ++j) acc[i][j] = (f32x4){0.f, 0.f, 0.f, 0.f};

    for (int k0 = 0; k0 < K; k0 += 32) {
        #pragma unroll
        for (int it = 0; it < BM / 64; ++it) {
            int c = it * 256 + tid;
            int m = c >> 2, s = c & 3;
            int kc = s ^ swz(m);
            const ushortT* g = A + (size_t)(m0 + m) * lda + k0 + kc * 8;
            GLD16(g, (ushortT*)As + (size_t)(it * 256 + wave * 64) * 8);
        }
        #pragma unroll
        for (int it = 0; it < BN / 64; ++it) {
            int c = it * 256 + tid;
            int n = c >> 2, s = c & 3;
            int kc = s ^ swz(n);
            const ushortT* g = W + (size_t)(n0 + n) * ldw + k0 + kc * 8;
            GLD16(g, (ushortT*)Bs + (size_t)(it * 256 + wave * 64) * 8);
        }
        __syncthreads();
        bf16x8 af[MI], bfr[NI];
        #pragma unroll
        for (int mi = 0; mi < MI; ++mi) {
            int r = wm + mi * 16 + l15;
            af[mi] = *(const bf16x8*)(As + r * 32 + (qd ^ swz(r)) * 8);
        }
        #pragma unroll
        for (int ni = 0; ni < NI; ++ni) {
            int r = wn + ni * 16 + l15;
            bfr[ni] = *(const bf16x8*)(Bs + r * 32 + (qd ^ swz(r)) * 8);
        }
        #pragma unroll
        for (int mi = 0; mi < MI; ++mi)
            #pragma unroll
            for (int ni = 0; ni < NI; ++ni)
                acc[mi][ni] = __builtin_amdgcn_mfma_f32_16x16x32_bf16(
                    af[mi], bfr[ni], acc[mi][ni], 0, 0, 0);
        __syncthreads();
    }

    #pragma unroll
    for (int mi = 0; mi < MI; ++mi) {
        #pragma unroll
        for (int ni = 0; ni < NI; ++ni) {
            int col = n0 + wn + ni * 16 + l15;
            float bv = bias ? bias[col] : 0.f;
            #pragma unroll
            for (int r = 0; r < 4; ++r) {
                int grow = m0 + wm + mi * 16 + qd * 4 + r;
                float v = acc[mi][ni][r] + bv;
                if (flags & F_BETA) v += betaC[(size_t)grow * ldc + col];
                if (flags & F_PE) {
                    int pos = grow & (S_LEN - 1);
                    float div = expf((float)(col & ~1) * (-9.210340371976184f / 256.0f));
                    float ang = (float)pos * div;
                    v += (col & 1) ? cosf(ang) : sinf(ang);
                }
                if (flags & F_GELU) v = gelu_f(v);
                if (out32) out32[(size_t)grow * ldc + col] = v;
                if (out16) out16[(size_t)grow * ldc + col] = f2bf(v);
            }
        }
    }
}

// Batched MFMA for Wcat: for each ls=(l,si):
//   Wcat[l][n][si*256+j] = sum_p fus_w[l][n][si*256+p] * ao_w[ls][p][j]
// fp32 inputs converted inline; B transposed during LDS staging.
__global__ __launch_bounds__(256) void wc_mfma(
    const float* __restrict__ fus_w, const float* __restrict__ ao_w,
    ushortT* __restrict__ Wcat)
{
    __shared__ __align__(16) ushortT As[128 * 32];
    __shared__ __align__(16) ushortT Bs[128 * 32];
    const int z = blockIdx.z, l = z >> 2, si = z & 3;
    const int m0 = blockIdx.x * 128, n0 = blockIdx.y * 128;
    const int tid = threadIdx.x;
    const int wave = tid >> 6, lane = tid & 63;
    const int l15 = lane & 15, qd = lane >> 4;
    const int wm = (wave >> 1) * 64, wn = (wave & 1) * 64;
    const float* Abase = fus_w + ((size_t)(l * 256) + m0) * 1024 + si * 256;
    const float* Bbase = ao_w + (size_t)z * 65536;

    f32x4 acc[4][4];
    #pragma unroll
    for (int i = 0; i < 4; ++i)
        #pragma unroll
        for (int j = 0; j < 4; ++j) acc[i][j] = (f32x4){0.f, 0.f, 0.f, 0.f};

    const int am = tid >> 1, ah = tid & 1;        // A: row, k-half(16)
    const int bp = tid >> 3, bj = (tid & 7) * 16; // B: p(k), j-group

    for (int k0 = 0; k0 < 256; k0 += 32) {
        #pragma unroll
        for (int j = 0; j < 2; ++j) {
            const float* src = Abase + (size_t)am * 1024 + k0 + ah * 16 + j * 8;
            float4 f0 = *(const float4*)src;
            float4 f1 = *(const float4*)(src + 4);
            int sc = ah * 2 + j;
            ushortT* d = As + am * 32 + (sc ^ swz(am)) * 8;
            ushort4 u0; u0.x = f2bf(f0.x); u0.y = f2bf(f0.y); u0.z = f2bf(f0.z); u0.w = f2bf(f0.w);
            ushort4 u1; u1.x = f2bf(f1.x); u1.y = f2bf(f1.y); u1.z = f2bf(f1.z); u1.w = f2bf(f1.w);
            *(ushort4*)d = u0; *(ushort4*)(d + 4) = u1;
        }
        #pragma unroll
        for (int c = 0; c < 4; ++c) {
            float4 f = *(const float4*)(Bbase + (size_t)(k0 + bp) * 256 + n0 + bj + c * 4);
            float vv[4] = {f.x, f.y, f.z, f.w};
            #pragma unroll
            for (int e = 0; e < 4; ++e) {
                int r = bj + c * 4 + e;
                Bs[r * 32 + (((bp >> 3) ^ swz(r)) * 8) + (bp & 7)] = f2bf(vv[e]);
            }
        }
        __syncthreads();
        bf16x8 af[4], bfr[4];
        #pragma unroll
        for (int mi = 0; mi < 4; ++mi) {
            int r = wm + mi * 16 + l15;
            af[mi] = *(const bf16x8*)(As + r * 32 + (qd ^ swz(r)) * 8);
        }
        #pragma unroll
        for (int ni = 0; ni < 4; ++ni) {
            int r = wn + ni * 16 + l15;
            bfr[ni] = *(const bf16x8*)(Bs + r * 32 + (qd ^ swz(r)) * 8);
        }
        #pragma unroll
        for (int mi = 0; mi < 4; ++mi)
            #pragma unroll
            for (int ni = 0; ni < 4; ++ni)
                acc[mi][ni] = __builtin_amdgcn_mfma_f32_16x16x32_bf16(
                    af[mi], bfr[ni], acc[mi][ni], 0, 0, 0);
        __syncthreads();
    }

    #pragma unroll
    for (int mi = 0; mi < 4; ++mi) {
        #pragma unroll
        for (int ni = 0; ni < 4; ++ni) {
            int col = n0 + wn + ni * 16 + l15;
            #pragma unroll
            for (int r = 0; r < 4; ++r) {
                int row = m0 + wm + mi * 16 + qd * 4 + r;
                Wcat[((size_t)(l * 256) + row) * 1024 + si * 256 + col] =
                    f2bf(acc[mi][ni][r]);
            }
        }
    }
}

// MFMA banded attention. qkv: (B*S, 1536) = pair of scales (cols 0 / 768), each q|k|v*256.
__global__ __launch_bounds__(256) void attn_mfma(
    const ushortT* __restrict__ qkv, ushortT* __restrict__ ocat,
    int si0, int r0, int si1, int r1)
{
    __shared__ __align__(16) ushortT Vt[32 * 216];     // [d][key_local], stride 216
    __shared__ __align__(16) ushortT Pl[4][16 * 168];  // per-wave P, stride 168
    const int bid = blockIdx.x;
    const int sp   = bid & 1;
    const int qblk = (bid >> 1) & 7;
    const int h    = (bid >> 4) & 7;
    const int b    = (bid >> 7) & 15;
    const int si = sp ? si1 : si0;
    const int r  = sp ? r1 : r0;
    const int lcol = sp * 768;
    const int tid = threadIdx.x;

    const int q0blk = qblk * 64;
    const int t0 = max(0, q0blk - r) >> 4;
    const int t1 = min(S_LEN - 1, q0blk + 63 + r) >> 4;
    const int nstage = (t1 - t0 + 2) * 16;   // +1 zero pad tile
    const int kmax = min(S_LEN - 1, t1 * 16 + 15);

    const ushortT* bbase = qkv + (size_t)(b * S_LEN) * 1536 + lcol;

    for (int idx = tid; idx < nstage * 4; idx += 256) {
        int row = idx >> 2, dch = idx & 3;
        int key = t0 * 16 + row;
        uint4 u = make_uint4(0, 0, 0, 0);
        if (key <= kmax)
            u = *(const uint4*)(bbase + (size_t)key * 1536 + 512 + h * HDIM + dch * 8);
        ushortT* dst = &Vt[(dch * 8) * 216 + row];
        uintT w[4] = {u.x, u.y, u.z, u.w};
        #pragma unroll
        for (int t = 0; t < 4; ++t) {
            dst[(2 * t) * 216]     = (ushortT)(w[t] & 0xffff);
            dst[(2 * t + 1) * 216] = (ushortT)(w[t] >> 16);
        }
    }

    const int wid = tid >> 6, lane = tid & 63;
    const int quad = lane >> 4, l15 = lane & 15;
    ushortT* Pw = Pl[wid];

    {
        uint4 z = make_uint4(0, 0, 0, 0);
        #pragma unroll
        for (int i = 0; i < 6; ++i) {
            int c = lane + i * 64;
            if (c < 336) ((uint4*)Pw)[c] = z;
        }
    }
    __syncthreads();

    const int q0w = q0blk + wid * 16;
    bf16x8 qf = *(const bf16x8*)(bbase + (size_t)(q0w + l15) * 1536 + h * HDIM + quad * 8);

    const int kt0 = max(0, q0w - r) >> 4;
    const int kt1 = min(S_LEN - 1, q0w + 15 + r) >> 4;
    const int nt = kt1 - kt0 + 1;

    f32x4 rs4 = (f32x4){0.f, 0.f, 0.f, 0.f};
    const unsigned span = (unsigned)(2 * r);

    for (int kt = kt0; kt <= kt1; ++kt) {
        int key = kt * 16 + l15;
        bf16x8 kf = *(const bf16x8*)(bbase + (size_t)key * 1536 + 256 + h * HDIM + quad * 8);
        f32x4 s4 = __builtin_amdgcn_mfma_f32_16x16x32_bf16(
            qf, kf, (f32x4){0.f, 0.f, 0.f, 0.f}, 0, 0, 0);
        #pragma unroll
        for (int rg = 0; rg < 4; ++rg) {
            int q = q0w + quad * 4 + rg;
            unsigned dd = (unsigned)(key - q + r);
            float p = (dd <= span)
                      ? __expf(fminf(s4[rg] * 0.17677669529663688f, 80.f)) : 0.f;
            rs4[rg] += p;
            Pw[(quad * 4 + rg) * 168 + (kt - kt0) * 16 + l15] = f2bf(p);
        }
    }

    #pragma unroll
    for (int m = 1; m < 16; m <<= 1) {
        #pragma unroll
        for (int rg = 0; rg < 4; ++rg) rs4[rg] += __shfl_xor(rs4[rg], m, 64);
    }

    f32x4 o0 = (f32x4){0.f, 0.f, 0.f, 0.f};
    f32x4 o1 = (f32x4){0.f, 0.f, 0.f, 0.f};
    const int basek = (kt0 - t0) * 16;
    const int nch = (nt + 1) >> 1;
    for (int c = 0; c < nch; ++c) {
        bf16x8 pa = *(const bf16x8*)(Pw + l15 * 168 + c * 32 + quad * 8);
        bf16x8 v0 = *(const bf16x8*)(&Vt[l15 * 216 + basek + c * 32 + quad * 8]);
        bf16x8 v1 = *(const bf16x8*)(&Vt[(l15 + 16) * 216 + basek + c * 32 + quad * 8]);
        o0 = __builtin_amdgcn_mfma_f32_16x16x32_bf16(pa, v0, o0, 0, 0, 0);
        o1 = __builtin_amdgcn_mfma_f32_16x16x32_bf16(pa, v1, o1, 0, 0, 0);
    }

    #pragma unroll
    for (int rg = 0; rg < 4; ++rg) {
        float inv = 1.0f / rs4[rg];
        int q = q0w + quad * 4 + rg;
        ushortT* op = ocat + ((size_t)(b * S_LEN) + q) * 1024 + si * DMODEL + h * HDIM;
        op[l15]      = f2bf(o0[rg] * inv);
        op[16 + l15] = f2bf(o1[rg] * inv);
    }
}

// one wave per 256-wide row: out = LN(a) * g + be; dual fp32/bf16 write
__global__ __launch_bounds__(64) void ln_wave(
    const float* __restrict__ a,
    const float* __restrict__ g, const float* __restrict__ be,
    float* __restrict__ o32, ushortT* __restrict__ o16)
{
    const int row = blockIdx.x, lane = threadIdx.x;
    float4 v = *(const float4*)(a + (size_t)row * DMODEL + lane * 4);
    float s = v.x + v.y + v.z + v.w;
    #pragma unroll
    for (int off = 32; off; off >>= 1) s += __shfl_xor(s, off, 64);
    float m = s * (1.0f / DMODEL);
    float dx = v.x - m, dy = v.y - m, dz = v.z - m, dw = v.w - m;
    float s2 = dx * dx + dy * dy + dz * dz + dw * dw;
    #pragma unroll
    for (int off = 32; off; off >>= 1) s2 += __shfl_xor(s2, off, 64);
    float r = rsqrtf(s2 * (1.0f / DMODEL) + 1e-5f);
    float4 gg = *(const float4*)(g + lane * 4);
    float4 bb = *(const float4*)(be + lane * 4);
    float y0 = dx * r * gg.x + bb.x, y1 = dy * r * gg.y + bb.y;
    float y2 = dz * r * gg.z + bb.z, y3 = dw * r * gg.w + bb.w;
    *(float4*)(o32 + (size_t)row * DMODEL + lane * 4) = make_float4(y0, y1, y2, y3);
    ushort4 u; u.x = f2bf(y0); u.y = f2bf(y1); u.z = f2bf(y2); u.w = f2bf(y3);
    *(ushort4*)(o16 + (size_t)row * DMODEL + lane * 4) = u;
}

// generic small transpose: dst[c*R + r] = src[r*C + c]
__global__ __launch_bounds__(256) void transp_kernel(
    const float* __restrict__ src, float* __restrict__ dst, int R, int C)
{
    int i = blockIdx.x * 256 + threadIdx.x;
    if (i < R * C) {
        int r = i / C, c = i - r * C;
        dst[(size_t)c * R + r] = src[i];
    }
}

// Whole head, 16 blocks (one per batch row) x 256 thr; weights pre-transposed.
__global__ __launch_bounds__(256) void head_kernel(
    const float* __restrict__ x32, const float* __restrict__ features,
    const float* __restrict__ feat_wT, const float* __restrict__ feat_b,
    const float* __restrict__ feat_ln_g, const float* __restrict__ feat_ln_b,
    const float* __restrict__ h1_wT, const float* __restrict__ h1_b,
    const float* __restrict__ h_ln_g, const float* __restrict__ h_ln_b,
    const float* __restrict__ h2_wT, const float* __restrict__ h2_b,
    const float* __restrict__ h3_w, const float* __restrict__ h3_b,
    float* __restrict__ outp)
{
    __shared__ float xcat[512];
    __shared__ float h1s[256];
    __shared__ float red[8];
    __shared__ float r2[128];
    const int r = blockIdx.x, t = threadIdx.x;
    const int wid = t >> 6, lane = t & 63;

    xcat[t] = x32[((size_t)r * S_LEN + S_LEN / 2) * DMODEL + t];

    const float* frow = features + (size_t)r * 66;
    float s = feat_b[t];
    for (int k = 0; k < 66; ++k) s = fmaf(frow[k], feat_wT[k * 256 + t], s);
    {
        float a = s, a2 = s * s;
        #pragma unroll
        for (int off = 32; off; off >>= 1) { a += __shfl_xor(a, off, 64); a2 += __shfl_xor(a2, off, 64); }
        if (lane == 0) { red[wid] = a; red[wid + 4] = a2; }
        __syncthreads();
        float ts = red[0] + red[1] + red[2] + red[3];
        float ts2 = red[4] + red[5] + red[6] + red[7];
        float m = ts * (1.0f / 256.0f);
        float var = ts2 * (1.0f / 256.0f) - m * m;
        float rstd = rsqrtf(var + 1e-5f);
        float v = (s - m) * rstd * feat_ln_g[t] + feat_ln_b[t];
        xcat[256 + t] = gelu_f(v);
        __syncthreads();
    }

    s = h1_b[t];
    #pragma unroll 8
    for (int k = 0; k < 512; ++k) s = fmaf(xcat[k], h1_wT[k * 256 + t], s);
    {
        float a = s, a2 = s * s;
        #pragma unroll
        for (int off = 32; off; off >>= 1) { a += __shfl_xor(a, off, 64); a2 += __shfl_xor(a2, off, 64); }
        if (lane == 0) { red[wid] = a; red[wid + 4] = a2; }
        __syncthreads();
        float ts = red[0] + red[1] + red[2] + red[3];
        float ts2 = red[4] + red[5] + red[6] + red[7];
        float m = ts * (1.0f / 256.0f);
        float var = ts2 * (1.0f / 256.0f) - m * m;
        float rstd = rsqrtf(var + 1e-5f);
        float v = (s - m) * rstd * h_ln_g[t] + h_ln_b[t];
        h1s[t] = gelu_f(v);
        __syncthreads();
    }

    if (t < 128) {
        float v = h2_b[t];
        #pragma unroll 8
        for (int k = 0; k < 256; ++k) v = fmaf(h1s[k], h2_wT[k * 128 + t], v);
        r2[t] = gelu_f(v) * h3_w[t];
    }
    __syncthreads();
    if (t < 64) {
        float p = r2[t] + r2[t + 64];
        #pragma unroll
        for (int off = 32; off; off >>= 1) p += __shfl_xor(p, off, 64);
        if (t == 0) outp[r] = p + h3_b[0];
    }
}

__global__ __launch_bounds__(256) void cvt_kernel(
    const float4* __restrict__ src, ushort4* __restrict__ dst, int n4)
{
    int i = blockIdx.x * 256 + threadIdx.x;
    if (i < n4) {
        float4 f = src[i];
        ushort4 u; u.x = f2bf(f.x); u.y = f2bf(f.y); u.z = f2bf(f.z); u.w = f2bf(f.w);
        dst[i] = u;
    }
}

__global__ __launch_bounds__(256) void qkvbias_kernel(
    const float* __restrict__ aib, const float* __restrict__ aiw,
    const float* __restrict__ se, float* __restrict__ eb)
{
    int i = blockIdx.x * 256 + threadIdx.x;   // < 12288
    int r = i % 3072, si = r / 768;
    const float* w = aiw + (size_t)i * 256;
    const float* s = se + si * 256;
    float acc = aib[i];
    for (int k = 0; k < 256; ++k) acc = fmaf(s[k], w[k], acc);
    eb[i] = acc;
}

__global__ __launch_bounds__(256) void fusbias_kernel(
    const float* __restrict__ fus_b, const float* __restrict__ fus_w,
    const float* __restrict__ aob, float* __restrict__ fb)
{
    int l = blockIdx.x, n = threadIdx.x;
    const float* w = fus_w + ((size_t)l * 256 + n) * 1024;
    const float* o = aob + (size_t)l * 1024;
    float acc = fus_b[l * 256 + n];
    for (int j = 0; j < 1024; ++j) acc = fmaf(o[j], w[j], acc);
    fb[l * 256 + n] = acc;
}

static inline void mgemm(hipStream_t s, const ushortT* A, int lda, const ushortT* W, int ldw,
                         const float* bias, const float* betaC, float* o32, ushortT* o16,
                         int ldc, int M, int N, int K, int flags)
{
    if (N >= 1024) {
        dim3 g(M / 64, N / 128);
        hipLaunchKernelGGL((mfma_gemm<64, 128>), g, dim3(256), 0, s,
                           A, lda, W, ldw, bias, betaC, o32, o16, ldc, K, flags);
    } else {
        dim3 g(M / 64, N / 64);
        hipLaunchKernelGGL((mfma_gemm<64, 64>), g, dim3(256), 0, s,
                           A, lda, W, ldw, bias, betaC, o32, o16, ldc, K, flags);
    }
}

static inline void cvt(hipStream_t s, const float* src, ushortT* dst, size_t n)
{
    int n4 = (int)(n / 4);
    hipLaunchKernelGGL(cvt_kernel, dim3((n4 + 255) / 256), dim3(256), 0, s,
                       (const float4*)src, (ushort4*)dst, n4);
}

extern "C" void kernel_launch(void* const* d_in, const int* in_sizes, int n_in,
                              void* d_out, int out_size, void* d_ws, size_t ws_size,
                              hipStream_t stream)
{
    const float* emb        = (const float*)d_in[0];
    const float* features   = (const float*)d_in[1];
    const float* ip_w       = (const float*)d_in[2];
    const float* ip_b       = (const float*)d_in[3];
    const float* scale_emb  = (const float*)d_in[4];
    const float* attn_in_w  = (const float*)d_in[5];
    const float* attn_in_b  = (const float*)d_in[6];
    const float* attn_out_w = (const float*)d_in[7];
    const float* attn_out_b = (const float*)d_in[8];
    const float* fus_w      = (const float*)d_in[9];
    const float* fus_b      = (const float*)d_in[10];
    const float* ffn_w1     = (const float*)d_in[11];
    const float* ffn_b1     = (const float*)d_in[12];
    const float* ffn_w2     = (const float*)d_in[13];
    const float* ffn_b2     = (const float*)d_in[14];
    const float* n1_g       = (const float*)d_in[15];
    const float* n1_b       = (const float*)d_in[16];
    const float* n2_g       = (const float*)d_in[17];
    const float* n2_b       = (const float*)d_in[18];
    const float* feat_w     = (const float*)d_in[19];
    const float* feat_b     = (const float*)d_in[20];
    const float* feat_ln_g  = (const float*)d_in[21];
    const float* feat_ln_b  = (const float*)d_in[22];
    const float* h1_w       = (const float*)d_in[23];
    const float* h1_b       = (const float*)d_in[24];
    const float* h_ln_g     = (const float*)d_in[25];
    const float* h_ln_b     = (const float*)d_in[26];
    const float* h2_w       = (const float*)d_in[27];
    const float* h2_b       = (const float*)d_in[28];
    const float* h3_w       = (const float*)d_in[29];
    const float* h3_b       = (const float*)d_in[30];
    float* outp = (float*)d_out;

    const int Btok = 16 * S_LEN;   // 8192

    // ---- workspace carve-up ----
    char* p = (char*)d_ws;
    float* x32     = (float*)p;              p += (size_t)Btok * DMODEL * 4;
    float* fused32 = (float*)p;              p += (size_t)Btok * DMODEL * 4;
    float* effqkvb = (float*)p;              p += 12288 * 4;
    float* fusbias = (float*)p;              p += 1024 * 4;
    float* featwT  = (float*)p;              p += 66 * 256 * 4;
    float* h1wT    = (float*)p;              p += 512 * 256 * 4;
    float* h2wT    = (float*)p;              p += 256 * 128 * 4;
    ushortT* xbf   = (ushortT*)p;            p += (size_t)Btok * DMODEL * 2;
    ushortT* qkv2  = (ushortT*)p;            p += (size_t)Btok * 1536 * 2;   // pair buffer
    ushortT* ocat  = (ushortT*)p;            p += (size_t)Btok * 1024 * 2;
    ushortT* ipw_bf  = (ushortT*)p;          p += (size_t)DMODEL * 640 * 2;
    ushortT* aiw_bf  = (ushortT*)p;          p += (size_t)16 * 768 * 256 * 2;
    ushortT* wcat_bf = (ushortT*)p;          p += (size_t)4 * 256 * 1024 * 2;
    ushortT* f1_bf   = (ushortT*)p;          p += (size_t)4 * 1024 * 256 * 2;
    ushortT* f2_bf   = (ushortT*)p;          p += (size_t)4 * 256 * 1024 * 2;
    ushortT* embbf = qkv2;                   // alias: emb_bf dead before layer-0 qkv
    ushortT* midbf = ocat;                   // alias: ffn mid after ocat consumed

    // ---- precompute ----
    cvt(stream, emb, embbf, (size_t)Btok * 640);
    cvt(stream, ip_w, ipw_bf, (size_t)DMODEL * 640);
    cvt(stream, attn_in_w, aiw_bf, (size_t)16 * 768 * 256);
    cvt(stream, ffn_w1, f1_bf, (size_t)4 * 1024 * 256);
    cvt(stream, ffn_w2, f2_bf, (size_t)4 * 256 * 1024);
    hipLaunchKernelGGL(wc_mfma, dim3(2, 2, 16), dim3(256), 0, stream,
                       fus_w, attn_out_w, wcat_bf);
    hipLaunchKernelGGL(qkvbias_kernel, dim3(48), dim3(256), 0, stream,
                       attn_in_b, attn_in_w, scale_emb, effqkvb);
    hipLaunchKernelGGL(fusbias_kernel, dim3(4), dim3(256), 0, stream,
                       fus_b, fus_w, attn_out_b, fusbias);
    hipLaunchKernelGGL(transp_kernel, dim3(66), dim3(256), 0, stream, feat_w, featwT, 256, 66);
    hipLaunchKernelGGL(transp_kernel, dim3(512), dim3(256), 0, stream, h1_w, h1wT, 256, 512);
    hipLaunchKernelGGL(transp_kernel, dim3(128), dim3(256), 0, stream, h2_w, h2wT, 128, 256);

    // ---- x = emb @ ip_w^T + ip_b + PE ----
    mgemm(stream, embbf, 640, ipw_bf, 640, ip_b, nullptr, x32, xbf,
          DMODEL, Btok, DMODEL, 640, F_PE);

    // contiguous scale pairs {0,1} and {2,3}: one N=1536 qkv GEMM per pair
    static const int RADII[NSCALE] = {5, 10, 20, 50};

    for (int l = 0; l < NLAYER; ++l) {
        for (int pr = 0; pr < 2; ++pr) {
            const int ls0 = l * NSCALE + pr * 2;
            mgemm(stream, xbf, DMODEL, aiw_bf + (size_t)ls0 * 768 * 256, DMODEL,
                  effqkvb + (size_t)ls0 * 768, nullptr, nullptr, qkv2,
                  1536, Btok, 1536, DMODEL, 0);
            hipLaunchKernelGGL(attn_mfma, dim3(2048), dim3(256), 0, stream,
                               qkv2, ocat,
                               pr * 2, RADII[pr * 2], pr * 2 + 1, RADII[pr * 2 + 1]);
        }
        // fused32 = x + ocat @ Wcat[l]^T + fusbias[l]   (residual folded in)
        mgemm(stream, ocat, 1024, wcat_bf + (size_t)l * 256 * 1024, 1024,
              fusbias + l * DMODEL, x32, fused32, nullptr,
              DMODEL, Btok, DMODEL, 1024, F_BETA);
        hipLaunchKernelGGL(ln_wave, dim3(Btok), dim3(64), 0, stream,
                           fused32, n1_g + l * DMODEL, n1_b + l * DMODEL, x32, xbf);
        mgemm(stream, xbf, DMODEL, f1_bf + (size_t)l * 1024 * 256, DMODEL,
              ffn_b1 + (size_t)l * 1024, nullptr, nullptr, midbf,
              1024, Btok, 1024, DMODEL, F_GELU);
        // fused32 = x + mid @ ffn2^T + b2   (residual folded in)
        mgemm(stream, midbf, 1024, f2_bf + (size_t)l * 256 * 1024, 1024,
              ffn_b2 + (size_t)l * DMODEL, x32, fused32, nullptr,
              DMODEL, Btok, DMODEL, 1024, F_BETA);
        hipLaunchKernelGGL(ln_wave, dim3(Btok), dim3(64), 0, stream,
                           fused32, n2_g + l * DMODEL, n2_b + l * DMODEL, x32, xbf);
    }

    // ---- head: one kernel, 16 blocks ----
    hipLaunchKernelGGL(head_kernel, dim3(16), dim3(256), 0, stream,
                       x32, features, featwT, feat_b, feat_ln_g, feat_ln_b,
                       h1wT, h1_b, h_ln_g, h_ln_b, h2wT, h2_b, h3_w, h3_b, outp);
}

// Round 8
// 842.450 us; speedup vs baseline: 8.0412x; 1.0476x over previous
//
#include <hip/hip_runtime.h>
#include <math.h>

#define S_LEN 512
#define DMODEL 256
#define NHEAD 8
#define HDIM 32
#define NLAYER 4
#define NSCALE 4

typedef unsigned short ushortT;
typedef unsigned int uintT;
typedef short bf16x8 __attribute__((ext_vector_type(8)));
typedef float f32x4 __attribute__((ext_vector_type(4)));

enum { F_PE = 1, F_BETA = 2, F_GELU = 4 };

__device__ __forceinline__ float gelu_f(float x) {
    return 0.5f * x * (1.0f + erff(x * 0.70710678118654752440f));
}
__device__ __forceinline__ ushortT f2bf(float f) {
    union { float f; uintT i; } u; u.f = f;
    uintT r = u.i + 0x7FFF + ((u.i >> 16) & 1);   // RNE
    return (ushortT)(r >> 16);
}
__device__ __forceinline__ int swz(int r) { return (r & 3) ^ ((r >> 2) & 3); }

#define GLD16(g, l) \
    __builtin_amdgcn_global_load_lds((const __attribute__((address_space(1))) void*)(g), \
                                     (__attribute__((address_space(3))) void*)(l), 16, 0, 0)

// C[M,N] = op(A[M,K]bf16 @ W[N,K]bf16^T + bias) ; M%BM==0, N%BN==0, K%32==0
template<int BM, int BN>
__global__ __launch_bounds__(256) void mfma_gemm(
    const ushortT* __restrict__ A, int lda,
    const ushortT* __restrict__ W, int ldw,
    const float* __restrict__ bias,
    const float* __restrict__ betaC,
    float* __restrict__ out32,
    ushortT* __restrict__ out16,
    int ldc, int K, int flags)
{
    constexpr int MI = BM / 32;
    constexpr int NI = BN / 32;
    __shared__ __align__(16) ushortT As[BM * 32];
    __shared__ __align__(16) ushortT Bs[BN * 32];
    const int tid = threadIdx.x;
    const int wave = tid >> 6, lane = tid & 63;
    const int l15 = lane & 15, qd = lane >> 4;
    const int m0 = blockIdx.x * BM, n0 = blockIdx.y * BN;
    const int wm = (wave >> 1) * (BM / 2), wn = (wave & 1) * (BN / 2);

    f32x4 acc[MI][NI];
    #pragma unroll
    for (int i = 0; i < MI; ++i)
        #pragma unroll
        for (int j = 0; j < NI; ++j) acc[i][j] = (f32x4){0.f, 0.f, 0.f, 0.f};

    for (int k0 = 0; k0 < K; k0 += 32) {
        #pragma unroll
        for (int it = 0; it < BM / 64; ++it) {
            int c = it * 256 + tid;
            int m = c >> 2, s = c & 3;
            int kc = s ^ swz(m);
            const ushortT* g = A + (size_t)(m0 + m) * lda + k0 + kc * 8;
            GLD16(g, (ushortT*)As + (size_t)(it * 256 + wave * 64) * 8);
        }
        #pragma unroll
        for (int it = 0; it < BN / 64; ++it) {
            int c = it * 256 + tid;
            int n = c >> 2, s = c & 3;
            int kc = s ^ swz(n);
            const ushortT* g = W + (size_t)(n0 + n) * ldw + k0 + kc * 8;
            GLD16(g, (ushortT*)Bs + (size_t)(it * 256 + wave * 64) * 8);
        }
        __syncthreads();
        bf16x8 af[MI], bfr[NI];
        #pragma unroll
        for (int mi = 0; mi < MI; ++mi) {
            int r = wm + mi * 16 + l15;
            af[mi] = *(const bf16x8*)(As + r * 32 + (qd ^ swz(r)) * 8);
        }
        #pragma unroll
        for (int ni = 0; ni < NI; ++ni) {
            int r = wn + ni * 16 + l15;
            bfr[ni] = *(const bf16x8*)(Bs + r * 32 + (qd ^ swz(r)) * 8);
        }
        #pragma unroll
        for (int mi = 0; mi < MI; ++mi)
            #pragma unroll
            for (int ni = 0; ni < NI; ++ni)
                acc[mi][ni] = __builtin_amdgcn_mfma_f32_16x16x32_bf16(
                    af[mi], bfr[ni], acc[mi][ni], 0, 0, 0);
        __syncthreads();
    }

    #pragma unroll
    for (int mi = 0; mi < MI; ++mi) {
        #pragma unroll
        for (int ni = 0; ni < NI; ++ni) {
            int col = n0 + wn + ni * 16 + l15;
            float bv = bias ? bias[col] : 0.f;
            #pragma unroll
            for (int r = 0; r < 4; ++r) {
                int grow = m0 + wm + mi * 16 + qd * 4 + r;
                float v = acc[mi][ni][r] + bv;
                if (flags & F_BETA) v += betaC[(size_t)grow * ldc + col];
                if (flags & F_PE) {
                    int pos = grow & (S_LEN - 1);
                    float div = expf((float)(col & ~1) * (-9.210340371976184f / 256.0f));
                    float ang = (float)pos * div;
                    v += (col & 1) ? cosf(ang) : sinf(ang);
                }
                if (flags & F_GELU) v = gelu_f(v);
                if (out32) out32[(size_t)grow * ldc + col] = v;
                if (out16) out16[(size_t)grow * ldc + col] = f2bf(v);
            }
        }
    }
}

// Batched MFMA for Wcat: for each ls=(l,si):
//   Wcat[l][n][si*256+j] = sum_p fus_w[l][n][si*256+p] * ao_w[ls][p][j]
__global__ __launch_bounds__(256) void wc_mfma(
    const float* __restrict__ fus_w, const float* __restrict__ ao_w,
    ushortT* __restrict__ Wcat)
{
    __shared__ __align__(16) ushortT As[128 * 32];
    __shared__ __align__(16) ushortT Bs[128 * 32];
    const int z = blockIdx.z, l = z >> 2, si = z & 3;
    const int m0 = blockIdx.x * 128, n0 = blockIdx.y * 128;
    const int tid = threadIdx.x;
    const int wave = tid >> 6, lane = tid & 63;
    const int l15 = lane & 15, qd = lane >> 4;
    const int wm = (wave >> 1) * 64, wn = (wave & 1) * 64;
    const float* Abase = fus_w + ((size_t)(l * 256) + m0) * 1024 + si * 256;
    const float* Bbase = ao_w + (size_t)z * 65536;

    f32x4 acc[4][4];
    #pragma unroll
    for (int i = 0; i < 4; ++i)
        #pragma unroll
        for (int j = 0; j < 4; ++j) acc[i][j] = (f32x4){0.f, 0.f, 0.f, 0.f};

    const int am = tid >> 1, ah = tid & 1;
    const int bp = tid >> 3, bj = (tid & 7) * 16;

    for (int k0 = 0; k0 < 256; k0 += 32) {
        #pragma unroll
        for (int j = 0; j < 2; ++j) {
            const float* src = Abase + (size_t)am * 1024 + k0 + ah * 16 + j * 8;
            float4 f0 = *(const float4*)src;
            float4 f1 = *(const float4*)(src + 4);
            int sc = ah * 2 + j;
            ushortT* d = As + am * 32 + (sc ^ swz(am)) * 8;
            ushort4 u0; u0.x = f2bf(f0.x); u0.y = f2bf(f0.y); u0.z = f2bf(f0.z); u0.w = f2bf(f0.w);
            ushort4 u1; u1.x = f2bf(f1.x); u1.y = f2bf(f1.y); u1.z = f2bf(f1.z); u1.w = f2bf(f1.w);
            *(ushort4*)d = u0; *(ushort4*)(d + 4) = u1;
        }
        #pragma unroll
        for (int c = 0; c < 4; ++c) {
            float4 f = *(const float4*)(Bbase + (size_t)(k0 + bp) * 256 + n0 + bj + c * 4);
            float vv[4] = {f.x, f.y, f.z, f.w};
            #pragma unroll
            for (int e = 0; e < 4; ++e) {
                int r = bj + c * 4 + e;
                Bs[r * 32 + (((bp >> 3) ^ swz(r)) * 8) + (bp & 7)] = f2bf(vv[e]);
            }
        }
        __syncthreads();
        bf16x8 af[4], bfr[4];
        #pragma unroll
        for (int mi = 0; mi < 4; ++mi) {
            int r = wm + mi * 16 + l15;
            af[mi] = *(const bf16x8*)(As + r * 32 + (qd ^ swz(r)) * 8);
        }
        #pragma unroll
        for (int ni = 0; ni < 4; ++ni) {
            int r = wn + ni * 16 + l15;
            bfr[ni] = *(const bf16x8*)(Bs + r * 32 + (qd ^ swz(r)) * 8);
        }
        #pragma unroll
        for (int mi = 0; mi < 4; ++mi)
            #pragma unroll
            for (int ni = 0; ni < 4; ++ni)
                acc[mi][ni] = __builtin_amdgcn_mfma_f32_16x16x32_bf16(
                    af[mi], bfr[ni], acc[mi][ni], 0, 0, 0);
        __syncthreads();
    }

    #pragma unroll
    for (int mi = 0; mi < 4; ++mi) {
        #pragma unroll
        for (int ni = 0; ni < 4; ++ni) {
            int col = n0 + wn + ni * 16 + l15;
            #pragma unroll
            for (int r = 0; r < 4; ++r) {
                int row = m0 + wm + mi * 16 + qd * 4 + r;
                Wcat[((size_t)(l * 256) + row) * 1024 + si * 256 + col] =
                    f2bf(acc[mi][ni][r]);
            }
        }
    }
}

// MFMA banded attention, ALL 4 scales per launch.
// qkv: (B*S, 3072) = 4 scales x (q|k|v * 256). Block = (slot, qblk, h, b).
__global__ __launch_bounds__(256) void attn_mfma(
    const ushortT* __restrict__ qkv, ushortT* __restrict__ ocat)
{
    __shared__ __align__(16) ushortT Vt[32 * 216];     // [d][key_local], stride 216
    __shared__ __align__(16) ushortT Pl[4][16 * 168];  // per-wave P, stride 168
    const int bid = blockIdx.x;
    const int sp   = bid & 3;            // scale slot
    const int qblk = (bid >> 2) & 7;
    const int h    = (bid >> 5) & 7;
    const int b    = (bid >> 8) & 15;
    const int RAD[4] = {5, 10, 20, 50};
    const int r = RAD[sp];
    const int lcol = sp * 768;
    const int tid = threadIdx.x;

    const int q0blk = qblk * 64;
    const int t0 = max(0, q0blk - r) >> 4;
    const int t1 = min(S_LEN - 1, q0blk + 63 + r) >> 4;
    const int nstage = (t1 - t0 + 2) * 16;   // +1 zero pad tile
    const int kmax = min(S_LEN - 1, t1 * 16 + 15);

    const ushortT* bbase = qkv + (size_t)(b * S_LEN) * 3072 + lcol;

    for (int idx = tid; idx < nstage * 4; idx += 256) {
        int row = idx >> 2, dch = idx & 3;
        int key = t0 * 16 + row;
        uint4 u = make_uint4(0, 0, 0, 0);
        if (key <= kmax)
            u = *(const uint4*)(bbase + (size_t)key * 3072 + 512 + h * HDIM + dch * 8);
        ushortT* dst = &Vt[(dch * 8) * 216 + row];
        uintT w[4] = {u.x, u.y, u.z, u.w};
        #pragma unroll
        for (int t = 0; t < 4; ++t) {
            dst[(2 * t) * 216]     = (ushortT)(w[t] & 0xffff);
            dst[(2 * t + 1) * 216] = (ushortT)(w[t] >> 16);
        }
    }

    const int wid = tid >> 6, lane = tid & 63;
    const int quad = lane >> 4, l15 = lane & 15;
    ushortT* Pw = Pl[wid];

    {
        uint4 z = make_uint4(0, 0, 0, 0);
        #pragma unroll
        for (int i = 0; i < 6; ++i) {
            int c = lane + i * 64;
            if (c < 336) ((uint4*)Pw)[c] = z;
        }
    }
    __syncthreads();

    const int q0w = q0blk + wid * 16;
    bf16x8 qf = *(const bf16x8*)(bbase + (size_t)(q0w + l15) * 3072 + h * HDIM + quad * 8);

    const int kt0 = max(0, q0w - r) >> 4;
    const int kt1 = min(S_LEN - 1, q0w + 15 + r) >> 4;
    const int nt = kt1 - kt0 + 1;

    f32x4 rs4 = (f32x4){0.f, 0.f, 0.f, 0.f};
    const unsigned span = (unsigned)(2 * r);

    for (int kt = kt0; kt <= kt1; ++kt) {
        int key = kt * 16 + l15;
        bf16x8 kf = *(const bf16x8*)(bbase + (size_t)key * 3072 + 256 + h * HDIM + quad * 8);
        f32x4 s4 = __builtin_amdgcn_mfma_f32_16x16x32_bf16(
            qf, kf, (f32x4){0.f, 0.f, 0.f, 0.f}, 0, 0, 0);
        #pragma unroll
        for (int rg = 0; rg < 4; ++rg) {
            int q = q0w + quad * 4 + rg;
            unsigned dd = (unsigned)(key - q + r);
            float p = (dd <= span)
                      ? __expf(fminf(s4[rg] * 0.17677669529663688f, 80.f)) : 0.f;
            rs4[rg] += p;
            Pw[(quad * 4 + rg) * 168 + (kt - kt0) * 16 + l15] = f2bf(p);
        }
    }

    #pragma unroll
    for (int m = 1; m < 16; m <<= 1) {
        #pragma unroll
        for (int rg = 0; rg < 4; ++rg) rs4[rg] += __shfl_xor(rs4[rg], m, 64);
    }

    f32x4 o0 = (f32x4){0.f, 0.f, 0.f, 0.f};
    f32x4 o1 = (f32x4){0.f, 0.f, 0.f, 0.f};
    const int basek = (kt0 - t0) * 16;
    const int nch = (nt + 1) >> 1;
    for (int c = 0; c < nch; ++c) {
        bf16x8 pa = *(const bf16x8*)(Pw + l15 * 168 + c * 32 + quad * 8);
        bf16x8 v0 = *(const bf16x8*)(&Vt[l15 * 216 + basek + c * 32 + quad * 8]);
        bf16x8 v1 = *(const bf16x8*)(&Vt[(l15 + 16) * 216 + basek + c * 32 + quad * 8]);
        o0 = __builtin_amdgcn_mfma_f32_16x16x32_bf16(pa, v0, o0, 0, 0, 0);
        o1 = __builtin_amdgcn_mfma_f32_16x16x32_bf16(pa, v1, o1, 0, 0, 0);
    }

    #pragma unroll
    for (int rg = 0; rg < 4; ++rg) {
        float inv = 1.0f / rs4[rg];
        int q = q0w + quad * 4 + rg;
        ushortT* op = ocat + ((size_t)(b * S_LEN) + q) * 1024 + sp * DMODEL + h * HDIM;
        op[l15]      = f2bf(o0[rg] * inv);
        op[16 + l15] = f2bf(o1[rg] * inv);
    }
}

// one wave per 256-wide row: out = LN(a) * g + be; dual fp32/bf16 write
__global__ __launch_bounds__(64) void ln_wave(
    const float* __restrict__ a,
    const float* __restrict__ g, const float* __restrict__ be,
    float* __restrict__ o32, ushortT* __restrict__ o16)
{
    const int row = blockIdx.x, lane = threadIdx.x;
    float4 v = *(const float4*)(a + (size_t)row * DMODEL + lane * 4);
    float s = v.x + v.y + v.z + v.w;
    #pragma unroll
    for (int off = 32; off; off >>= 1) s += __shfl_xor(s, off, 64);
    float m = s * (1.0f / DMODEL);
    float dx = v.x - m, dy = v.y - m, dz = v.z - m, dw = v.w - m;
    float s2 = dx * dx + dy * dy + dz * dz + dw * dw;
    #pragma unroll
    for (int off = 32; off; off >>= 1) s2 += __shfl_xor(s2, off, 64);
    float r = rsqrtf(s2 * (1.0f / DMODEL) + 1e-5f);
    float4 gg = *(const float4*)(g + lane * 4);
    float4 bb = *(const float4*)(be + lane * 4);
    float y0 = dx * r * gg.x + bb.x, y1 = dy * r * gg.y + bb.y;
    float y2 = dz * r * gg.z + bb.z, y3 = dw * r * gg.w + bb.w;
    *(float4*)(o32 + (size_t)row * DMODEL + lane * 4) = make_float4(y0, y1, y2, y3);
    ushort4 u; u.x = f2bf(y0); u.y = f2bf(y1); u.z = f2bf(y2); u.w = f2bf(y3);
    *(ushort4*)(o16 + (size_t)row * DMODEL + lane * 4) = u;
}

// merged small precompute: ip_w cvt + 3 weight transposes
__global__ __launch_bounds__(256) void prep_misc(
    const float* __restrict__ ip_w, ushortT* __restrict__ ipw_bf,
    const float* __restrict__ feat_w, float* __restrict__ featwT,
    const float* __restrict__ h1_w, float* __restrict__ h1wT,
    const float* __restrict__ h2_w, float* __restrict__ h2wT)
{
    int i = blockIdx.x * 256 + threadIdx.x;
    if (i < 40960) {                                  // ip_w: 163840 elems as float4
        float4 f = ((const float4*)ip_w)[i];
        ushort4 u; u.x = f2bf(f.x); u.y = f2bf(f.y); u.z = f2bf(f.z); u.w = f2bf(f.w);
        ((ushort4*)ipw_bf)[i] = u;
        return;
    }
    int j = i - 40960;
    if (j < 16896) {                                  // feat_w 256x66 -> T
        int r = j / 66, c = j - r * 66;
        featwT[(size_t)c * 256 + r] = feat_w[j];
        return;
    }
    j -= 16896;
    if (j < 131072) {                                 // h1_w 256x512 -> T
        int r = j >> 9, c = j & 511;
        h1wT[(size_t)c * 256 + r] = h1_w[j];
        return;
    }
    j -= 131072;
    if (j < 32768) {                                  // h2_w 128x256 -> T
        int r = j >> 8, c = j & 255;
        h2wT[(size_t)c * 128 + r] = h2_w[j];
    }
}

// Whole head, 16 blocks (one per batch row) x 256 thr; weights pre-transposed.
__global__ __launch_bounds__(256) void head_kernel(
    const float* __restrict__ x32, const float* __restrict__ features,
    const float* __restrict__ feat_wT, const float* __restrict__ feat_b,
    const float* __restrict__ feat_ln_g, const float* __restrict__ feat_ln_b,
    const float* __restrict__ h1_wT, const float* __restrict__ h1_b,
    const float* __restrict__ h_ln_g, const float* __restrict__ h_ln_b,
    const float* __restrict__ h2_wT, const float* __restrict__ h2_b,
    const float* __restrict__ h3_w, const float* __restrict__ h3_b,
    float* __restrict__ outp)
{
    __shared__ float xcat[512];
    __shared__ float h1s[256];
    __shared__ float red[8];
    __shared__ float r2[128];
    const int r = blockIdx.x, t = threadIdx.x;
    const int wid = t >> 6, lane = t & 63;

    xcat[t] = x32[((size_t)r * S_LEN + S_LEN / 2) * DMODEL + t];

    const float* frow = features + (size_t)r * 66;
    float s = feat_b[t];
    for (int k = 0; k < 66; ++k) s = fmaf(frow[k], feat_wT[k * 256 + t], s);
    {
        float a = s, a2 = s * s;
        #pragma unroll
        for (int off = 32; off; off >>= 1) { a += __shfl_xor(a, off, 64); a2 += __shfl_xor(a2, off, 64); }
        if (lane == 0) { red[wid] = a; red[wid + 4] = a2; }
        __syncthreads();
        float ts = red[0] + red[1] + red[2] + red[3];
        float ts2 = red[4] + red[5] + red[6] + red[7];
        float m = ts * (1.0f / 256.0f);
        float var = ts2 * (1.0f / 256.0f) - m * m;
        float rstd = rsqrtf(var + 1e-5f);
        float v = (s - m) * rstd * feat_ln_g[t] + feat_ln_b[t];
        xcat[256 + t] = gelu_f(v);
        __syncthreads();
    }

    s = h1_b[t];
    #pragma unroll 8
    for (int k = 0; k < 512; ++k) s = fmaf(xcat[k], h1_wT[k * 256 + t], s);
    {
        float a = s, a2 = s * s;
        #pragma unroll
        for (int off = 32; off; off >>= 1) { a += __shfl_xor(a, off, 64); a2 += __shfl_xor(a2, off, 64); }
        if (lane == 0) { red[wid] = a; red[wid + 4] = a2; }
        __syncthreads();
        float ts = red[0] + red[1] + red[2] + red[3];
        float ts2 = red[4] + red[5] + red[6] + red[7];
        float m = ts * (1.0f / 256.0f);
        float var = ts2 * (1.0f / 256.0f) - m * m;
        float rstd = rsqrtf(var + 1e-5f);
        float v = (s - m) * rstd * h_ln_g[t] + h_ln_b[t];
        h1s[t] = gelu_f(v);
        __syncthreads();
    }

    if (t < 128) {
        float v = h2_b[t];
        #pragma unroll 8
        for (int k = 0; k < 256; ++k) v = fmaf(h1s[k], h2_wT[k * 128 + t], v);
        r2[t] = gelu_f(v) * h3_w[t];
    }
    __syncthreads();
    if (t < 64) {
        float p = r2[t] + r2[t + 64];
        #pragma unroll
        for (int off = 32; off; off >>= 1) p += __shfl_xor(p, off, 64);
        if (t == 0) outp[r] = p + h3_b[0];
    }
}

__global__ __launch_bounds__(256) void cvt_kernel(
    const float4* __restrict__ src, ushort4* __restrict__ dst, int n4)
{
    int i = blockIdx.x * 256 + threadIdx.x;
    if (i < n4) {
        float4 f = src[i];
        ushort4 u; u.x = f2bf(f.x); u.y = f2bf(f.y); u.z = f2bf(f.z); u.w = f2bf(f.w);
        dst[i] = u;
    }
}

__global__ __launch_bounds__(256) void qkvbias_kernel(
    const float* __restrict__ aib, const float* __restrict__ aiw,
    const float* __restrict__ se, float* __restrict__ eb)
{
    int i = blockIdx.x * 256 + threadIdx.x;   // < 12288
    int r = i % 3072, si = r / 768;
    const float* w = aiw + (size_t)i * 256;
    const float* s = se + si * 256;
    float acc = aib[i];
    for (int k = 0; k < 256; ++k) acc = fmaf(s[k], w[k], acc);
    eb[i] = acc;
}

__global__ __launch_bounds__(256) void fusbias_kernel(
    const float* __restrict__ fus_b, const float* __restrict__ fus_w,
    const float* __restrict__ aob, float* __restrict__ fb)
{
    int l = blockIdx.x, n = threadIdx.x;
    const float* w = fus_w + ((size_t)l * 256 + n) * 1024;
    const float* o = aob + (size_t)l * 1024;
    float acc = fus_b[l * 256 + n];
    for (int j = 0; j < 1024; ++j) acc = fmaf(o[j], w[j], acc);
    fb[l * 256 + n] = acc;
}

static inline void mgemm(hipStream_t s, const ushortT* A, int lda, const ushortT* W, int ldw,
                         const float* bias, const float* betaC, float* o32, ushortT* o16,
                         int ldc, int M, int N, int K, int flags)
{
    if (N >= 3072) {
        dim3 g(M / 128, N / 128);
        hipLaunchKernelGGL((mfma_gemm<128, 128>), g, dim3(256), 0, s,
                           A, lda, W, ldw, bias, betaC, o32, o16, ldc, K, flags);
    } else if (N >= 1024) {
        dim3 g(M / 64, N / 128);
        hipLaunchKernelGGL((mfma_gemm<64, 128>), g, dim3(256), 0, s,
                           A, lda, W, ldw, bias, betaC, o32, o16, ldc, K, flags);
    } else {
        dim3 g(M / 64, N / 64);
        hipLaunchKernelGGL((mfma_gemm<64, 64>), g, dim3(256), 0, s,
                           A, lda, W, ldw, bias, betaC, o32, o16, ldc, K, flags);
    }
}

static inline void cvt(hipStream_t s, const float* src, ushortT* dst, size_t n)
{
    int n4 = (int)(n / 4);
    hipLaunchKernelGGL(cvt_kernel, dim3((n4 + 255) / 256), dim3(256), 0, s,
                       (const float4*)src, (ushort4*)dst, n4);
}

extern "C" void kernel_launch(void* const* d_in, const int* in_sizes, int n_in,
                              void* d_out, int out_size, void* d_ws, size_t ws_size,
                              hipStream_t stream)
{
    const float* emb        = (const float*)d_in[0];
    const float* features   = (const float*)d_in[1];
    const float* ip_w       = (const float*)d_in[2];
    const float* ip_b       = (const float*)d_in[3];
    const float* scale_emb  = (const float*)d_in[4];
    const float* attn_in_w  = (const float*)d_in[5];
    const float* attn_in_b  = (const float*)d_in[6];
    const float* attn_out_w = (const float*)d_in[7];
    const float* attn_out_b = (const float*)d_in[8];
    const float* fus_w      = (const float*)d_in[9];
    const float* fus_b      = (const float*)d_in[10];
    const float* ffn_w1     = (const float*)d_in[11];
    const float* ffn_b1     = (const float*)d_in[12];
    const float* ffn_w2     = (const float*)d_in[13];
    const float* ffn_b2     = (const float*)d_in[14];
    const float* n1_g       = (const float*)d_in[15];
    const float* n1_b       = (const float*)d_in[16];
    const float* n2_g       = (const float*)d_in[17];
    const float* n2_b       = (const float*)d_in[18];
    const float* feat_w     = (const float*)d_in[19];
    const float* feat_b     = (const float*)d_in[20];
    const float* feat_ln_g  = (const float*)d_in[21];
    const float* feat_ln_b  = (const float*)d_in[22];
    const float* h1_w       = (const float*)d_in[23];
    const float* h1_b       = (const float*)d_in[24];
    const float* h_ln_g     = (const float*)d_in[25];
    const float* h_ln_b     = (const float*)d_in[26];
    const float* h2_w       = (const float*)d_in[27];
    const float* h2_b       = (const float*)d_in[28];
    const float* h3_w       = (const float*)d_in[29];
    const float* h3_b       = (const float*)d_in[30];
    float* outp = (float*)d_out;

    const int Btok = 16 * S_LEN;   // 8192

    // ---- workspace carve-up ----
    char* p = (char*)d_ws;
    float* x32     = (float*)p;              p += (size_t)Btok * DMODEL * 4;
    float* fused32 = (float*)p;              p += (size_t)Btok * DMODEL * 4;
    float* effqkvb = (float*)p;              p += 12288 * 4;
    float* fusbias = (float*)p;              p += 1024 * 4;
    float* featwT  = (float*)p;              p += 66 * 256 * 4;
    float* h1wT    = (float*)p;              p += 512 * 256 * 4;
    float* h2wT    = (float*)p;              p += 256 * 128 * 4;
    ushortT* xbf   = (ushortT*)p;            p += (size_t)Btok * DMODEL * 2;
    ushortT* qkv4  = (ushortT*)p;            p += (size_t)Btok * 3072 * 2;   // all 4 scales
    ushortT* ocat  = (ushortT*)p;            p += (size_t)Btok * 1024 * 2;
    ushortT* ipw_bf  = (ushortT*)p;          p += (size_t)DMODEL * 640 * 2;
    ushortT* aiw_bf  = (ushortT*)p;          p += (size_t)16 * 768 * 256 * 2;
    ushortT* wcat_bf = (ushortT*)p;          p += (size_t)4 * 256 * 1024 * 2;
    ushortT* f1_bf   = (ushortT*)p;          p += (size_t)4 * 1024 * 256 * 2;
    ushortT* f2_bf   = (ushortT*)p;          p += (size_t)4 * 256 * 1024 * 2;
    ushortT* embbf = qkv4;                   // alias: emb_bf dead before layer-0 qkv
    ushortT* midbf = ocat;                   // alias: ffn mid after ocat consumed

    // ---- precompute ----
    cvt(stream, emb, embbf, (size_t)Btok * 640);
    cvt(stream, attn_in_w, aiw_bf, (size_t)16 * 768 * 256);
    cvt(stream, ffn_w1, f1_bf, (size_t)4 * 1024 * 256);
    cvt(stream, ffn_w2, f2_bf, (size_t)4 * 256 * 1024);
    hipLaunchKernelGGL(prep_misc, dim3(866), dim3(256), 0, stream,
                       ip_w, ipw_bf, feat_w, featwT, h1_w, h1wT, h2_w, h2wT);
    hipLaunchKernelGGL(wc_mfma, dim3(2, 2, 16), dim3(256), 0, stream,
                       fus_w, attn_out_w, wcat_bf);
    hipLaunchKernelGGL(qkvbias_kernel, dim3(48), dim3(256), 0, stream,
                       attn_in_b, attn_in_w, scale_emb, effqkvb);
    hipLaunchKernelGGL(fusbias_kernel, dim3(4), dim3(256), 0, stream,
                       fus_b, fus_w, attn_out_b, fusbias);

    // ---- x = emb @ ip_w^T + ip_b + PE ----
    mgemm(stream, embbf, 640, ipw_bf, 640, ip_b, nullptr, x32, xbf,
          DMODEL, Btok, DMODEL, 640, F_PE);

    for (int l = 0; l < NLAYER; ++l) {
        // qkv for ALL 4 scales: N=3072, one launch
        mgemm(stream, xbf, DMODEL, aiw_bf + (size_t)l * 3072 * 256, DMODEL,
              effqkvb + (size_t)l * 3072, nullptr, nullptr, qkv4,
              3072, Btok, 3072, DMODEL, 0);
        hipLaunchKernelGGL(attn_mfma, dim3(4096), dim3(256), 0, stream, qkv4, ocat);
        // fused32 = x + ocat @ Wcat[l]^T + fusbias[l]
        mgemm(stream, ocat, 1024, wcat_bf + (size_t)l * 256 * 1024, 1024,
              fusbias + l * DMODEL, x32, fused32, nullptr,
              DMODEL, Btok, DMODEL, 1024, F_BETA);
        hipLaunchKernelGGL(ln_wave, dim3(Btok), dim3(64), 0, stream,
                           fused32, n1_g + l * DMODEL, n1_b + l * DMODEL, x32, xbf);
        mgemm(stream, xbf, DMODEL, f1_bf + (size_t)l * 1024 * 256, DMODEL,
              ffn_b1 + (size_t)l * 1024, nullptr, nullptr, midbf,
              1024, Btok, 1024, DMODEL, F_GELU);
        // fused32 = x + mid @ ffn2^T + b2
        mgemm(stream, midbf, 1024, f2_bf + (size_t)l * 256 * 1024, 1024,
              ffn_b2 + (size_t)l * DMODEL, x32, fused32, nullptr,
              DMODEL, Btok, DMODEL, 1024, F_BETA);
        hipLaunchKernelGGL(ln_wave, dim3(Btok), dim3(64), 0, stream,
                           fused32, n2_g + l * DMODEL, n2_b + l * DMODEL, x32, xbf);
    }

    // ---- head ----
    hipLaunchKernelGGL(head_kernel, dim3(16), dim3(256), 0, stream,
                       x32, features, featwT, feat_b, feat_ln_g, feat_ln_b,
                       h1wT, h1_b, h_ln_g, h_ln_b, h2wT, h2_b, h3_w, h3_b, outp);
}